// Round 9
// baseline (2182.865 us; speedup 1.0000x reference)
//
#include <hip/hip_runtime.h>
#include <cstdint>
#include <cstddef>

#define GN    32768
#define GG    64
#define NNODE 512
#define EE    256
#define LL    4
#define DFFN  2048
#define NHH   8
#define HD    32
#define NEDGE 524288
#define KSEL  128
#define DIN   128

typedef __attribute__((ext_vector_type(8))) short short8;
typedef __attribute__((ext_vector_type(4))) float floatx4;

// ---- bf16 helpers (RNE) ---------------------------------------------------
__device__ __forceinline__ unsigned short f2bf(float x) {
  unsigned u = __float_as_uint(x);
  u = (u + 0x7FFFu + ((u >> 16) & 1u)) >> 16;
  return (unsigned short)u;
}
__device__ __forceinline__ float bf2f(unsigned short u) {
  return __uint_as_float((unsigned)u << 16);
}
// trunc-split + hw pack: low16 = bf16(hi, exact), high16 = bf16(residual, RNE)
__device__ __forceinline__ unsigned tpack(float v) {
  unsigned hib = __float_as_uint(v) & 0xFFFF0000u;
  float hif = __uint_as_float(hib);
  unsigned pk;
  asm("v_cvt_pk_bf16_f32 %0, %1, %2" : "=v"(pk) : "v"(hif), "v"(v - hif));
  return pk;
}
// unpack 8 packed uints (2x uint4) -> hi short8 + lo short8
__device__ __forceinline__ void unpk(uint4 a0, uint4 a1, short8& hi, short8& lo) {
  union { short8 s; unsigned u[4]; } H, L;
  H.u[0] = __builtin_amdgcn_perm(a0.y, a0.x, 0x05040100u);
  H.u[1] = __builtin_amdgcn_perm(a0.w, a0.z, 0x05040100u);
  H.u[2] = __builtin_amdgcn_perm(a1.y, a1.x, 0x05040100u);
  H.u[3] = __builtin_amdgcn_perm(a1.w, a1.z, 0x05040100u);
  L.u[0] = __builtin_amdgcn_perm(a0.y, a0.x, 0x07060302u);
  L.u[1] = __builtin_amdgcn_perm(a0.w, a0.z, 0x07060302u);
  L.u[2] = __builtin_amdgcn_perm(a1.y, a1.x, 0x07060302u);
  L.u[3] = __builtin_amdgcn_perm(a1.w, a1.z, 0x07060302u);
  hi = H.s; lo = L.s;
}

// async global->LDS, 16B per lane (LDS dst must be wave-uniform base + lane*16)
__device__ __forceinline__ void ld_lds16(const ushort* g, ushort* l) {
  __builtin_amdgcn_global_load_lds(
      (const __attribute__((address_space(1))) unsigned int*)g,
      (__attribute__((address_space(3))) unsigned int*)l, 16, 0, 0);
}

// ---------------------------------------------------------------------------
// split fp32 -> (hi, lo) bf16 pair, 4 elements/thread
// ---------------------------------------------------------------------------
__global__ __launch_bounds__(256) void split_kernel(const float* __restrict__ in,
                                                    ushort* __restrict__ hi,
                                                    ushort* __restrict__ lo, int n4) {
  int i = blockIdx.x * 256 + threadIdx.x;
  if (i >= n4) return;
  float4 v = ((const float4*)in)[i];
  ushort4 hv, lv;
  float t[4] = {v.x, v.y, v.z, v.w};
  unsigned short hb;
  hb = f2bf(t[0]); hv.x = hb; lv.x = f2bf(t[0] - bf2f(hb));
  hb = f2bf(t[1]); hv.y = hb; lv.y = f2bf(t[1] - bf2f(hb));
  hb = f2bf(t[2]); hv.z = hb; lv.z = f2bf(t[2] - bf2f(hb));
  hb = f2bf(t[3]); hv.w = hb; lv.w = f2bf(t[3] - bf2f(hb));
  ((ushort4*)hi)[i] = hv;
  ((ushort4*)lo)[i] = lv;
}

// ---------------------------------------------------------------------------
// qkv_w split with softmax scale folded into Q rows (rows 0..255 of each 768)
// — removes 16 per-tile VALU muls in attn (exact fp32 pre-mul, same rel prec).
// ---------------------------------------------------------------------------
__global__ __launch_bounds__(256) void split_qkvw(const float* __restrict__ in,
                                                  ushort* __restrict__ hi,
                                                  ushort* __restrict__ lo, int n4) {
  int i = blockIdx.x * 256 + threadIdx.x;
  if (i >= n4) return;
  float4 v = ((const float4*)in)[i];
  int row = (i >> 6) % 768;   // element i*4 / 256-per-row
  float sc = (row < 256) ? (0.17677669529663687f * 1.44269504088896340f) : 1.0f;
  float t[4] = {v.x * sc, v.y * sc, v.z * sc, v.w * sc};
  ushort4 hv, lv;
  unsigned short hb;
  hb = f2bf(t[0]); hv.x = hb; lv.x = f2bf(t[0] - bf2f(hb));
  hb = f2bf(t[1]); hv.y = hb; lv.y = f2bf(t[1] - bf2f(hb));
  hb = f2bf(t[2]); hv.z = hb; lv.z = f2bf(t[2] - bf2f(hb));
  hb = f2bf(t[3]); hv.w = hb; lv.w = f2bf(t[3] - bf2f(hb));
  ((ushort4*)hi)[i] = hv;
  ((ushort4*)lo)[i] = lv;
}

// qkv bias with Q entries scaled
__global__ __launch_bounds__(256) void scale_qb(const float* __restrict__ qb,
                                                float* __restrict__ outb) {
  int i = blockIdx.x * 256 + threadIdx.x;
  if (i >= LL * 768) return;
  float sc = ((i % 768) < 256) ? (0.17677669529663687f * 1.44269504088896340f) : 1.0f;
  outb[i] = qb[i] * sc;
}

// ---------------------------------------------------------------------------
// Split-bf16 MFMA GEMM: C[M,N] = split(A)[M,K] @ split(B)[N,K]^T (+bias / +=C)
// XOR-swizzled LDS; XCD-chunked block swizzle (r1, FETCH 111->30 MB);
// double-buffered K-loop (r3).
// MODE bit0: fp32 C; bit1: split bf16 C (dual 2B arrays).
// PACKA: A is packed uint (hi|lo<<16), lda in uints.
// PACKC: C written packed uint (tpack) -> full 64B lines. PACKC+VT: packed
//   V-transpose scatter (4B).
// r5/r7 lesson: do NOT fuse FFN at BM=32 (L2-BW-bound on weights).
// r9: FFN row-sliced — ff1 full-DFF on half rows -> tP (128MB), ff2 K=2048
//   single-pass, no delta ACC round-trip (saves 64MB/layer fp32 traffic).
// ---------------------------------------------------------------------------
template <int BM, int BN, int MODE, bool RELU, bool VT, bool ACC,
          bool PACKA = false, bool PACKC = false>
__global__ __launch_bounds__(256) void mm_split(
    const ushort* __restrict__ a_hi, const ushort* __restrict__ a_lo,
    const ushort* __restrict__ b_hi, const ushort* __restrict__ b_lo,
    const float* __restrict__ bias,
    float* __restrict__ Cf, ushort* __restrict__ c_hi, ushort* __restrict__ c_lo,
    ushort* __restrict__ vth, ushort* __restrict__ vtl,
    int M, int N, int K, int lda, int ldb) {
  constexpr int MI = BM / 32;
  constexpr int NJ = BN / 32;
  __shared__ ushort As[2][2][BM * 32];   // [dbuf][hi/lo] (PACKA: packed uints)
  __shared__ ushort Bs[2][2][BN * 32];
  const int tid = threadIdx.x;
  const int w = tid >> 6, lane = tid & 63;
  const int wm = (w >> 1) * (BM / 2), wn = (w & 1) * (BN / 2);

  const int nwg = gridDim.x * gridDim.y;
  int flat = blockIdx.x + gridDim.x * blockIdx.y;
  int bnb, bmb;
  if ((nwg & 7) == 0) {
    int v = (flat & 7) * (nwg >> 3) + (flat >> 3);
    bnb = v % gridDim.x;
    bmb = v / gridDim.x;
  } else {
    bnb = blockIdx.x;
    bmb = blockIdx.y;
  }
  const int bm = bmb * BM, bn = bnb * BN;
  const int lrow = lane & 15, lquad = lane >> 4;

  floatx4 acc[MI][NJ];
  floatx4 zz = {0.f, 0.f, 0.f, 0.f};
#pragma unroll
  for (int i = 0; i < MI; ++i)
#pragma unroll
    for (int j = 0; j < NJ; ++j) acc[i][j] = zz;

  const uint* aP = (const uint*)a_hi;     // PACKA view
  const int arow = tid >> 2;
  const int acol = (((tid & 3) ^ ((arow >> 1) & 3)) << 3);  // swizzled source col
  const ushort* pah = a_hi + (size_t)(bm + arow) * lda + acol;
  const ushort* pal = a_lo + (size_t)(bm + arow) * lda + acol;
  const ushort* pbh = b_hi + (size_t)(bn + arow) * ldb + acol;
  const ushort* pbl = b_lo + (size_t)(bn + arow) * ldb + acol;

  auto stage = [&](int p, int k0) {
    if constexpr (PACKA) {
      // packed rows: 32 uints (128B) per k-step; 8 threads/row, 16B each,
      // 16B-group XOR (row&7) -> frag reads spread over 8 slots (2-way, free)
#pragma unroll
      for (int s = 0; s < BM / 32; ++s) {
        int row = s * 32 + (tid >> 3);
        int gp = tid & 7;
        const uint* src = aP + (size_t)(bm + row) * lda + k0 + ((gp ^ (row & 7)) << 2);
        ld_lds16((const ushort*)src,
                 (ushort*)((char*)&As[p][0][0] + s * 4096 + tid * 16));
      }
    } else {
#pragma unroll
      for (int s = 0; s < BM / 64; ++s) {
        ld_lds16(pah + (size_t)s * 64 * lda + k0, &As[p][0][s * 2048 + tid * 8]);
        ld_lds16(pal + (size_t)s * 64 * lda + k0, &As[p][1][s * 2048 + tid * 8]);
      }
    }
#pragma unroll
    for (int s = 0; s < BN / 64; ++s) {
      ld_lds16(pbh + (size_t)s * 64 * ldb + k0, &Bs[p][0][s * 2048 + tid * 8]);
      ld_lds16(pbl + (size_t)s * 64 * ldb + k0, &Bs[p][1][s * 2048 + tid * 8]);
    }
  };

  stage(0, 0);
  const int nk = K >> 5;
  for (int t = 0; t < nk; ++t) {
    const int p = t & 1;
    __syncthreads();                 // stage(p) landed; prev readers of p^1 done
    if (t + 1 < nk) stage(p ^ 1, (t + 1) << 5);  // async under compute(t)
    short8 ah[MI], al[MI], bh[NJ], bl[NJ];
    if constexpr (PACKA) {
      const uint* Ap = (const uint*)&As[p][0][0];
#pragma unroll
      for (int i = 0; i < MI; ++i) {
        int rr = wm + i * 16 + lrow;
        const uint* rb = Ap + rr * 32;
        uint4 a0 = *(const uint4*)(rb + (((lquad * 2) ^ (rr & 7)) << 2));
        uint4 a1 = *(const uint4*)(rb + (((lquad * 2 + 1) ^ (rr & 7)) << 2));
        unpk(a0, a1, ah[i], al[i]);
      }
    } else {
#pragma unroll
      for (int i = 0; i < MI; ++i) {
        int rr = wm + i * 16 + lrow;
        int r = rr * 32 + ((lquad ^ ((rr >> 1) & 3)) << 3);
        ah[i] = *(const short8*)&As[p][0][r];
        al[i] = *(const short8*)&As[p][1][r];
      }
    }
#pragma unroll
    for (int j = 0; j < NJ; ++j) {
      int rr = wn + j * 16 + lrow;
      int r = rr * 32 + ((lquad ^ ((rr >> 1) & 3)) << 3);
      bh[j] = *(const short8*)&Bs[p][0][r];
      bl[j] = *(const short8*)&Bs[p][1][r];
    }
#pragma unroll
    for (int i = 0; i < MI; ++i)
#pragma unroll
      for (int j = 0; j < NJ; ++j) {
        acc[i][j] = __builtin_amdgcn_mfma_f32_16x16x32_bf16(al[i], bh[j], acc[i][j], 0, 0, 0);
        acc[i][j] = __builtin_amdgcn_mfma_f32_16x16x32_bf16(ah[i], bl[j], acc[i][j], 0, 0, 0);
        acc[i][j] = __builtin_amdgcn_mfma_f32_16x16x32_bf16(ah[i], bh[j], acc[i][j], 0, 0, 0);
      }
  }

#pragma unroll
  for (int j = 0; j < NJ; ++j) {
    int col = bn + wn + j * 16 + lrow;
    float bj = ACC ? 0.0f : bias[col];
#pragma unroll
    for (int i = 0; i < MI; ++i) {
      int row0 = bm + wm + i * 16 + lquad * 4;
#pragma unroll
      for (int r = 0; r < 4; ++r) {
        size_t off = (size_t)(row0 + r) * N + col;
        float v = acc[i][j][r] + bj;
        if constexpr (ACC) v += Cf[off];
        if (RELU) v = fmaxf(v, 0.0f);
        if constexpr (MODE & 1) Cf[off] = v;
        if constexpr (PACKC) {
          unsigned pk = tpack(v);
          ((uint*)c_hi)[off] = pk;            // low16=hi, high16=lo
          if constexpr (VT) {
            if (col >= 512) {
              int hd = col - 512;
              int row = row0 + r;
              size_t vo = ((size_t)((row >> 9) * 8 + (hd >> 5)) * 32 + (hd & 31)) * 512 + (row & 511);
              ((uint*)vth)[vo] = pk;          // packed V-transpose scatter (4B)
            }
          }
        } else if constexpr (MODE & 2) {
          unsigned short hb = f2bf(v);
          unsigned short lb = f2bf(v - bf2f(hb));
          c_hi[off] = hb;
          c_lo[off] = lb;
          if constexpr (VT) {
            if (col >= 512) {
              int hd = col - 512;
              int row = row0 + r;
              size_t vo = ((size_t)((row >> 9) * 8 + (hd >> 5)) * 32 + (hd & 31)) * 512 + (row & 511);
              vth[vo] = hb;
              vtl[vo] = lb;
            }
          }
        }
      }
    }
  }
}

// ---------------------------------------------------------------------------
// Split GEMM + bias + residual + LayerNorm fused epilogue (BM=32; K=256
// out-proj only). r9: A input is PACKED attn output (uint hi|lo<<16) —
// full-line 4B attn stores + PACKA-style staged read here.
// ---------------------------------------------------------------------------
__global__ __launch_bounds__(256) void mm_ln(
    const uint* __restrict__ oP,
    const ushort* __restrict__ b_hi, const ushort* __restrict__ b_lo,
    const float* __restrict__ bias, const float* __restrict__ lnw,
    const float* __restrict__ lnb, float* __restrict__ hbuf,
    ushort* __restrict__ hhi, ushort* __restrict__ hlo, int K) {
  __shared__ uint AsP[32 * 32];          // packed A chunk (4KB)
  __shared__ ushort Bs[2][256 * 32];
  __shared__ float rsum[32], rsq[32], muA[32], rsA[32];
  const int tid = threadIdx.x;
  const int w = tid >> 6, lane = tid & 63;
  const int wn = w * 64;
  const int bm = blockIdx.x * 32;
  const int lr = lane & 15, quad = lane >> 4;

  floatx4 acc[2][4];
  floatx4 zz = {0.f, 0.f, 0.f, 0.f};
#pragma unroll
  for (int i = 0; i < 2; ++i)
#pragma unroll
    for (int j = 0; j < 4; ++j) acc[i][j] = zz;

  if (tid < 32) { rsum[tid] = 0.f; rsq[tid] = 0.f; }

  const int brow = tid >> 2;
  const int bcol = (((tid & 3) ^ ((brow >> 1) & 3)) << 3);

  for (int k0 = 0; k0 < K; k0 += 32) {
    __syncthreads();
    {
      int row = tid >> 3, gp = tid & 7;
      const uint* src = oP + (size_t)(bm + row) * 256 + k0 + ((gp ^ (row & 7)) << 2);
      ld_lds16((const ushort*)src, (ushort*)((char*)AsP + tid * 16));
    }
#pragma unroll
    for (int s = 0; s < 4; ++s) {
      ld_lds16(b_hi + (size_t)(s * 64 + brow) * K + bcol + k0, &Bs[0][s * 2048 + tid * 8]);
      ld_lds16(b_lo + (size_t)(s * 64 + brow) * K + bcol + k0, &Bs[1][s * 2048 + tid * 8]);
    }
    __syncthreads();
    short8 ah[2], al[2], bh[4], bl[4];
#pragma unroll
    for (int i = 0; i < 2; ++i) {
      int rr = i * 16 + lr;
      const uint* rb = AsP + rr * 32;
      uint4 a0 = *(const uint4*)(rb + (((quad * 2) ^ (rr & 7)) << 2));
      uint4 a1 = *(const uint4*)(rb + (((quad * 2 + 1) ^ (rr & 7)) << 2));
      unpk(a0, a1, ah[i], al[i]);
    }
#pragma unroll
    for (int j = 0; j < 4; ++j) {
      int rr = wn + j * 16 + lr;
      int r = rr * 32 + ((quad ^ ((rr >> 1) & 3)) << 3);
      bh[j] = *(const short8*)&Bs[0][r];
      bl[j] = *(const short8*)&Bs[1][r];
    }
#pragma unroll
    for (int i = 0; i < 2; ++i)
#pragma unroll
      for (int j = 0; j < 4; ++j) {
        acc[i][j] = __builtin_amdgcn_mfma_f32_16x16x32_bf16(al[i], bh[j], acc[i][j], 0, 0, 0);
        acc[i][j] = __builtin_amdgcn_mfma_f32_16x16x32_bf16(ah[i], bl[j], acc[i][j], 0, 0, 0);
        acc[i][j] = __builtin_amdgcn_mfma_f32_16x16x32_bf16(ah[i], bh[j], acc[i][j], 0, 0, 0);
      }
  }

  // ---- epilogue: v = acc + bias + residual; row LN; write h + split ----
#pragma unroll
  for (int i = 0; i < 2; ++i) {
#pragma unroll
    for (int r = 0; r < 4; ++r) {
      int ridx = i * 16 + quad * 4 + r;
      float sp = 0.f, qp = 0.f;
#pragma unroll
      for (int j = 0; j < 4; ++j) {
        int col = wn + j * 16 + lr;
        float v = acc[i][j][r] + bias[col] + hbuf[(size_t)(bm + ridx) * EE + col];
        acc[i][j][r] = v;
        sp += v;
        qp += v * v;
      }
#pragma unroll
      for (int m = 1; m < 16; m <<= 1) { sp += __shfl_xor(sp, m); qp += __shfl_xor(qp, m); }
      if (lr == 0) { atomicAdd(&rsum[ridx], sp); atomicAdd(&rsq[ridx], qp); }
    }
  }
  __syncthreads();
  if (tid < 32) {
    float mu = rsum[tid] * (1.0f / 256.0f);
    float var = rsq[tid] * (1.0f / 256.0f) - mu * mu;
    muA[tid] = mu;
    rsA[tid] = 1.0f / sqrtf(var + 1e-5f);
  }
  __syncthreads();
#pragma unroll
  for (int i = 0; i < 2; ++i) {
#pragma unroll
    for (int r = 0; r < 4; ++r) {
      int ridx = i * 16 + quad * 4 + r;
      float mu = muA[ridx], rsv = rsA[ridx];
#pragma unroll
      for (int j = 0; j < 4; ++j) {
        int col = wn + j * 16 + lr;
        float o = (acc[i][j][r] - mu) * rsv * lnw[col] + lnb[col];
        size_t off = (size_t)(bm + ridx) * EE + col;
        hbuf[off] = o;
        unsigned short hb = f2bf(o);
        hhi[off] = hb;
        hlo[off] = f2bf(o - bf2f(hb));
      }
    }
  }
}

// ---------------------------------------------------------------------------
// h = LN(h + t)*w + b ; also writes split(h). One wave per row.
// ---------------------------------------------------------------------------
__global__ __launch_bounds__(256) void ln_res_kernel(float* __restrict__ h,
                                                     const float* __restrict__ t,
                                                     const float* __restrict__ w,
                                                     const float* __restrict__ b,
                                                     ushort* __restrict__ h_hi,
                                                     ushort* __restrict__ h_lo) {
  int row = blockIdx.x * 4 + (threadIdx.x >> 6);
  int lane = threadIdx.x & 63;
  size_t off = (size_t)row * EE + (lane << 2);
  float4 hv = *(const float4*)&h[off];
  float4 tv = *(const float4*)&t[off];
  float v0 = hv.x + tv.x, v1 = hv.y + tv.y, v2 = hv.z + tv.z, v3 = hv.w + tv.w;
  float s = (v0 + v1) + (v2 + v3);
#pragma unroll
  for (int m = 32; m > 0; m >>= 1) s += __shfl_xor(s, m);
  float mu = s * (1.0f / 256.0f);
  float d0 = v0 - mu, d1 = v1 - mu, d2 = v2 - mu, d3 = v3 - mu;
  float s2 = (d0 * d0 + d1 * d1) + (d2 * d2 + d3 * d3);
#pragma unroll
  for (int m = 32; m > 0; m >>= 1) s2 += __shfl_xor(s2, m);
  float rs = 1.0f / sqrtf(s2 * (1.0f / 256.0f) + 1e-5f);
  float4 wv = *(const float4*)&w[lane << 2];
  float4 bv = *(const float4*)&b[lane << 2];
  float4 o;
  o.x = d0 * rs * wv.x + bv.x;
  o.y = d1 * rs * wv.y + bv.y;
  o.z = d2 * rs * wv.z + bv.z;
  o.w = d3 * rs * wv.w + bv.w;
  *(float4*)&h[off] = o;
  ushort4 hb4, lb4;
  unsigned short hb;
  hb = f2bf(o.x); hb4.x = hb; lb4.x = f2bf(o.x - bf2f(hb));
  hb = f2bf(o.y); hb4.y = hb; lb4.y = f2bf(o.y - bf2f(hb));
  hb = f2bf(o.z); hb4.z = hb; lb4.z = f2bf(o.z - bf2f(hb));
  hb = f2bf(o.w); hb4.w = hb; lb4.w = f2bf(o.w - bf2f(hb));
  *(ushort4*)&h_hi[off] = hb4;
  *(ushort4*)&h_lo[off] = lb4;
}

// ---------------------------------------------------------------------------
// MFMA flash attention — r7 structure + VALU diet + XCD-chunked grid swizzle
// + packed qkv/vt input (r8) + r9: scale pre-folded into Q (exp2(S) direct),
// PACKED o output (8x4B full-line stores, was 16x2B at 2x amplification).
// Do NOT: hoist S across m-tiles, chunk softmax <128 keys, 2 m-tiles/block,
// (gh,qt) grid — all measured regressions.
// ---------------------------------------------------------------------------
__global__ __launch_bounds__(256) void attn_mfma(const uint* __restrict__ qP,
                                                 const uint* __restrict__ vtP,
                                                 uint* __restrict__ oP) {
  __shared__ ushort Ks[2][64 * 40];
  __shared__ ushort Vt[2][32 * 72];
  __shared__ unsigned Pint[4][16 * 68];
  const int tid = threadIdx.x;
  const int w = tid >> 6, lane = tid & 63, c = lane & 15, quad = lane >> 4;
  int flat = blockIdx.x + 8 * (blockIdx.y + 8 * blockIdx.z);
  int v = (flat & 7) * ((GG * 64) >> 3) + (flat >> 3);
  const int qt = v & 7, hh = (v >> 3) & 7, g = v >> 6;
  const size_t g512 = (size_t)g * 512;
  const size_t vtbase = (size_t)(g * 8 + hh) * 32 * 512;

  const size_t qnode = g512 + qt * 64 + w * 16 + c;
  const uint* qp0 = qP + qnode * 768 + hh * 32 + quad * 8;
  uint4 q0 = *(const uint4*)qp0, q1 = *(const uint4*)(qp0 + 4);
  short8 qfh, qfl;
  unpk(q0, q1, qfh, qfl);

  floatx4 O0 = {0.f, 0.f, 0.f, 0.f}, O1 = {0.f, 0.f, 0.f, 0.f};
  floatx4 Lac = {0.f, 0.f, 0.f, 0.f};
  const short onev = (short)0x3F80;  // bf16 1.0
  const short8 onef = {onev, onev, onev, onev, onev, onev, onev, onev};

  const int skey = tid >> 2, sdc = (tid & 3) << 3;
  const int sd = tid >> 3, skc = (tid & 7) << 3;
  uint4 stg[4];
  auto load_tile = [&](int kb) {
    size_t go = (g512 + kb + skey) * 768 + 256 + hh * 32 + sdc;
    stg[0] = *(const uint4*)(qP + go);
    stg[1] = *(const uint4*)(qP + go + 4);
    size_t vo = vtbase + (size_t)sd * 512 + kb + skc;
    stg[2] = *(const uint4*)(vtP + vo);
    stg[3] = *(const uint4*)(vtP + vo + 4);
  };
  load_tile(0);

  for (int t = 0; t < 8; ++t) {
    if (t) __syncthreads();
    {
      short8 kh, kl, vh, vl;
      unpk(stg[0], stg[1], kh, kl);
      unpk(stg[2], stg[3], vh, vl);
      *(short8*)&Ks[0][skey * 40 + sdc] = kh;
      *(short8*)&Ks[1][skey * 40 + sdc] = kl;
      *(short8*)&Vt[0][sd * 72 + skc] = vh;
      *(short8*)&Vt[1][sd * 72 + skc] = vl;
    }
    __syncthreads();
    if (t < 7) load_tile((t + 1) * 64);

    // ---- S = Q K^T : 4 n-tiles of 16x16 (Q pre-scaled at split) ----
    floatx4 S[4];
#pragma unroll
    for (int n = 0; n < 4; ++n) {
      int r = (n * 16 + c) * 40 + quad * 8;
      short8 kfh = *(const short8*)&Ks[0][r];
      short8 kfl = *(const short8*)&Ks[1][r];
      floatx4 s = {0.f, 0.f, 0.f, 0.f};
      s = __builtin_amdgcn_mfma_f32_16x16x32_bf16(qfh, kfl, s, 0, 0, 0);
      s = __builtin_amdgcn_mfma_f32_16x16x32_bf16(qfl, kfh, s, 0, 0, 0);
      s = __builtin_amdgcn_mfma_f32_16x16x32_bf16(qfh, kfh, s, 0, 0, 0);
      S[n] = s;
    }
    // ---- softmax numerator, no max-sub: P = exp2(S); pack hi/lo ----
#pragma unroll
    for (int n = 0; n < 4; ++n) {
#pragma unroll
      for (int r = 0; r < 4; ++r) {
        float pp = exp2f(S[n][r]);
        Pint[w][(quad * 4 + r) * 68 + n * 16 + c] = tpack(pp);  // low=hi, high=lo
      }
    }
    // ---- PV: O += P @ V ; l += P @ 1 (2 d-tiles x 2 k-steps, split) ----
#pragma unroll
    for (int ks = 0; ks < 2; ++ks) {
      const unsigned* pp = &Pint[w][c * 68 + ks * 32 + quad * 8];
      uint4 a = *(const uint4*)pp;
      uint4 b = *(const uint4*)(pp + 4);
      short8 phs, pls;
      unpk(a, b, phs, pls);
      int r0 = c * 72 + ks * 32 + quad * 8;
      int r1 = (16 + c) * 72 + ks * 32 + quad * 8;
      short8 v0h = *(const short8*)&Vt[0][r0];
      short8 v0l = *(const short8*)&Vt[1][r0];
      short8 v1h = *(const short8*)&Vt[0][r1];
      short8 v1l = *(const short8*)&Vt[1][r1];
      O0 = __builtin_amdgcn_mfma_f32_16x16x32_bf16(phs, v0l, O0, 0, 0, 0);
      O0 = __builtin_amdgcn_mfma_f32_16x16x32_bf16(pls, v0h, O0, 0, 0, 0);
      O0 = __builtin_amdgcn_mfma_f32_16x16x32_bf16(phs, v0h, O0, 0, 0, 0);
      O1 = __builtin_amdgcn_mfma_f32_16x16x32_bf16(phs, v1l, O1, 0, 0, 0);
      O1 = __builtin_amdgcn_mfma_f32_16x16x32_bf16(pls, v1h, O1, 0, 0, 0);
      O1 = __builtin_amdgcn_mfma_f32_16x16x32_bf16(phs, v1h, O1, 0, 0, 0);
      Lac = __builtin_amdgcn_mfma_f32_16x16x32_bf16(phs, onef, Lac, 0, 0, 0);
      Lac = __builtin_amdgcn_mfma_f32_16x16x32_bf16(pls, onef, Lac, 0, 0, 0);
    }
  }

  // ---- epilogue: normalize, pack, store (full 64B lines) ----
#pragma unroll
  for (int r = 0; r < 4; ++r) {
    float inv = 1.0f / Lac[r];
    size_t node = g512 + qt * 64 + w * 16 + quad * 4 + r;
    size_t off0 = node * EE + hh * 32 + c;
    oP[off0] = tpack(O0[r] * inv);
    oP[off0 + 16] = tpack(O1[r] * inv);
  }
}

// ---------------------------------------------------------------------------
__global__ __launch_bounds__(256) void score_kernel(const float* __restrict__ h,
                                                    const float* __restrict__ sw,
                                                    const float* __restrict__ sb,
                                                    float* __restrict__ probs) {
  int row = blockIdx.x * 4 + (threadIdx.x >> 6);
  int lane = threadIdx.x & 63;
  float4 a = *(const float4*)&h[(size_t)row * EE + (lane << 2)];
  float4 w = *(const float4*)&sw[lane << 2];
  float s = (a.x * w.x + a.y * w.y) + (a.z * w.z + a.w * w.w);
#pragma unroll
  for (int m = 32; m > 0; m >>= 1) s += __shfl_xor(s, m);
  if (lane == 0) {
    float sc = s + sb[0];
    probs[row] = 1.0f / (1.0f + expf(-sc));
  }
}

// ---------------------------------------------------------------------------
// Per-graph exact top-k with jax.lax.top_k tie semantics (lower index wins).
// ---------------------------------------------------------------------------
__global__ __launch_bounds__(256) void topk_kernel(const float* __restrict__ probs,
                                                   float* __restrict__ out) {
  __shared__ unsigned long long keys[NNODE];
  __shared__ float pv[NNODE];
  __shared__ int flags[NNODE];
  __shared__ int sc[NNODE];
  const int g = blockIdx.x, tid = threadIdx.x;
  for (int i = tid; i < NNODE; i += 256) {
    float p = probs[g * NNODE + i];
    pv[i] = p;
    keys[i] = ((unsigned long long)__float_as_uint(p) << 32) |
              (unsigned long long)(~(unsigned)i);
    flags[i] = 0;
  }
  for (int k = 2; k <= NNODE; k <<= 1) {
    for (int j = k >> 1; j > 0; j >>= 1) {
      __syncthreads();
      for (int i = tid; i < NNODE; i += 256) {
        int ixj = i ^ j;
        if (ixj > i) {
          unsigned long long a = keys[i], bq = keys[ixj];
          bool desc = ((i & k) == 0);
          bool sw = desc ? (a < bq) : (a > bq);
          if (sw) { keys[i] = bq; keys[ixj] = a; }
        }
      }
    }
  }
  __syncthreads();
  if (tid < KSEL) {
    unsigned idx = ~(unsigned)(keys[tid] & 0xFFFFFFFFull);
    flags[idx] = 1;
  }
  __syncthreads();
  sc[tid] = flags[tid];
  sc[tid + 256] = flags[tid + 256];
  for (int off = 1; off < NNODE; off <<= 1) {
    __syncthreads();
    int x0 = (tid >= off) ? sc[tid - off] : 0;
    int x1 = sc[tid + 256 - off];
    int b0 = sc[tid], b1 = sc[tid + 256];
    __syncthreads();
    sc[tid] = b0 + x0;
    sc[tid + 256] = b1 + x1;
  }
  __syncthreads();
  for (int i = tid; i < NNODE; i += 256) {
    float p = pv[i];
    int f = flags[i];
    float ind = ((float)f - p) + p;
    float pf = p * ind;
    out[NEDGE + GG * KSEL + g * NNODE + i] = pf;
    if (f) out[NEDGE + g * KSEL + (sc[i] - 1)] = (float)(g * NNODE + i);
  }
}

// ---------------------------------------------------------------------------
__global__ __launch_bounds__(256) void edge_kernel(const int* __restrict__ ei,
                                                   const float* __restrict__ w,
                                                   float* __restrict__ out) {
  int e = blockIdx.x * 256 + threadIdx.x;
  const float* pf = out + NEDGE + GG * KSEL;
  out[e] = w[e] * pf[ei[e]] * pf[ei[NEDGE + e]];
}

// ---------------------------------------------------------------------------
extern "C" void kernel_launch(void* const* d_in, const int* in_sizes, int n_in,
                              void* d_out, int out_size, void* d_ws, size_t ws_size,
                              hipStream_t stream) {
  (void)in_sizes; (void)n_in; (void)out_size; (void)ws_size;
  const float* x     = (const float*)d_in[0];
  const int*   ei    = (const int*)d_in[1];
  const float* ewts  = (const float*)d_in[2];
  const float* emb_w = (const float*)d_in[3];
  const float* emb_b = (const float*)d_in[4];
  const float* qkv_w = (const float*)d_in[5];
  const float* qkv_b = (const float*)d_in[6];
  const float* out_w = (const float*)d_in[7];
  const float* out_b = (const float*)d_in[8];
  const float* ln1_w = (const float*)d_in[9];
  const float* ln1_b = (const float*)d_in[10];
  const float* ln2_w = (const float*)d_in[11];
  const float* ln2_b = (const float*)d_in[12];
  const float* ff1_w = (const float*)d_in[13];
  const float* ff1_b = (const float*)d_in[14];
  const float* ff2_w = (const float*)d_in[15];
  const float* ff2_b = (const float*)d_in[16];
  const float* sc_w  = (const float*)d_in[17];
  const float* sc_b  = (const float*)d_in[18];
  float* out = (float*)d_out;

  const size_t MB = 1024 * 1024;
  char* base = (char*)d_ws;
  float*  h    = (float*)base;                       // [0,32)
  ushort* h_hi = (ushort*)(base + 32 * MB);          // [32,48)
  ushort* h_lo = (ushort*)(base + 48 * MB);          // [48,64)
  char*   R    = base + 64 * MB;                     // [64,224) multi-use
  // attn phase:
  uint*   qkvP = (uint*)R;                           // [64,160)  GN x 768 packed
  uint*   oP   = (uint*)(R + 96 * MB);               // [160,192) GN x 256 packed
  uint*   vtP  = (uint*)(R + 128 * MB);              // [192,224) packed V-transpose
  // FFN phase (qkvP/oP/vtP dead): row-sliced
  uint*   tP   = (uint*)R;                           // [64,192)  16384 x 2048 packed = 128MB
  float*  delta = (float*)(R + 128 * MB);            // [192,224) GN x 256 fp32
  // embed phase:
  ushort* x_hi = (ushort*)R;                         // [64,72)
  ushort* x_lo = (ushort*)(R + 8 * MB);              // [72,80)
  float*  probs = (float*)R;                         // final
  char* W = base + 224 * MB;
  size_t woff = 0;
  auto walloc = [&](size_t bytes) { char* r = W + woff; woff += (bytes + 255) & ~(size_t)255; return (ushort*)r; };
  ushort* we_hi = walloc(256 * 128 * 2);
  ushort* we_lo = walloc(256 * 128 * 2);
  ushort* wq_hi = walloc((size_t)LL * 768 * 256 * 2);
  ushort* wq_lo = walloc((size_t)LL * 768 * 256 * 2);
  ushort* wo_hi = walloc((size_t)LL * 256 * 256 * 2);
  ushort* wo_lo = walloc((size_t)LL * 256 * 256 * 2);
  ushort* w1_hi = walloc((size_t)LL * DFFN * 256 * 2);
  ushort* w1_lo = walloc((size_t)LL * DFFN * 256 * 2);
  ushort* w2_hi = walloc((size_t)LL * 256 * DFFN * 2);
  ushort* w2_lo = walloc((size_t)LL * 256 * DFFN * 2);
  float*  qbs   = (float*)walloc((size_t)LL * 768 * 4);  // scaled qkv bias

  auto split = [&](const float* src, ushort* hi, ushort* lo, size_t n) {
    int n4 = (int)(n / 4);
    split_kernel<<<(n4 + 255) / 256, 256, 0, stream>>>(src, hi, lo, n4);
  };
  split(x, x_hi, x_lo, (size_t)GN * DIN);
  split(emb_w, we_hi, we_lo, 256 * 128);
  // qkv weights with softmax scale folded into Q rows
  split_qkvw<<<((LL * 768 * 256 / 4) + 255) / 256, 256, 0, stream>>>(
      qkv_w, wq_hi, wq_lo, LL * 768 * 256 / 4);
  scale_qb<<<(LL * 768 + 255) / 256, 256, 0, stream>>>(qkv_b, qbs);
  split(out_w, wo_hi, wo_lo, (size_t)LL * 256 * 256);
  split(ff1_w, w1_hi, w1_lo, (size_t)LL * DFFN * 256);
  split(ff2_w, w2_hi, w2_lo, (size_t)LL * 256 * DFFN);

  // ---- embed: h = x @ emb_w^T + emb_b (fp32 + split) ----
  mm_split<128, 128, 3, false, false, false><<<dim3(EE / 128, GN / 128), 256, 0, stream>>>(
      x_hi, x_lo, we_hi, we_lo, emb_b, h, h_hi, h_lo, nullptr, nullptr,
      GN, EE, DIN, DIN, DIN);

  for (int l = 0; l < LL; ++l) {
    // qkv: PACKED out (full-line 4B stores) + packed V-transpose scatter
    mm_split<128, 128, 0, false, true, false, false, true><<<dim3(768 / 128, GN / 128), 256, 0, stream>>>(
        h_hi, h_lo, wq_hi + (size_t)l * 768 * 256, wq_lo + (size_t)l * 768 * 256,
        qbs + l * 768, nullptr, (ushort*)qkvP, nullptr, (ushort*)vtP, nullptr,
        GN, 768, EE, EE, EE);
    attn_mfma<<<dim3(8, 8, GG), 256, 0, stream>>>(qkvP, vtP, oP);
    // out-proj + residual + LN1 fused (K=256), packed A
    mm_ln<<<GN / 32, 256, 0, stream>>>(
        oP, wo_hi + (size_t)l * 256 * 256, wo_lo + (size_t)l * 256 * 256,
        out_b + l * 256, ln1_w + l * EE, ln1_b + l * EE, h, h_hi, h_lo, EE);
    // FFN row-sliced: per half-rows, ff1 full-DFF -> tP, ff2 K=2048 single
    // pass (no delta ACC round-trip: delta written exactly once per row)
    for (int s = 0; s < 2; ++s) {
      const size_t rowbase = (size_t)s * 16384;
      mm_split<128, 128, 0, true, false, false, false, true><<<dim3(DFFN / 128, 16384 / 128), 256, 0, stream>>>(
          h_hi + rowbase * EE, h_lo + rowbase * EE,
          w1_hi + (size_t)l * DFFN * 256, w1_lo + (size_t)l * DFFN * 256,
          ff1_b + l * DFFN, nullptr, (ushort*)tP, nullptr, nullptr, nullptr,
          16384, DFFN, EE, EE, EE);
      mm_split<128, 128, 1, false, false, false, true, false><<<dim3(EE / 128, 16384 / 128), 256, 0, stream>>>(
          (const ushort*)tP, nullptr,
          w2_hi + (size_t)l * 256 * DFFN, w2_lo + (size_t)l * 256 * DFFN,
          ff2_b + l * 256, delta + rowbase * EE, nullptr, nullptr, nullptr, nullptr,
          16384, EE, DFFN, DFFN, DFFN);
    }
    ln_res_kernel<<<GN / 4, 256, 0, stream>>>(
        h, delta, ln2_w + l * EE, ln2_b + l * EE, h_hi, h_lo);
  }

  score_kernel<<<GN / 4, 256, 0, stream>>>(h, sc_w, sc_b, probs);
  topk_kernel<<<GG, 256, 0, stream>>>(probs, out);
  edge_kernel<<<NEDGE / 256, 256, 0, stream>>>(ei, ewts, out);
}

// Round 10
// 1918.451 us; speedup vs baseline: 1.1378x; 1.1378x over previous
//
#include <hip/hip_runtime.h>
#include <cstdint>
#include <cstddef>

#define GN    32768
#define GG    64
#define NNODE 512
#define EE    256
#define LL    4
#define DFFN  2048
#define NHH   8
#define HD    32
#define NEDGE 524288
#define KSEL  128
#define DIN   128

typedef __attribute__((ext_vector_type(8))) short short8;
typedef __attribute__((ext_vector_type(4))) float floatx4;

// ---- bf16 helpers (RNE) ---------------------------------------------------
__device__ __forceinline__ unsigned short f2bf(float x) {
  unsigned u = __float_as_uint(x);
  u = (u + 0x7FFFu + ((u >> 16) & 1u)) >> 16;
  return (unsigned short)u;
}
__device__ __forceinline__ float bf2f(unsigned short u) {
  return __uint_as_float((unsigned)u << 16);
}
// trunc-split + hw pack: low16 = bf16(hi, exact), high16 = bf16(residual, RNE)
__device__ __forceinline__ unsigned tpack(float v) {
  unsigned hib = __float_as_uint(v) & 0xFFFF0000u;
  float hif = __uint_as_float(hib);
  unsigned pk;
  asm("v_cvt_pk_bf16_f32 %0, %1, %2" : "=v"(pk) : "v"(hif), "v"(v - hif));
  return pk;
}
// unpack 8 packed uints (2x uint4) -> hi short8 + lo short8
__device__ __forceinline__ void unpk(uint4 a0, uint4 a1, short8& hi, short8& lo) {
  union { short8 s; unsigned u[4]; } H, L;
  H.u[0] = __builtin_amdgcn_perm(a0.y, a0.x, 0x05040100u);
  H.u[1] = __builtin_amdgcn_perm(a0.w, a0.z, 0x05040100u);
  H.u[2] = __builtin_amdgcn_perm(a1.y, a1.x, 0x05040100u);
  H.u[3] = __builtin_amdgcn_perm(a1.w, a1.z, 0x05040100u);
  L.u[0] = __builtin_amdgcn_perm(a0.y, a0.x, 0x07060302u);
  L.u[1] = __builtin_amdgcn_perm(a0.w, a0.z, 0x07060302u);
  L.u[2] = __builtin_amdgcn_perm(a1.y, a1.x, 0x07060302u);
  L.u[3] = __builtin_amdgcn_perm(a1.w, a1.z, 0x07060302u);
  hi = H.s; lo = L.s;
}

// async global->LDS, 16B per lane (LDS dst must be wave-uniform base + lane*16)
__device__ __forceinline__ void ld_lds16(const ushort* g, ushort* l) {
  __builtin_amdgcn_global_load_lds(
      (const __attribute__((address_space(1))) unsigned int*)g,
      (__attribute__((address_space(3))) unsigned int*)l, 16, 0, 0);
}

// ---------------------------------------------------------------------------
// split fp32 -> (hi, lo) bf16 pair, 4 elements/thread
// ---------------------------------------------------------------------------
__global__ __launch_bounds__(256) void split_kernel(const float* __restrict__ in,
                                                    ushort* __restrict__ hi,
                                                    ushort* __restrict__ lo, int n4) {
  int i = blockIdx.x * 256 + threadIdx.x;
  if (i >= n4) return;
  float4 v = ((const float4*)in)[i];
  ushort4 hv, lv;
  float t[4] = {v.x, v.y, v.z, v.w};
  unsigned short hb;
  hb = f2bf(t[0]); hv.x = hb; lv.x = f2bf(t[0] - bf2f(hb));
  hb = f2bf(t[1]); hv.y = hb; lv.y = f2bf(t[1] - bf2f(hb));
  hb = f2bf(t[2]); hv.z = hb; lv.z = f2bf(t[2] - bf2f(hb));
  hb = f2bf(t[3]); hv.w = hb; lv.w = f2bf(t[3] - bf2f(hb));
  ((ushort4*)hi)[i] = hv;
  ((ushort4*)lo)[i] = lv;
}

// ---------------------------------------------------------------------------
// qkv_w split with softmax scale folded into Q rows (rows 0..255 of each 768)
// — removes 16 per-tile VALU muls in attn (exact fp32 pre-mul, same rel prec).
// ---------------------------------------------------------------------------
__global__ __launch_bounds__(256) void split_qkvw(const float* __restrict__ in,
                                                  ushort* __restrict__ hi,
                                                  ushort* __restrict__ lo, int n4) {
  int i = blockIdx.x * 256 + threadIdx.x;
  if (i >= n4) return;
  float4 v = ((const float4*)in)[i];
  int row = (i >> 6) % 768;   // element i*4 / 256-per-row
  float sc = (row < 256) ? (0.17677669529663687f * 1.44269504088896340f) : 1.0f;
  float t[4] = {v.x * sc, v.y * sc, v.z * sc, v.w * sc};
  ushort4 hv, lv;
  unsigned short hb;
  hb = f2bf(t[0]); hv.x = hb; lv.x = f2bf(t[0] - bf2f(hb));
  hb = f2bf(t[1]); hv.y = hb; lv.y = f2bf(t[1] - bf2f(hb));
  hb = f2bf(t[2]); hv.z = hb; lv.z = f2bf(t[2] - bf2f(hb));
  hb = f2bf(t[3]); hv.w = hb; lv.w = f2bf(t[3] - bf2f(hb));
  ((ushort4*)hi)[i] = hv;
  ((ushort4*)lo)[i] = lv;
}

// qkv bias with Q entries scaled
__global__ __launch_bounds__(256) void scale_qb(const float* __restrict__ qb,
                                                float* __restrict__ outb) {
  int i = blockIdx.x * 256 + threadIdx.x;
  if (i >= LL * 768) return;
  float sc = ((i % 768) < 256) ? (0.17677669529663687f * 1.44269504088896340f) : 1.0f;
  outb[i] = qb[i] * sc;
}

// ---------------------------------------------------------------------------
// Split-bf16 MFMA GEMM: C[M,N] = split(A)[M,K] @ split(B)[N,K]^T (+bias / +=C)
// XOR-swizzled LDS; XCD-chunked block swizzle (r1, FETCH 111->30 MB);
// double-buffered K-loop (r3).
// MODE bit0: fp32 C; bit1: split bf16 C (dual 2B arrays).
// PACKA: A is packed uint (hi|lo<<16), lda in uints.
// PACKC: C written packed uint (tpack) -> full 64B lines. PACKC+VT: packed
//   V-transpose scatter (4B). MODE&1 and PACKC compose (embed writes both).
// r5/r7 lesson: do NOT fuse FFN at BM=32 (L2-BW-bound on weights).
// r9 lesson: do NOT row-slice FFN (ff2 grid 256 blocks = 1/CU, -230us).
// ---------------------------------------------------------------------------
template <int BM, int BN, int MODE, bool RELU, bool VT, bool ACC,
          bool PACKA = false, bool PACKC = false>
__global__ __launch_bounds__(256) void mm_split(
    const ushort* __restrict__ a_hi, const ushort* __restrict__ a_lo,
    const ushort* __restrict__ b_hi, const ushort* __restrict__ b_lo,
    const float* __restrict__ bias,
    float* __restrict__ Cf, ushort* __restrict__ c_hi, ushort* __restrict__ c_lo,
    ushort* __restrict__ vth, ushort* __restrict__ vtl,
    int M, int N, int K, int lda, int ldb) {
  constexpr int MI = BM / 32;
  constexpr int NJ = BN / 32;
  __shared__ ushort As[2][2][BM * 32];   // [dbuf][hi/lo] (PACKA: packed uints)
  __shared__ ushort Bs[2][2][BN * 32];
  const int tid = threadIdx.x;
  const int w = tid >> 6, lane = tid & 63;
  const int wm = (w >> 1) * (BM / 2), wn = (w & 1) * (BN / 2);

  const int nwg = gridDim.x * gridDim.y;
  int flat = blockIdx.x + gridDim.x * blockIdx.y;
  int bnb, bmb;
  if ((nwg & 7) == 0) {
    int v = (flat & 7) * (nwg >> 3) + (flat >> 3);
    bnb = v % gridDim.x;
    bmb = v / gridDim.x;
  } else {
    bnb = blockIdx.x;
    bmb = blockIdx.y;
  }
  const int bm = bmb * BM, bn = bnb * BN;
  const int lrow = lane & 15, lquad = lane >> 4;

  floatx4 acc[MI][NJ];
  floatx4 zz = {0.f, 0.f, 0.f, 0.f};
#pragma unroll
  for (int i = 0; i < MI; ++i)
#pragma unroll
    for (int j = 0; j < NJ; ++j) acc[i][j] = zz;

  const uint* aP = (const uint*)a_hi;     // PACKA view
  const int arow = tid >> 2;
  const int acol = (((tid & 3) ^ ((arow >> 1) & 3)) << 3);  // swizzled source col
  const ushort* pah = a_hi + (size_t)(bm + arow) * lda + acol;
  const ushort* pal = a_lo + (size_t)(bm + arow) * lda + acol;
  const ushort* pbh = b_hi + (size_t)(bn + arow) * ldb + acol;
  const ushort* pbl = b_lo + (size_t)(bn + arow) * ldb + acol;

  auto stage = [&](int p, int k0) {
    if constexpr (PACKA) {
      // packed rows: 32 uints (128B) per k-step; 8 threads/row, 16B each,
      // 16B-group XOR (row&7) -> frag reads spread over 8 slots (2-way, free)
#pragma unroll
      for (int s = 0; s < BM / 32; ++s) {
        int row = s * 32 + (tid >> 3);
        int gp = tid & 7;
        const uint* src = aP + (size_t)(bm + row) * lda + k0 + ((gp ^ (row & 7)) << 2);
        ld_lds16((const ushort*)src,
                 (ushort*)((char*)&As[p][0][0] + s * 4096 + tid * 16));
      }
    } else {
#pragma unroll
      for (int s = 0; s < BM / 64; ++s) {
        ld_lds16(pah + (size_t)s * 64 * lda + k0, &As[p][0][s * 2048 + tid * 8]);
        ld_lds16(pal + (size_t)s * 64 * lda + k0, &As[p][1][s * 2048 + tid * 8]);
      }
    }
#pragma unroll
    for (int s = 0; s < BN / 64; ++s) {
      ld_lds16(pbh + (size_t)s * 64 * ldb + k0, &Bs[p][0][s * 2048 + tid * 8]);
      ld_lds16(pbl + (size_t)s * 64 * ldb + k0, &Bs[p][1][s * 2048 + tid * 8]);
    }
  };

  stage(0, 0);
  const int nk = K >> 5;
  for (int t = 0; t < nk; ++t) {
    const int p = t & 1;
    __syncthreads();                 // stage(p) landed; prev readers of p^1 done
    if (t + 1 < nk) stage(p ^ 1, (t + 1) << 5);  // async under compute(t)
    short8 ah[MI], al[MI], bh[NJ], bl[NJ];
    if constexpr (PACKA) {
      const uint* Ap = (const uint*)&As[p][0][0];
#pragma unroll
      for (int i = 0; i < MI; ++i) {
        int rr = wm + i * 16 + lrow;
        const uint* rb = Ap + rr * 32;
        uint4 a0 = *(const uint4*)(rb + (((lquad * 2) ^ (rr & 7)) << 2));
        uint4 a1 = *(const uint4*)(rb + (((lquad * 2 + 1) ^ (rr & 7)) << 2));
        unpk(a0, a1, ah[i], al[i]);
      }
    } else {
#pragma unroll
      for (int i = 0; i < MI; ++i) {
        int rr = wm + i * 16 + lrow;
        int r = rr * 32 + ((lquad ^ ((rr >> 1) & 3)) << 3);
        ah[i] = *(const short8*)&As[p][0][r];
        al[i] = *(const short8*)&As[p][1][r];
      }
    }
#pragma unroll
    for (int j = 0; j < NJ; ++j) {
      int rr = wn + j * 16 + lrow;
      int r = rr * 32 + ((lquad ^ ((rr >> 1) & 3)) << 3);
      bh[j] = *(const short8*)&Bs[p][0][r];
      bl[j] = *(const short8*)&Bs[p][1][r];
    }
#pragma unroll
    for (int i = 0; i < MI; ++i)
#pragma unroll
      for (int j = 0; j < NJ; ++j) {
        acc[i][j] = __builtin_amdgcn_mfma_f32_16x16x32_bf16(al[i], bh[j], acc[i][j], 0, 0, 0);
        acc[i][j] = __builtin_amdgcn_mfma_f32_16x16x32_bf16(ah[i], bl[j], acc[i][j], 0, 0, 0);
        acc[i][j] = __builtin_amdgcn_mfma_f32_16x16x32_bf16(ah[i], bh[j], acc[i][j], 0, 0, 0);
      }
  }

#pragma unroll
  for (int j = 0; j < NJ; ++j) {
    int col = bn + wn + j * 16 + lrow;
    float bj = ACC ? 0.0f : bias[col];
#pragma unroll
    for (int i = 0; i < MI; ++i) {
      int row0 = bm + wm + i * 16 + lquad * 4;
#pragma unroll
      for (int r = 0; r < 4; ++r) {
        size_t off = (size_t)(row0 + r) * N + col;
        float v = acc[i][j][r] + bj;
        if constexpr (ACC) v += Cf[off];
        if (RELU) v = fmaxf(v, 0.0f);
        if constexpr (MODE & 1) Cf[off] = v;
        if constexpr (PACKC) {
          unsigned pk = tpack(v);
          ((uint*)c_hi)[off] = pk;            // low16=hi, high16=lo
          if constexpr (VT) {
            if (col >= 512) {
              int hd = col - 512;
              int row = row0 + r;
              size_t vo = ((size_t)((row >> 9) * 8 + (hd >> 5)) * 32 + (hd & 31)) * 512 + (row & 511);
              ((uint*)vth)[vo] = pk;          // packed V-transpose scatter (4B)
            }
          }
        } else if constexpr (MODE & 2) {
          unsigned short hb = f2bf(v);
          unsigned short lb = f2bf(v - bf2f(hb));
          c_hi[off] = hb;
          c_lo[off] = lb;
          if constexpr (VT) {
            if (col >= 512) {
              int hd = col - 512;
              int row = row0 + r;
              size_t vo = ((size_t)((row >> 9) * 8 + (hd >> 5)) * 32 + (hd & 31)) * 512 + (row & 511);
              vth[vo] = hb;
              vtl[vo] = lb;
            }
          }
        }
      }
    }
  }
}

// ---------------------------------------------------------------------------
// Split GEMM + bias + residual + LayerNorm fused epilogue (BM=32; K=256
// out-proj only). A input = PACKED attn output; h output = PACKED hP
// (full-64B-line 4B stores; dual-2B stores measured 1.45x write amplif.).
// ---------------------------------------------------------------------------
__global__ __launch_bounds__(256) void mm_ln(
    const uint* __restrict__ oP,
    const ushort* __restrict__ b_hi, const ushort* __restrict__ b_lo,
    const float* __restrict__ bias, const float* __restrict__ lnw,
    const float* __restrict__ lnb, float* __restrict__ hbuf,
    uint* __restrict__ hP, int K) {
  __shared__ uint AsP[32 * 32];          // packed A chunk (4KB)
  __shared__ ushort Bs[2][256 * 32];
  __shared__ float rsum[32], rsq[32], muA[32], rsA[32];
  const int tid = threadIdx.x;
  const int w = tid >> 6, lane = tid & 63;
  const int wn = w * 64;
  const int bm = blockIdx.x * 32;
  const int lr = lane & 15, quad = lane >> 4;

  floatx4 acc[2][4];
  floatx4 zz = {0.f, 0.f, 0.f, 0.f};
#pragma unroll
  for (int i = 0; i < 2; ++i)
#pragma unroll
    for (int j = 0; j < 4; ++j) acc[i][j] = zz;

  if (tid < 32) { rsum[tid] = 0.f; rsq[tid] = 0.f; }

  const int brow = tid >> 2;
  const int bcol = (((tid & 3) ^ ((brow >> 1) & 3)) << 3);

  for (int k0 = 0; k0 < K; k0 += 32) {
    __syncthreads();
    {
      int row = tid >> 3, gp = tid & 7;
      const uint* src = oP + (size_t)(bm + row) * 256 + k0 + ((gp ^ (row & 7)) << 2);
      ld_lds16((const ushort*)src, (ushort*)((char*)AsP + tid * 16));
    }
#pragma unroll
    for (int s = 0; s < 4; ++s) {
      ld_lds16(b_hi + (size_t)(s * 64 + brow) * K + bcol + k0, &Bs[0][s * 2048 + tid * 8]);
      ld_lds16(b_lo + (size_t)(s * 64 + brow) * K + bcol + k0, &Bs[1][s * 2048 + tid * 8]);
    }
    __syncthreads();
    short8 ah[2], al[2], bh[4], bl[4];
#pragma unroll
    for (int i = 0; i < 2; ++i) {
      int rr = i * 16 + lr;
      const uint* rb = AsP + rr * 32;
      uint4 a0 = *(const uint4*)(rb + (((quad * 2) ^ (rr & 7)) << 2));
      uint4 a1 = *(const uint4*)(rb + (((quad * 2 + 1) ^ (rr & 7)) << 2));
      unpk(a0, a1, ah[i], al[i]);
    }
#pragma unroll
    for (int j = 0; j < 4; ++j) {
      int rr = wn + j * 16 + lr;
      int r = rr * 32 + ((quad ^ ((rr >> 1) & 3)) << 3);
      bh[j] = *(const short8*)&Bs[0][r];
      bl[j] = *(const short8*)&Bs[1][r];
    }
#pragma unroll
    for (int i = 0; i < 2; ++i)
#pragma unroll
      for (int j = 0; j < 4; ++j) {
        acc[i][j] = __builtin_amdgcn_mfma_f32_16x16x32_bf16(al[i], bh[j], acc[i][j], 0, 0, 0);
        acc[i][j] = __builtin_amdgcn_mfma_f32_16x16x32_bf16(ah[i], bl[j], acc[i][j], 0, 0, 0);
        acc[i][j] = __builtin_amdgcn_mfma_f32_16x16x32_bf16(ah[i], bh[j], acc[i][j], 0, 0, 0);
      }
  }

  // ---- epilogue: v = acc + bias + residual; row LN; write h + packed ----
#pragma unroll
  for (int i = 0; i < 2; ++i) {
#pragma unroll
    for (int r = 0; r < 4; ++r) {
      int ridx = i * 16 + quad * 4 + r;
      float sp = 0.f, qp = 0.f;
#pragma unroll
      for (int j = 0; j < 4; ++j) {
        int col = wn + j * 16 + lr;
        float v = acc[i][j][r] + bias[col] + hbuf[(size_t)(bm + ridx) * EE + col];
        acc[i][j][r] = v;
        sp += v;
        qp += v * v;
      }
#pragma unroll
      for (int m = 1; m < 16; m <<= 1) { sp += __shfl_xor(sp, m); qp += __shfl_xor(qp, m); }
      if (lr == 0) { atomicAdd(&rsum[ridx], sp); atomicAdd(&rsq[ridx], qp); }
    }
  }
  __syncthreads();
  if (tid < 32) {
    float mu = rsum[tid] * (1.0f / 256.0f);
    float var = rsq[tid] * (1.0f / 256.0f) - mu * mu;
    muA[tid] = mu;
    rsA[tid] = 1.0f / sqrtf(var + 1e-5f);
  }
  __syncthreads();
#pragma unroll
  for (int i = 0; i < 2; ++i) {
#pragma unroll
    for (int r = 0; r < 4; ++r) {
      int ridx = i * 16 + quad * 4 + r;
      float mu = muA[ridx], rsv = rsA[ridx];
#pragma unroll
      for (int j = 0; j < 4; ++j) {
        int col = wn + j * 16 + lr;
        float o = (acc[i][j][r] - mu) * rsv * lnw[col] + lnb[col];
        size_t off = (size_t)(bm + ridx) * EE + col;
        hbuf[off] = o;
        hP[off] = tpack(o);
      }
    }
  }
}

// ---------------------------------------------------------------------------
// h = LN(h + t)*w + b ; writes fp32 h + PACKED hP. One wave per row.
// ---------------------------------------------------------------------------
__global__ __launch_bounds__(256) void ln_res_kernel(float* __restrict__ h,
                                                     const float* __restrict__ t,
                                                     const float* __restrict__ w,
                                                     const float* __restrict__ b,
                                                     uint* __restrict__ hP) {
  int row = blockIdx.x * 4 + (threadIdx.x >> 6);
  int lane = threadIdx.x & 63;
  size_t off = (size_t)row * EE + (lane << 2);
  float4 hv = *(const float4*)&h[off];
  float4 tv = *(const float4*)&t[off];
  float v0 = hv.x + tv.x, v1 = hv.y + tv.y, v2 = hv.z + tv.z, v3 = hv.w + tv.w;
  float s = (v0 + v1) + (v2 + v3);
#pragma unroll
  for (int m = 32; m > 0; m >>= 1) s += __shfl_xor(s, m);
  float mu = s * (1.0f / 256.0f);
  float d0 = v0 - mu, d1 = v1 - mu, d2 = v2 - mu, d3 = v3 - mu;
  float s2 = (d0 * d0 + d1 * d1) + (d2 * d2 + d3 * d3);
#pragma unroll
  for (int m = 32; m > 0; m >>= 1) s2 += __shfl_xor(s2, m);
  float rs = 1.0f / sqrtf(s2 * (1.0f / 256.0f) + 1e-5f);
  float4 wv = *(const float4*)&w[lane << 2];
  float4 bv = *(const float4*)&b[lane << 2];
  float4 o;
  o.x = d0 * rs * wv.x + bv.x;
  o.y = d1 * rs * wv.y + bv.y;
  o.z = d2 * rs * wv.z + bv.z;
  o.w = d3 * rs * wv.w + bv.w;
  *(float4*)&h[off] = o;
  uint4 pk;
  pk.x = tpack(o.x);
  pk.y = tpack(o.y);
  pk.z = tpack(o.z);
  pk.w = tpack(o.w);
  *(uint4*)&hP[off] = pk;
}

// ---------------------------------------------------------------------------
// MFMA flash attention — r7 structure + VALU diet + XCD-chunked grid swizzle
// + packed qkv/vt input (r8) + packed o output + Q-scale pre-fold (r9).
// Do NOT: hoist S across m-tiles, chunk softmax <128 keys, 2 m-tiles/block,
// (gh,qt) grid — all measured regressions.
// ---------------------------------------------------------------------------
__global__ __launch_bounds__(256) void attn_mfma(const uint* __restrict__ qP,
                                                 const uint* __restrict__ vtP,
                                                 uint* __restrict__ oP) {
  __shared__ ushort Ks[2][64 * 40];
  __shared__ ushort Vt[2][32 * 72];
  __shared__ unsigned Pint[4][16 * 68];
  const int tid = threadIdx.x;
  const int w = tid >> 6, lane = tid & 63, c = lane & 15, quad = lane >> 4;
  int flat = blockIdx.x + 8 * (blockIdx.y + 8 * blockIdx.z);
  int v = (flat & 7) * ((GG * 64) >> 3) + (flat >> 3);
  const int qt = v & 7, hh = (v >> 3) & 7, g = v >> 6;
  const size_t g512 = (size_t)g * 512;
  const size_t vtbase = (size_t)(g * 8 + hh) * 32 * 512;

  const size_t qnode = g512 + qt * 64 + w * 16 + c;
  const uint* qp0 = qP + qnode * 768 + hh * 32 + quad * 8;
  uint4 q0 = *(const uint4*)qp0, q1 = *(const uint4*)(qp0 + 4);
  short8 qfh, qfl;
  unpk(q0, q1, qfh, qfl);

  floatx4 O0 = {0.f, 0.f, 0.f, 0.f}, O1 = {0.f, 0.f, 0.f, 0.f};
  floatx4 Lac = {0.f, 0.f, 0.f, 0.f};
  const short onev = (short)0x3F80;  // bf16 1.0
  const short8 onef = {onev, onev, onev, onev, onev, onev, onev, onev};

  const int skey = tid >> 2, sdc = (tid & 3) << 3;
  const int sd = tid >> 3, skc = (tid & 7) << 3;
  uint4 stg[4];
  auto load_tile = [&](int kb) {
    size_t go = (g512 + kb + skey) * 768 + 256 + hh * 32 + sdc;
    stg[0] = *(const uint4*)(qP + go);
    stg[1] = *(const uint4*)(qP + go + 4);
    size_t vo = vtbase + (size_t)sd * 512 + kb + skc;
    stg[2] = *(const uint4*)(vtP + vo);
    stg[3] = *(const uint4*)(vtP + vo + 4);
  };
  load_tile(0);

  for (int t = 0; t < 8; ++t) {
    if (t) __syncthreads();
    {
      short8 kh, kl, vh, vl;
      unpk(stg[0], stg[1], kh, kl);
      unpk(stg[2], stg[3], vh, vl);
      *(short8*)&Ks[0][skey * 40 + sdc] = kh;
      *(short8*)&Ks[1][skey * 40 + sdc] = kl;
      *(short8*)&Vt[0][sd * 72 + skc] = vh;
      *(short8*)&Vt[1][sd * 72 + skc] = vl;
    }
    __syncthreads();
    if (t < 7) load_tile((t + 1) * 64);

    // ---- S = Q K^T : 4 n-tiles of 16x16 (Q pre-scaled at split) ----
    floatx4 S[4];
#pragma unroll
    for (int n = 0; n < 4; ++n) {
      int r = (n * 16 + c) * 40 + quad * 8;
      short8 kfh = *(const short8*)&Ks[0][r];
      short8 kfl = *(const short8*)&Ks[1][r];
      floatx4 s = {0.f, 0.f, 0.f, 0.f};
      s = __builtin_amdgcn_mfma_f32_16x16x32_bf16(qfh, kfl, s, 0, 0, 0);
      s = __builtin_amdgcn_mfma_f32_16x16x32_bf16(qfl, kfh, s, 0, 0, 0);
      s = __builtin_amdgcn_mfma_f32_16x16x32_bf16(qfh, kfh, s, 0, 0, 0);
      S[n] = s;
    }
    // ---- softmax numerator, no max-sub: P = exp2(S); pack hi/lo ----
#pragma unroll
    for (int n = 0; n < 4; ++n) {
#pragma unroll
      for (int r = 0; r < 4; ++r) {
        float pp = exp2f(S[n][r]);
        Pint[w][(quad * 4 + r) * 68 + n * 16 + c] = tpack(pp);  // low=hi, high=lo
      }
    }
    // ---- PV: O += P @ V ; l += P @ 1 (2 d-tiles x 2 k-steps, split) ----
#pragma unroll
    for (int ks = 0; ks < 2; ++ks) {
      const unsigned* pp = &Pint[w][c * 68 + ks * 32 + quad * 8];
      uint4 a = *(const uint4*)pp;
      uint4 b = *(const uint4*)(pp + 4);
      short8 phs, pls;
      unpk(a, b, phs, pls);
      int r0 = c * 72 + ks * 32 + quad * 8;
      int r1 = (16 + c) * 72 + ks * 32 + quad * 8;
      short8 v0h = *(const short8*)&Vt[0][r0];
      short8 v0l = *(const short8*)&Vt[1][r0];
      short8 v1h = *(const short8*)&Vt[0][r1];
      short8 v1l = *(const short8*)&Vt[1][r1];
      O0 = __builtin_amdgcn_mfma_f32_16x16x32_bf16(phs, v0l, O0, 0, 0, 0);
      O0 = __builtin_amdgcn_mfma_f32_16x16x32_bf16(pls, v0h, O0, 0, 0, 0);
      O0 = __builtin_amdgcn_mfma_f32_16x16x32_bf16(phs, v0h, O0, 0, 0, 0);
      O1 = __builtin_amdgcn_mfma_f32_16x16x32_bf16(phs, v1l, O1, 0, 0, 0);
      O1 = __builtin_amdgcn_mfma_f32_16x16x32_bf16(pls, v1h, O1, 0, 0, 0);
      O1 = __builtin_amdgcn_mfma_f32_16x16x32_bf16(phs, v1h, O1, 0, 0, 0);
      Lac = __builtin_amdgcn_mfma_f32_16x16x32_bf16(phs, onef, Lac, 0, 0, 0);
      Lac = __builtin_amdgcn_mfma_f32_16x16x32_bf16(pls, onef, Lac, 0, 0, 0);
    }
  }

  // ---- epilogue: normalize, pack, store (full 64B lines) ----
#pragma unroll
  for (int r = 0; r < 4; ++r) {
    float inv = 1.0f / Lac[r];
    size_t node = g512 + qt * 64 + w * 16 + quad * 4 + r;
    size_t off0 = node * EE + hh * 32 + c;
    oP[off0] = tpack(O0[r] * inv);
    oP[off0 + 16] = tpack(O1[r] * inv);
  }
}

// ---------------------------------------------------------------------------
__global__ __launch_bounds__(256) void score_kernel(const float* __restrict__ h,
                                                    const float* __restrict__ sw,
                                                    const float* __restrict__ sb,
                                                    float* __restrict__ probs) {
  int row = blockIdx.x * 4 + (threadIdx.x >> 6);
  int lane = threadIdx.x & 63;
  float4 a = *(const float4*)&h[(size_t)row * EE + (lane << 2)];
  float4 w = *(const float4*)&sw[lane << 2];
  float s = (a.x * w.x + a.y * w.y) + (a.z * w.z + a.w * w.w);
#pragma unroll
  for (int m = 32; m > 0; m >>= 1) s += __shfl_xor(s, m);
  if (lane == 0) {
    float sc = s + sb[0];
    probs[row] = 1.0f / (1.0f + expf(-sc));
  }
}

// ---------------------------------------------------------------------------
// Per-graph exact top-k with jax.lax.top_k tie semantics (lower index wins).
// ---------------------------------------------------------------------------
__global__ __launch_bounds__(256) void topk_kernel(const float* __restrict__ probs,
                                                   float* __restrict__ out) {
  __shared__ unsigned long long keys[NNODE];
  __shared__ float pv[NNODE];
  __shared__ int flags[NNODE];
  __shared__ int sc[NNODE];
  const int g = blockIdx.x, tid = threadIdx.x;
  for (int i = tid; i < NNODE; i += 256) {
    float p = probs[g * NNODE + i];
    pv[i] = p;
    keys[i] = ((unsigned long long)__float_as_uint(p) << 32) |
              (unsigned long long)(~(unsigned)i);
    flags[i] = 0;
  }
  for (int k = 2; k <= NNODE; k <<= 1) {
    for (int j = k >> 1; j > 0; j >>= 1) {
      __syncthreads();
      for (int i = tid; i < NNODE; i += 256) {
        int ixj = i ^ j;
        if (ixj > i) {
          unsigned long long a = keys[i], bq = keys[ixj];
          bool desc = ((i & k) == 0);
          bool sw = desc ? (a < bq) : (a > bq);
          if (sw) { keys[i] = bq; keys[ixj] = a; }
        }
      }
    }
  }
  __syncthreads();
  if (tid < KSEL) {
    unsigned idx = ~(unsigned)(keys[tid] & 0xFFFFFFFFull);
    flags[idx] = 1;
  }
  __syncthreads();
  sc[tid] = flags[tid];
  sc[tid + 256] = flags[tid + 256];
  for (int off = 1; off < NNODE; off <<= 1) {
    __syncthreads();
    int x0 = (tid >= off) ? sc[tid - off] : 0;
    int x1 = sc[tid + 256 - off];
    int b0 = sc[tid], b1 = sc[tid + 256];
    __syncthreads();
    sc[tid] = b0 + x0;
    sc[tid + 256] = b1 + x1;
  }
  __syncthreads();
  for (int i = tid; i < NNODE; i += 256) {
    float p = pv[i];
    int f = flags[i];
    float ind = ((float)f - p) + p;
    float pf = p * ind;
    out[NEDGE + GG * KSEL + g * NNODE + i] = pf;
    if (f) out[NEDGE + g * KSEL + (sc[i] - 1)] = (float)(g * NNODE + i);
  }
}

// ---------------------------------------------------------------------------
__global__ __launch_bounds__(256) void edge_kernel(const int* __restrict__ ei,
                                                   const float* __restrict__ w,
                                                   float* __restrict__ out) {
  int e = blockIdx.x * 256 + threadIdx.x;
  const float* pf = out + NEDGE + GG * KSEL;
  out[e] = w[e] * pf[ei[e]] * pf[ei[NEDGE + e]];
}

// ---------------------------------------------------------------------------
extern "C" void kernel_launch(void* const* d_in, const int* in_sizes, int n_in,
                              void* d_out, int out_size, void* d_ws, size_t ws_size,
                              hipStream_t stream) {
  (void)in_sizes; (void)n_in; (void)out_size; (void)ws_size;
  const float* x     = (const float*)d_in[0];
  const int*   ei    = (const int*)d_in[1];
  const float* ewts  = (const float*)d_in[2];
  const float* emb_w = (const float*)d_in[3];
  const float* emb_b = (const float*)d_in[4];
  const float* qkv_w = (const float*)d_in[5];
  const float* qkv_b = (const float*)d_in[6];
  const float* out_w = (const float*)d_in[7];
  const float* out_b = (const float*)d_in[8];
  const float* ln1_w = (const float*)d_in[9];
  const float* ln1_b = (const float*)d_in[10];
  const float* ln2_w = (const float*)d_in[11];
  const float* ln2_b = (const float*)d_in[12];
  const float* ff1_w = (const float*)d_in[13];
  const float* ff1_b = (const float*)d_in[14];
  const float* ff2_w = (const float*)d_in[15];
  const float* ff2_b = (const float*)d_in[16];
  const float* sc_w  = (const float*)d_in[17];
  const float* sc_b  = (const float*)d_in[18];
  float* out = (float*)d_out;

  const size_t MB = 1024 * 1024;
  char* base = (char*)d_ws;
  float*  h    = (float*)base;                       // [0,32)
  uint*   hP   = (uint*)(base + 32 * MB);            // [32,64) GN x 256 packed
  char*   R    = base + 64 * MB;                     // [64,224) multi-use
  // attn phase:
  uint*   qkvP = (uint*)R;                           // [64,160)  GN x 768 packed
  uint*   oP   = (uint*)(R + 96 * MB);               // [160,192) GN x 256 packed
  uint*   vtP  = (uint*)(R + 128 * MB);              // [192,224) packed V-transpose
  // FFN phase (qkvP/oP/vtP dead): DFF-sliced (r8 scheme)
  uint*   tP   = (uint*)R;                           // [64,192)  GN x 1024 packed
  float*  delta = (float*)(R + 128 * MB);            // [192,224) GN x 256 fp32
  // embed phase:
  ushort* x_hi = (ushort*)R;                         // [64,72)
  ushort* x_lo = (ushort*)(R + 8 * MB);              // [72,80)
  float*  probs = (float*)R;                         // final
  char* W = base + 224 * MB;
  size_t woff = 0;
  auto walloc = [&](size_t bytes) { char* r = W + woff; woff += (bytes + 255) & ~(size_t)255; return (ushort*)r; };
  ushort* we_hi = walloc(256 * 128 * 2);
  ushort* we_lo = walloc(256 * 128 * 2);
  ushort* wq_hi = walloc((size_t)LL * 768 * 256 * 2);
  ushort* wq_lo = walloc((size_t)LL * 768 * 256 * 2);
  ushort* wo_hi = walloc((size_t)LL * 256 * 256 * 2);
  ushort* wo_lo = walloc((size_t)LL * 256 * 256 * 2);
  ushort* w1_hi = walloc((size_t)LL * DFFN * 256 * 2);
  ushort* w1_lo = walloc((size_t)LL * DFFN * 256 * 2);
  ushort* w2_hi = walloc((size_t)LL * 256 * DFFN * 2);
  ushort* w2_lo = walloc((size_t)LL * 256 * DFFN * 2);
  float*  qbs   = (float*)walloc((size_t)LL * 768 * 4);  // scaled qkv bias

  auto split = [&](const float* src, ushort* hi, ushort* lo, size_t n) {
    int n4 = (int)(n / 4);
    split_kernel<<<(n4 + 255) / 256, 256, 0, stream>>>(src, hi, lo, n4);
  };
  split(x, x_hi, x_lo, (size_t)GN * DIN);
  split(emb_w, we_hi, we_lo, 256 * 128);
  // qkv weights with softmax scale folded into Q rows
  split_qkvw<<<((LL * 768 * 256 / 4) + 255) / 256, 256, 0, stream>>>(
      qkv_w, wq_hi, wq_lo, LL * 768 * 256 / 4);
  scale_qb<<<(LL * 768 + 255) / 256, 256, 0, stream>>>(qkv_b, qbs);
  split(out_w, wo_hi, wo_lo, (size_t)LL * 256 * 256);
  split(ff1_w, w1_hi, w1_lo, (size_t)LL * DFFN * 256);
  split(ff2_w, w2_hi, w2_lo, (size_t)LL * 256 * DFFN);

  // ---- embed: h = x @ emb_w^T + emb_b (fp32 h + PACKED hP) ----
  mm_split<128, 128, 1, false, false, false, false, true><<<dim3(EE / 128, GN / 128), 256, 0, stream>>>(
      x_hi, x_lo, we_hi, we_lo, emb_b, h, (ushort*)hP, nullptr, nullptr, nullptr,
      GN, EE, DIN, DIN, DIN);

  for (int l = 0; l < LL; ++l) {
    // qkv: PACKED A (hP) -> PACKED out + packed V-transpose scatter
    mm_split<128, 128, 0, false, true, false, true, true><<<dim3(768 / 128, GN / 128), 256, 0, stream>>>(
        (const ushort*)hP, nullptr, wq_hi + (size_t)l * 768 * 256, wq_lo + (size_t)l * 768 * 256,
        qbs + l * 768, nullptr, (ushort*)qkvP, nullptr, (ushort*)vtP, nullptr,
        GN, 768, EE, EE, EE);
    attn_mfma<<<dim3(8, 8, GG), 256, 0, stream>>>(qkvP, vtP, oP);
    // out-proj + residual + LN1 fused (K=256), packed A + packed h out
    mm_ln<<<GN / 32, 256, 0, stream>>>(
        oP, wo_hi + (size_t)l * 256 * 256, wo_lo + (size_t)l * 256 * 256,
        out_b + l * 256, ln1_w + l * EE, ln1_b + l * EE, h, hP, EE);
    // FFN DFF-sliced (r8): ff1 (PACKA h) -> packed t; ff2 (PACKA t) -> delta,
    // slice 1 accumulates. 512-block ff2 grids (r9's 256-block row-slice lost).
    for (int s = 0; s < 2; ++s) {
      mm_split<128, 128, 0, true, false, false, true, true><<<dim3(1024 / 128, GN / 128), 256, 0, stream>>>(
          (const ushort*)hP, nullptr,
          w1_hi + (size_t)l * DFFN * 256 + (size_t)s * 1024 * 256,
          w1_lo + (size_t)l * DFFN * 256 + (size_t)s * 1024 * 256,
          ff1_b + l * DFFN + s * 1024, nullptr, (ushort*)tP, nullptr, nullptr, nullptr,
          GN, 1024, EE, EE, EE);
      if (s == 0)
        mm_split<128, 128, 1, false, false, false, true, false><<<dim3(EE / 128, GN / 128), 256, 0, stream>>>(
            (const ushort*)tP, nullptr,
            w2_hi + (size_t)l * 256 * DFFN, w2_lo + (size_t)l * 256 * DFFN,
            ff2_b + l * 256, delta, nullptr, nullptr, nullptr, nullptr,
            GN, EE, 1024, 1024, DFFN);
      else
        mm_split<128, 128, 1, false, false, true, true, false><<<dim3(EE / 128, GN / 128), 256, 0, stream>>>(
            (const ushort*)tP, nullptr,
            w2_hi + (size_t)l * 256 * DFFN + 1024, w2_lo + (size_t)l * 256 * DFFN + 1024,
            ff2_b + l * 256, delta, nullptr, nullptr, nullptr, nullptr,
            GN, EE, 1024, 1024, DFFN);
    }
    ln_res_kernel<<<GN / 4, 256, 0, stream>>>(
        h, delta, ln2_w + l * EE, ln2_b + l * EE, hP);
  }

  score_kernel<<<GN / 4, 256, 0, stream>>>(h, sc_w, sc_b, probs);
  topk_kernel<<<GG, 256, 0, stream>>>(probs, out);
  edge_kernel<<<NEDGE / 256, 256, 0, stream>>>(ei, ewts, out);
}

// Round 11
// 1907.518 us; speedup vs baseline: 1.1443x; 1.0057x over previous
//
#include <hip/hip_runtime.h>
#include <cstdint>
#include <cstddef>

#define GN    32768
#define GG    64
#define NNODE 512
#define EE    256
#define LL    4
#define DFFN  2048
#define NHH   8
#define HD    32
#define NEDGE 524288
#define KSEL  128
#define DIN   128

typedef __attribute__((ext_vector_type(8))) short short8;
typedef __attribute__((ext_vector_type(4))) float floatx4;

// ---- bf16 helpers (RNE) ---------------------------------------------------
__device__ __forceinline__ unsigned short f2bf(float x) {
  unsigned u = __float_as_uint(x);
  u = (u + 0x7FFFu + ((u >> 16) & 1u)) >> 16;
  return (unsigned short)u;
}
__device__ __forceinline__ float bf2f(unsigned short u) {
  return __uint_as_float((unsigned)u << 16);
}
// trunc-split + hw pack: low16 = bf16(hi, exact), high16 = bf16(residual, RNE)
__device__ __forceinline__ unsigned tpack(float v) {
  unsigned hib = __float_as_uint(v) & 0xFFFF0000u;
  float hif = __uint_as_float(hib);
  unsigned pk;
  asm("v_cvt_pk_bf16_f32 %0, %1, %2" : "=v"(pk) : "v"(hif), "v"(v - hif));
  return pk;
}
// single bf16 RNE via hw cvt (1 VALU; low16 of result)
__device__ __forceinline__ unsigned short bf1(float v) {
  unsigned pk;
  asm("v_cvt_pk_bf16_f32 %0, %1, %2" : "=v"(pk) : "v"(v), "v"(0.0f));
  return (unsigned short)pk;
}
// unpack 8 packed uints (2x uint4) -> hi short8 + lo short8
__device__ __forceinline__ void unpk(uint4 a0, uint4 a1, short8& hi, short8& lo) {
  union { short8 s; unsigned u[4]; } H, L;
  H.u[0] = __builtin_amdgcn_perm(a0.y, a0.x, 0x05040100u);
  H.u[1] = __builtin_amdgcn_perm(a0.w, a0.z, 0x05040100u);
  H.u[2] = __builtin_amdgcn_perm(a1.y, a1.x, 0x05040100u);
  H.u[3] = __builtin_amdgcn_perm(a1.w, a1.z, 0x05040100u);
  L.u[0] = __builtin_amdgcn_perm(a0.y, a0.x, 0x07060302u);
  L.u[1] = __builtin_amdgcn_perm(a0.w, a0.z, 0x07060302u);
  L.u[2] = __builtin_amdgcn_perm(a1.y, a1.x, 0x07060302u);
  L.u[3] = __builtin_amdgcn_perm(a1.w, a1.z, 0x07060302u);
  hi = H.s; lo = L.s;
}

// async global->LDS, 16B per lane (LDS dst must be wave-uniform base + lane*16)
__device__ __forceinline__ void ld_lds16(const ushort* g, ushort* l) {
  __builtin_amdgcn_global_load_lds(
      (const __attribute__((address_space(1))) unsigned int*)g,
      (__attribute__((address_space(3))) unsigned int*)l, 16, 0, 0);
}

// ---------------------------------------------------------------------------
// split fp32 -> (hi, lo) bf16 pair, 4 elements/thread
// ---------------------------------------------------------------------------
__global__ __launch_bounds__(256) void split_kernel(const float* __restrict__ in,
                                                    ushort* __restrict__ hi,
                                                    ushort* __restrict__ lo, int n4) {
  int i = blockIdx.x * 256 + threadIdx.x;
  if (i >= n4) return;
  float4 v = ((const float4*)in)[i];
  ushort4 hv, lv;
  float t[4] = {v.x, v.y, v.z, v.w};
  unsigned short hb;
  hb = f2bf(t[0]); hv.x = hb; lv.x = f2bf(t[0] - bf2f(hb));
  hb = f2bf(t[1]); hv.y = hb; lv.y = f2bf(t[1] - bf2f(hb));
  hb = f2bf(t[2]); hv.z = hb; lv.z = f2bf(t[2] - bf2f(hb));
  hb = f2bf(t[3]); hv.w = hb; lv.w = f2bf(t[3] - bf2f(hb));
  ((ushort4*)hi)[i] = hv;
  ((ushort4*)lo)[i] = lv;
}

// ---------------------------------------------------------------------------
// qkv_w split with softmax scale folded into Q rows (rows 0..255 of each 768)
// — removes 16 per-tile VALU muls in attn (exact fp32 pre-mul, same rel prec).
// ---------------------------------------------------------------------------
__global__ __launch_bounds__(256) void split_qkvw(const float* __restrict__ in,
                                                  ushort* __restrict__ hi,
                                                  ushort* __restrict__ lo, int n4) {
  int i = blockIdx.x * 256 + threadIdx.x;
  if (i >= n4) return;
  float4 v = ((const float4*)in)[i];
  int row = (i >> 6) % 768;   // element i*4 / 256-per-row
  float sc = (row < 256) ? (0.17677669529663687f * 1.44269504088896340f) : 1.0f;
  float t[4] = {v.x * sc, v.y * sc, v.z * sc, v.w * sc};
  ushort4 hv, lv;
  unsigned short hb;
  hb = f2bf(t[0]); hv.x = hb; lv.x = f2bf(t[0] - bf2f(hb));
  hb = f2bf(t[1]); hv.y = hb; lv.y = f2bf(t[1] - bf2f(hb));
  hb = f2bf(t[2]); hv.z = hb; lv.z = f2bf(t[2] - bf2f(hb));
  hb = f2bf(t[3]); hv.w = hb; lv.w = f2bf(t[3] - bf2f(hb));
  ((ushort4*)hi)[i] = hv;
  ((ushort4*)lo)[i] = lv;
}

// qkv bias with Q entries scaled
__global__ __launch_bounds__(256) void scale_qb(const float* __restrict__ qb,
                                                float* __restrict__ outb) {
  int i = blockIdx.x * 256 + threadIdx.x;
  if (i >= LL * 768) return;
  float sc = ((i % 768) < 256) ? (0.17677669529663687f * 1.44269504088896340f) : 1.0f;
  outb[i] = qb[i] * sc;
}

// ---------------------------------------------------------------------------
// Split-bf16 MFMA GEMM: C[M,N] = split(A)[M,K] @ split(B)[N,K]^T (+bias / +=C)
// XOR-swizzled LDS; XCD-chunked block swizzle (r1, FETCH 111->30 MB);
// double-buffered K-loop (r3).
// MODE bit0: fp32 C; bit1: split bf16 C (dual 2B arrays).
// PACKA: A is packed uint (hi|lo<<16), lda in uints.
// PACKC: C written packed uint (tpack) -> full 64B lines. PACKC+VT: packed
//   V-transpose scatter (4B). MODE&1 and PACKC compose (embed writes both).
// r5/r7 lesson: do NOT fuse FFN at BM=32 (L2-BW-bound on weights).
// r9 lesson: do NOT row-slice FFN (ff2 grid 256 blocks = 1/CU, -230us).
// ---------------------------------------------------------------------------
template <int BM, int BN, int MODE, bool RELU, bool VT, bool ACC,
          bool PACKA = false, bool PACKC = false>
__global__ __launch_bounds__(256) void mm_split(
    const ushort* __restrict__ a_hi, const ushort* __restrict__ a_lo,
    const ushort* __restrict__ b_hi, const ushort* __restrict__ b_lo,
    const float* __restrict__ bias,
    float* __restrict__ Cf, ushort* __restrict__ c_hi, ushort* __restrict__ c_lo,
    ushort* __restrict__ vth, ushort* __restrict__ vtl,
    int M, int N, int K, int lda, int ldb) {
  constexpr int MI = BM / 32;
  constexpr int NJ = BN / 32;
  __shared__ ushort As[2][2][BM * 32];   // [dbuf][hi/lo] (PACKA: packed uints)
  __shared__ ushort Bs[2][2][BN * 32];
  const int tid = threadIdx.x;
  const int w = tid >> 6, lane = tid & 63;
  const int wm = (w >> 1) * (BM / 2), wn = (w & 1) * (BN / 2);

  const int nwg = gridDim.x * gridDim.y;
  int flat = blockIdx.x + gridDim.x * blockIdx.y;
  int bnb, bmb;
  if ((nwg & 7) == 0) {
    int v = (flat & 7) * (nwg >> 3) + (flat >> 3);
    bnb = v % gridDim.x;
    bmb = v / gridDim.x;
  } else {
    bnb = blockIdx.x;
    bmb = blockIdx.y;
  }
  const int bm = bmb * BM, bn = bnb * BN;
  const int lrow = lane & 15, lquad = lane >> 4;

  floatx4 acc[MI][NJ];
  floatx4 zz = {0.f, 0.f, 0.f, 0.f};
#pragma unroll
  for (int i = 0; i < MI; ++i)
#pragma unroll
    for (int j = 0; j < NJ; ++j) acc[i][j] = zz;

  const uint* aP = (const uint*)a_hi;     // PACKA view
  const int arow = tid >> 2;
  const int acol = (((tid & 3) ^ ((arow >> 1) & 3)) << 3);  // swizzled source col
  const ushort* pah = a_hi + (size_t)(bm + arow) * lda + acol;
  const ushort* pal = a_lo + (size_t)(bm + arow) * lda + acol;
  const ushort* pbh = b_hi + (size_t)(bn + arow) * ldb + acol;
  const ushort* pbl = b_lo + (size_t)(bn + arow) * ldb + acol;

  auto stage = [&](int p, int k0) {
    if constexpr (PACKA) {
      // packed rows: 32 uints (128B) per k-step; 8 threads/row, 16B each,
      // 16B-group XOR (row&7) -> frag reads spread over 8 slots (2-way, free)
#pragma unroll
      for (int s = 0; s < BM / 32; ++s) {
        int row = s * 32 + (tid >> 3);
        int gp = tid & 7;
        const uint* src = aP + (size_t)(bm + row) * lda + k0 + ((gp ^ (row & 7)) << 2);
        ld_lds16((const ushort*)src,
                 (ushort*)((char*)&As[p][0][0] + s * 4096 + tid * 16));
      }
    } else {
#pragma unroll
      for (int s = 0; s < BM / 64; ++s) {
        ld_lds16(pah + (size_t)s * 64 * lda + k0, &As[p][0][s * 2048 + tid * 8]);
        ld_lds16(pal + (size_t)s * 64 * lda + k0, &As[p][1][s * 2048 + tid * 8]);
      }
    }
#pragma unroll
    for (int s = 0; s < BN / 64; ++s) {
      ld_lds16(pbh + (size_t)s * 64 * ldb + k0, &Bs[p][0][s * 2048 + tid * 8]);
      ld_lds16(pbl + (size_t)s * 64 * ldb + k0, &Bs[p][1][s * 2048 + tid * 8]);
    }
  };

  stage(0, 0);
  const int nk = K >> 5;
  for (int t = 0; t < nk; ++t) {
    const int p = t & 1;
    __syncthreads();                 // stage(p) landed; prev readers of p^1 done
    if (t + 1 < nk) stage(p ^ 1, (t + 1) << 5);  // async under compute(t)
    short8 ah[MI], al[MI], bh[NJ], bl[NJ];
    if constexpr (PACKA) {
      const uint* Ap = (const uint*)&As[p][0][0];
#pragma unroll
      for (int i = 0; i < MI; ++i) {
        int rr = wm + i * 16 + lrow;
        const uint* rb = Ap + rr * 32;
        uint4 a0 = *(const uint4*)(rb + (((lquad * 2) ^ (rr & 7)) << 2));
        uint4 a1 = *(const uint4*)(rb + (((lquad * 2 + 1) ^ (rr & 7)) << 2));
        unpk(a0, a1, ah[i], al[i]);
      }
    } else {
#pragma unroll
      for (int i = 0; i < MI; ++i) {
        int rr = wm + i * 16 + lrow;
        int r = rr * 32 + ((lquad ^ ((rr >> 1) & 3)) << 3);
        ah[i] = *(const short8*)&As[p][0][r];
        al[i] = *(const short8*)&As[p][1][r];
      }
    }
#pragma unroll
    for (int j = 0; j < NJ; ++j) {
      int rr = wn + j * 16 + lrow;
      int r = rr * 32 + ((lquad ^ ((rr >> 1) & 3)) << 3);
      bh[j] = *(const short8*)&Bs[p][0][r];
      bl[j] = *(const short8*)&Bs[p][1][r];
    }
#pragma unroll
    for (int i = 0; i < MI; ++i)
#pragma unroll
      for (int j = 0; j < NJ; ++j) {
        acc[i][j] = __builtin_amdgcn_mfma_f32_16x16x32_bf16(al[i], bh[j], acc[i][j], 0, 0, 0);
        acc[i][j] = __builtin_amdgcn_mfma_f32_16x16x32_bf16(ah[i], bl[j], acc[i][j], 0, 0, 0);
        acc[i][j] = __builtin_amdgcn_mfma_f32_16x16x32_bf16(ah[i], bh[j], acc[i][j], 0, 0, 0);
      }
  }

#pragma unroll
  for (int j = 0; j < NJ; ++j) {
    int col = bn + wn + j * 16 + lrow;
    float bj = ACC ? 0.0f : bias[col];
#pragma unroll
    for (int i = 0; i < MI; ++i) {
      int row0 = bm + wm + i * 16 + lquad * 4;
#pragma unroll
      for (int r = 0; r < 4; ++r) {
        size_t off = (size_t)(row0 + r) * N + col;
        float v = acc[i][j][r] + bj;
        if constexpr (ACC) v += Cf[off];
        if (RELU) v = fmaxf(v, 0.0f);
        if constexpr (MODE & 1) Cf[off] = v;
        if constexpr (PACKC) {
          unsigned pk = tpack(v);
          ((uint*)c_hi)[off] = pk;            // low16=hi, high16=lo
          if constexpr (VT) {
            if (col >= 512) {
              int hd = col - 512;
              int row = row0 + r;
              size_t vo = ((size_t)((row >> 9) * 8 + (hd >> 5)) * 32 + (hd & 31)) * 512 + (row & 511);
              ((uint*)vth)[vo] = pk;          // packed V-transpose scatter (4B)
            }
          }
        } else if constexpr (MODE & 2) {
          unsigned short hb = f2bf(v);
          unsigned short lb = f2bf(v - bf2f(hb));
          c_hi[off] = hb;
          c_lo[off] = lb;
          if constexpr (VT) {
            if (col >= 512) {
              int hd = col - 512;
              int row = row0 + r;
              size_t vo = ((size_t)((row >> 9) * 8 + (hd >> 5)) * 32 + (hd & 31)) * 512 + (row & 511);
              vth[vo] = hb;
              vtl[vo] = lb;
            }
          }
        }
      }
    }
  }
}

// ---------------------------------------------------------------------------
// Split GEMM + bias + residual + LayerNorm fused epilogue (BM=32; K=256
// out-proj only). A input = PACKED attn output; h output = PACKED hP
// (full-64B-line 4B stores; dual-2B stores measured 1.45x write amplif.).
// ---------------------------------------------------------------------------
__global__ __launch_bounds__(256) void mm_ln(
    const uint* __restrict__ oP,
    const ushort* __restrict__ b_hi, const ushort* __restrict__ b_lo,
    const float* __restrict__ bias, const float* __restrict__ lnw,
    const float* __restrict__ lnb, float* __restrict__ hbuf,
    uint* __restrict__ hP, int K) {
  __shared__ uint AsP[32 * 32];          // packed A chunk (4KB)
  __shared__ ushort Bs[2][256 * 32];
  __shared__ float rsum[32], rsq[32], muA[32], rsA[32];
  const int tid = threadIdx.x;
  const int w = tid >> 6, lane = tid & 63;
  const int wn = w * 64;
  const int bm = blockIdx.x * 32;
  const int lr = lane & 15, quad = lane >> 4;

  floatx4 acc[2][4];
  floatx4 zz = {0.f, 0.f, 0.f, 0.f};
#pragma unroll
  for (int i = 0; i < 2; ++i)
#pragma unroll
    for (int j = 0; j < 4; ++j) acc[i][j] = zz;

  if (tid < 32) { rsum[tid] = 0.f; rsq[tid] = 0.f; }

  const int brow = tid >> 2;
  const int bcol = (((tid & 3) ^ ((brow >> 1) & 3)) << 3);

  for (int k0 = 0; k0 < K; k0 += 32) {
    __syncthreads();
    {
      int row = tid >> 3, gp = tid & 7;
      const uint* src = oP + (size_t)(bm + row) * 256 + k0 + ((gp ^ (row & 7)) << 2);
      ld_lds16((const ushort*)src, (ushort*)((char*)AsP + tid * 16));
    }
#pragma unroll
    for (int s = 0; s < 4; ++s) {
      ld_lds16(b_hi + (size_t)(s * 64 + brow) * K + bcol + k0, &Bs[0][s * 2048 + tid * 8]);
      ld_lds16(b_lo + (size_t)(s * 64 + brow) * K + bcol + k0, &Bs[1][s * 2048 + tid * 8]);
    }
    __syncthreads();
    short8 ah[2], al[2], bh[4], bl[4];
#pragma unroll
    for (int i = 0; i < 2; ++i) {
      int rr = i * 16 + lr;
      const uint* rb = AsP + rr * 32;
      uint4 a0 = *(const uint4*)(rb + (((quad * 2) ^ (rr & 7)) << 2));
      uint4 a1 = *(const uint4*)(rb + (((quad * 2 + 1) ^ (rr & 7)) << 2));
      unpk(a0, a1, ah[i], al[i]);
    }
#pragma unroll
    for (int j = 0; j < 4; ++j) {
      int rr = wn + j * 16 + lr;
      int r = rr * 32 + ((quad ^ ((rr >> 1) & 3)) << 3);
      bh[j] = *(const short8*)&Bs[0][r];
      bl[j] = *(const short8*)&Bs[1][r];
    }
#pragma unroll
    for (int i = 0; i < 2; ++i)
#pragma unroll
      for (int j = 0; j < 4; ++j) {
        acc[i][j] = __builtin_amdgcn_mfma_f32_16x16x32_bf16(al[i], bh[j], acc[i][j], 0, 0, 0);
        acc[i][j] = __builtin_amdgcn_mfma_f32_16x16x32_bf16(ah[i], bl[j], acc[i][j], 0, 0, 0);
        acc[i][j] = __builtin_amdgcn_mfma_f32_16x16x32_bf16(ah[i], bh[j], acc[i][j], 0, 0, 0);
      }
  }

  // ---- epilogue: v = acc + bias + residual; row LN; write h + packed ----
#pragma unroll
  for (int i = 0; i < 2; ++i) {
#pragma unroll
    for (int r = 0; r < 4; ++r) {
      int ridx = i * 16 + quad * 4 + r;
      float sp = 0.f, qp = 0.f;
#pragma unroll
      for (int j = 0; j < 4; ++j) {
        int col = wn + j * 16 + lr;
        float v = acc[i][j][r] + bias[col] + hbuf[(size_t)(bm + ridx) * EE + col];
        acc[i][j][r] = v;
        sp += v;
        qp += v * v;
      }
#pragma unroll
      for (int m = 1; m < 16; m <<= 1) { sp += __shfl_xor(sp, m); qp += __shfl_xor(qp, m); }
      if (lr == 0) { atomicAdd(&rsum[ridx], sp); atomicAdd(&rsq[ridx], qp); }
    }
  }
  __syncthreads();
  if (tid < 32) {
    float mu = rsum[tid] * (1.0f / 256.0f);
    float var = rsq[tid] * (1.0f / 256.0f) - mu * mu;
    muA[tid] = mu;
    rsA[tid] = 1.0f / sqrtf(var + 1e-5f);
  }
  __syncthreads();
#pragma unroll
  for (int i = 0; i < 2; ++i) {
#pragma unroll
    for (int r = 0; r < 4; ++r) {
      int ridx = i * 16 + quad * 4 + r;
      float mu = muA[ridx], rsv = rsA[ridx];
#pragma unroll
      for (int j = 0; j < 4; ++j) {
        int col = wn + j * 16 + lr;
        float o = (acc[i][j][r] - mu) * rsv * lnw[col] + lnb[col];
        size_t off = (size_t)(bm + ridx) * EE + col;
        hbuf[off] = o;
        hP[off] = tpack(o);
      }
    }
  }
}

// ---------------------------------------------------------------------------
// h = LN(h + t)*w + b ; writes fp32 h + PACKED hP. One wave per row.
// ---------------------------------------------------------------------------
__global__ __launch_bounds__(256) void ln_res_kernel(float* __restrict__ h,
                                                     const float* __restrict__ t,
                                                     const float* __restrict__ w,
                                                     const float* __restrict__ b,
                                                     uint* __restrict__ hP) {
  int row = blockIdx.x * 4 + (threadIdx.x >> 6);
  int lane = threadIdx.x & 63;
  size_t off = (size_t)row * EE + (lane << 2);
  float4 hv = *(const float4*)&h[off];
  float4 tv = *(const float4*)&t[off];
  float v0 = hv.x + tv.x, v1 = hv.y + tv.y, v2 = hv.z + tv.z, v3 = hv.w + tv.w;
  float s = (v0 + v1) + (v2 + v3);
#pragma unroll
  for (int m = 32; m > 0; m >>= 1) s += __shfl_xor(s, m);
  float mu = s * (1.0f / 256.0f);
  float d0 = v0 - mu, d1 = v1 - mu, d2 = v2 - mu, d3 = v3 - mu;
  float s2 = (d0 * d0 + d1 * d1) + (d2 * d2 + d3 * d3);
#pragma unroll
  for (int m = 32; m > 0; m >>= 1) s2 += __shfl_xor(s2, m);
  float rs = 1.0f / sqrtf(s2 * (1.0f / 256.0f) + 1e-5f);
  float4 wv = *(const float4*)&w[lane << 2];
  float4 bv = *(const float4*)&b[lane << 2];
  float4 o;
  o.x = d0 * rs * wv.x + bv.x;
  o.y = d1 * rs * wv.y + bv.y;
  o.z = d2 * rs * wv.z + bv.z;
  o.w = d3 * rs * wv.w + bv.w;
  *(float4*)&h[off] = o;
  uint4 pk;
  pk.x = tpack(o.x);
  pk.y = tpack(o.y);
  pk.z = tpack(o.z);
  pk.w = tpack(o.w);
  *(uint4*)&hP[off] = pk;
}

// ---------------------------------------------------------------------------
// MFMA flash attention — r7 structure + VALU diet + XCD-chunked grid swizzle
// + packed qkv/vt input + packed o output + Q-scale pre-fold (r8/r9).
// r11: P stored as SINGLE bf16 (self-consistent softmax: O = sum(P^)V/sum(P^)
// is an exact softmax of 2^-9-perturbed weights -> error ~2e-4). Kills the
// tpack (48->16 VALU), the PV unpack (16 perms -> 0), and 6 MFMA/tile;
// LDS 36.9 -> 28.7 KB = 5 blocks/CU.
// Do NOT: hoist S across m-tiles, chunk softmax <128 keys, 2 m-tiles/block,
// (gh,qt) grid — all measured regressions.
// ---------------------------------------------------------------------------
__global__ __launch_bounds__(256) void attn_mfma(const uint* __restrict__ qP,
                                                 const uint* __restrict__ vtP,
                                                 uint* __restrict__ oP) {
  __shared__ ushort Ks[2][64 * 40];
  __shared__ ushort Vt[2][32 * 72];
  __shared__ ushort Ps[4][16 * 72];   // single-bf16 P (9 KB)
  const int tid = threadIdx.x;
  const int w = tid >> 6, lane = tid & 63, c = lane & 15, quad = lane >> 4;
  int flat = blockIdx.x + 8 * (blockIdx.y + 8 * blockIdx.z);
  int v = (flat & 7) * ((GG * 64) >> 3) + (flat >> 3);
  const int qt = v & 7, hh = (v >> 3) & 7, g = v >> 6;
  const size_t g512 = (size_t)g * 512;
  const size_t vtbase = (size_t)(g * 8 + hh) * 32 * 512;

  const size_t qnode = g512 + qt * 64 + w * 16 + c;
  const uint* qp0 = qP + qnode * 768 + hh * 32 + quad * 8;
  uint4 q0 = *(const uint4*)qp0, q1 = *(const uint4*)(qp0 + 4);
  short8 qfh, qfl;
  unpk(q0, q1, qfh, qfl);

  floatx4 O0 = {0.f, 0.f, 0.f, 0.f}, O1 = {0.f, 0.f, 0.f, 0.f};
  floatx4 Lac = {0.f, 0.f, 0.f, 0.f};
  const short onev = (short)0x3F80;  // bf16 1.0
  const short8 onef = {onev, onev, onev, onev, onev, onev, onev, onev};

  const int skey = tid >> 2, sdc = (tid & 3) << 3;
  const int sd = tid >> 3, skc = (tid & 7) << 3;
  uint4 stg[4];
  auto load_tile = [&](int kb) {
    size_t go = (g512 + kb + skey) * 768 + 256 + hh * 32 + sdc;
    stg[0] = *(const uint4*)(qP + go);
    stg[1] = *(const uint4*)(qP + go + 4);
    size_t vo = vtbase + (size_t)sd * 512 + kb + skc;
    stg[2] = *(const uint4*)(vtP + vo);
    stg[3] = *(const uint4*)(vtP + vo + 4);
  };
  load_tile(0);

  for (int t = 0; t < 8; ++t) {
    if (t) __syncthreads();
    {
      short8 kh, kl, vh, vl;
      unpk(stg[0], stg[1], kh, kl);
      unpk(stg[2], stg[3], vh, vl);
      *(short8*)&Ks[0][skey * 40 + sdc] = kh;
      *(short8*)&Ks[1][skey * 40 + sdc] = kl;
      *(short8*)&Vt[0][sd * 72 + skc] = vh;
      *(short8*)&Vt[1][sd * 72 + skc] = vl;
    }
    __syncthreads();
    if (t < 7) load_tile((t + 1) * 64);

    // ---- S = Q K^T : 4 n-tiles of 16x16 (Q pre-scaled at split) ----
    floatx4 S[4];
#pragma unroll
    for (int n = 0; n < 4; ++n) {
      int r = (n * 16 + c) * 40 + quad * 8;
      short8 kfh = *(const short8*)&Ks[0][r];
      short8 kfl = *(const short8*)&Ks[1][r];
      floatx4 s = {0.f, 0.f, 0.f, 0.f};
      s = __builtin_amdgcn_mfma_f32_16x16x32_bf16(qfh, kfl, s, 0, 0, 0);
      s = __builtin_amdgcn_mfma_f32_16x16x32_bf16(qfl, kfh, s, 0, 0, 0);
      s = __builtin_amdgcn_mfma_f32_16x16x32_bf16(qfh, kfh, s, 0, 0, 0);
      S[n] = s;
    }
    // ---- softmax numerator: P = bf16(exp2(S)), single precision ----
#pragma unroll
    for (int n = 0; n < 4; ++n) {
#pragma unroll
      for (int r = 0; r < 4; ++r) {
        float pp = exp2f(S[n][r]);
        Ps[w][(quad * 4 + r) * 72 + n * 16 + c] = bf1(pp);
      }
    }
    // ---- PV: O += P @ (Vh+Vl) ; l += P @ 1 (2 d-tiles x 2 k-steps) ----
#pragma unroll
    for (int ks = 0; ks < 2; ++ks) {
      short8 p = *(const short8*)&Ps[w][c * 72 + ks * 32 + quad * 8];
      int r0 = c * 72 + ks * 32 + quad * 8;
      int r1 = (16 + c) * 72 + ks * 32 + quad * 8;
      short8 v0h = *(const short8*)&Vt[0][r0];
      short8 v0l = *(const short8*)&Vt[1][r0];
      short8 v1h = *(const short8*)&Vt[0][r1];
      short8 v1l = *(const short8*)&Vt[1][r1];
      O0 = __builtin_amdgcn_mfma_f32_16x16x32_bf16(p, v0l, O0, 0, 0, 0);
      O0 = __builtin_amdgcn_mfma_f32_16x16x32_bf16(p, v0h, O0, 0, 0, 0);
      O1 = __builtin_amdgcn_mfma_f32_16x16x32_bf16(p, v1l, O1, 0, 0, 0);
      O1 = __builtin_amdgcn_mfma_f32_16x16x32_bf16(p, v1h, O1, 0, 0, 0);
      Lac = __builtin_amdgcn_mfma_f32_16x16x32_bf16(p, onef, Lac, 0, 0, 0);
    }
  }

  // ---- epilogue: normalize, pack, store (full 64B lines) ----
#pragma unroll
  for (int r = 0; r < 4; ++r) {
    float inv = 1.0f / Lac[r];
    size_t node = g512 + qt * 64 + w * 16 + quad * 4 + r;
    size_t off0 = node * EE + hh * 32 + c;
    oP[off0] = tpack(O0[r] * inv);
    oP[off0 + 16] = tpack(O1[r] * inv);
  }
}

// ---------------------------------------------------------------------------
__global__ __launch_bounds__(256) void score_kernel(const float* __restrict__ h,
                                                    const float* __restrict__ sw,
                                                    const float* __restrict__ sb,
                                                    float* __restrict__ probs) {
  int row = blockIdx.x * 4 + (threadIdx.x >> 6);
  int lane = threadIdx.x & 63;
  float4 a = *(const float4*)&h[(size_t)row * EE + (lane << 2)];
  float4 w = *(const float4*)&sw[lane << 2];
  float s = (a.x * w.x + a.y * w.y) + (a.z * w.z + a.w * w.w);
#pragma unroll
  for (int m = 32; m > 0; m >>= 1) s += __shfl_xor(s, m);
  if (lane == 0) {
    float sc = s + sb[0];
    probs[row] = 1.0f / (1.0f + expf(-sc));
  }
}

// ---------------------------------------------------------------------------
// Per-graph exact top-k with jax.lax.top_k tie semantics (lower index wins).
// ---------------------------------------------------------------------------
__global__ __launch_bounds__(256) void topk_kernel(const float* __restrict__ probs,
                                                   float* __restrict__ out) {
  __shared__ unsigned long long keys[NNODE];
  __shared__ float pv[NNODE];
  __shared__ int flags[NNODE];
  __shared__ int sc[NNODE];
  const int g = blockIdx.x, tid = threadIdx.x;
  for (int i = tid; i < NNODE; i += 256) {
    float p = probs[g * NNODE + i];
    pv[i] = p;
    keys[i] = ((unsigned long long)__float_as_uint(p) << 32) |
              (unsigned long long)(~(unsigned)i);
    flags[i] = 0;
  }
  for (int k = 2; k <= NNODE; k <<= 1) {
    for (int j = k >> 1; j > 0; j >>= 1) {
      __syncthreads();
      for (int i = tid; i < NNODE; i += 256) {
        int ixj = i ^ j;
        if (ixj > i) {
          unsigned long long a = keys[i], bq = keys[ixj];
          bool desc = ((i & k) == 0);
          bool sw = desc ? (a < bq) : (a > bq);
          if (sw) { keys[i] = bq; keys[ixj] = a; }
        }
      }
    }
  }
  __syncthreads();
  if (tid < KSEL) {
    unsigned idx = ~(unsigned)(keys[tid] & 0xFFFFFFFFull);
    flags[idx] = 1;
  }
  __syncthreads();
  sc[tid] = flags[tid];
  sc[tid + 256] = flags[tid + 256];
  for (int off = 1; off < NNODE; off <<= 1) {
    __syncthreads();
    int x0 = (tid >= off) ? sc[tid - off] : 0;
    int x1 = sc[tid + 256 - off];
    int b0 = sc[tid], b1 = sc[tid + 256];
    __syncthreads();
    sc[tid] = b0 + x0;
    sc[tid + 256] = b1 + x1;
  }
  __syncthreads();
  for (int i = tid; i < NNODE; i += 256) {
    float p = pv[i];
    int f = flags[i];
    float ind = ((float)f - p) + p;
    float pf = p * ind;
    out[NEDGE + GG * KSEL + g * NNODE + i] = pf;
    if (f) out[NEDGE + g * KSEL + (sc[i] - 1)] = (float)(g * NNODE + i);
  }
}

// ---------------------------------------------------------------------------
__global__ __launch_bounds__(256) void edge_kernel(const int* __restrict__ ei,
                                                   const float* __restrict__ w,
                                                   float* __restrict__ out) {
  int e = blockIdx.x * 256 + threadIdx.x;
  const float* pf = out + NEDGE + GG * KSEL;
  out[e] = w[e] * pf[ei[e]] * pf[ei[NEDGE + e]];
}

// ---------------------------------------------------------------------------
extern "C" void kernel_launch(void* const* d_in, const int* in_sizes, int n_in,
                              void* d_out, int out_size, void* d_ws, size_t ws_size,
                              hipStream_t stream) {
  (void)in_sizes; (void)n_in; (void)out_size; (void)ws_size;
  const float* x     = (const float*)d_in[0];
  const int*   ei    = (const int*)d_in[1];
  const float* ewts  = (const float*)d_in[2];
  const float* emb_w = (const float*)d_in[3];
  const float* emb_b = (const float*)d_in[4];
  const float* qkv_w = (const float*)d_in[5];
  const float* qkv_b = (const float*)d_in[6];
  const float* out_w = (const float*)d_in[7];
  const float* out_b = (const float*)d_in[8];
  const float* ln1_w = (const float*)d_in[9];
  const float* ln1_b = (const float*)d_in[10];
  const float* ln2_w = (const float*)d_in[11];
  const float* ln2_b = (const float*)d_in[12];
  const float* ff1_w = (const float*)d_in[13];
  const float* ff1_b = (const float*)d_in[14];
  const float* ff2_w = (const float*)d_in[15];
  const float* ff2_b = (const float*)d_in[16];
  const float* sc_w  = (const float*)d_in[17];
  const float* sc_b  = (const float*)d_in[18];
  float* out = (float*)d_out;

  const size_t MB = 1024 * 1024;
  char* base = (char*)d_ws;
  float*  h    = (float*)base;                       // [0,32)
  uint*   hP   = (uint*)(base + 32 * MB);            // [32,64) GN x 256 packed
  char*   R    = base + 64 * MB;                     // [64,224) multi-use
  // attn phase:
  uint*   qkvP = (uint*)R;                           // [64,160)  GN x 768 packed
  uint*   oP   = (uint*)(R + 96 * MB);               // [160,192) GN x 256 packed
  uint*   vtP  = (uint*)(R + 128 * MB);              // [192,224) packed V-transpose
  // FFN phase (qkvP/oP/vtP dead): DFF-sliced (r8 scheme)
  uint*   tP   = (uint*)R;                           // [64,192)  GN x 1024 packed
  float*  delta = (float*)(R + 128 * MB);            // [192,224) GN x 256 fp32
  // embed phase:
  ushort* x_hi = (ushort*)R;                         // [64,72)
  ushort* x_lo = (ushort*)(R + 8 * MB);              // [72,80)
  float*  probs = (float*)R;                         // final
  char* W = base + 224 * MB;
  size_t woff = 0;
  auto walloc = [&](size_t bytes) { char* r = W + woff; woff += (bytes + 255) & ~(size_t)255; return (ushort*)r; };
  ushort* we_hi = walloc(256 * 128 * 2);
  ushort* we_lo = walloc(256 * 128 * 2);
  ushort* wq_hi = walloc((size_t)LL * 768 * 256 * 2);
  ushort* wq_lo = walloc((size_t)LL * 768 * 256 * 2);
  ushort* wo_hi = walloc((size_t)LL * 256 * 256 * 2);
  ushort* wo_lo = walloc((size_t)LL * 256 * 256 * 2);
  ushort* w1_hi = walloc((size_t)LL * DFFN * 256 * 2);
  ushort* w1_lo = walloc((size_t)LL * DFFN * 256 * 2);
  ushort* w2_hi = walloc((size_t)LL * 256 * DFFN * 2);
  ushort* w2_lo = walloc((size_t)LL * 256 * DFFN * 2);
  float*  qbs   = (float*)walloc((size_t)LL * 768 * 4);  // scaled qkv bias

  auto split = [&](const float* src, ushort* hi, ushort* lo, size_t n) {
    int n4 = (int)(n / 4);
    split_kernel<<<(n4 + 255) / 256, 256, 0, stream>>>(src, hi, lo, n4);
  };
  split(x, x_hi, x_lo, (size_t)GN * DIN);
  split(emb_w, we_hi, we_lo, 256 * 128);
  // qkv weights with softmax scale folded into Q rows
  split_qkvw<<<((LL * 768 * 256 / 4) + 255) / 256, 256, 0, stream>>>(
      qkv_w, wq_hi, wq_lo, LL * 768 * 256 / 4);
  scale_qb<<<(LL * 768 + 255) / 256, 256, 0, stream>>>(qkv_b, qbs);
  split(out_w, wo_hi, wo_lo, (size_t)LL * 256 * 256);
  split(ff1_w, w1_hi, w1_lo, (size_t)LL * DFFN * 256);
  split(ff2_w, w2_hi, w2_lo, (size_t)LL * 256 * DFFN);

  // ---- embed: h = x @ emb_w^T + emb_b (fp32 h + PACKED hP) ----
  mm_split<128, 128, 1, false, false, false, false, true><<<dim3(EE / 128, GN / 128), 256, 0, stream>>>(
      x_hi, x_lo, we_hi, we_lo, emb_b, h, (ushort*)hP, nullptr, nullptr, nullptr,
      GN, EE, DIN, DIN, DIN);

  for (int l = 0; l < LL; ++l) {
    // qkv: PACKED A (hP) -> PACKED out + packed V-transpose scatter
    mm_split<128, 128, 0, false, true, false, true, true><<<dim3(768 / 128, GN / 128), 256, 0, stream>>>(
        (const ushort*)hP, nullptr, wq_hi + (size_t)l * 768 * 256, wq_lo + (size_t)l * 768 * 256,
        qbs + l * 768, nullptr, (ushort*)qkvP, nullptr, (ushort*)vtP, nullptr,
        GN, 768, EE, EE, EE);
    attn_mfma<<<dim3(8, 8, GG), 256, 0, stream>>>(qkvP, vtP, oP);
    // out-proj + residual + LN1 fused (K=256), packed A + packed h out
    mm_ln<<<GN / 32, 256, 0, stream>>>(
        oP, wo_hi + (size_t)l * 256 * 256, wo_lo + (size_t)l * 256 * 256,
        out_b + l * 256, ln1_w + l * EE, ln1_b + l * EE, h, hP, EE);
    // FFN DFF-sliced (r8): ff1 (PACKA h) -> packed t; ff2 (PACKA t) -> delta,
    // slice 1 accumulates. 512-block ff2 grids (r9's 256-block row-slice lost).
    for (int s = 0; s < 2; ++s) {
      mm_split<128, 128, 0, true, false, false, true, true><<<dim3(1024 / 128, GN / 128), 256, 0, stream>>>(
          (const ushort*)hP, nullptr,
          w1_hi + (size_t)l * DFFN * 256 + (size_t)s * 1024 * 256,
          w1_lo + (size_t)l * DFFN * 256 + (size_t)s * 1024 * 256,
          ff1_b + l * DFFN + s * 1024, nullptr, (ushort*)tP, nullptr, nullptr, nullptr,
          GN, 1024, EE, EE, EE);
      if (s == 0)
        mm_split<128, 128, 1, false, false, false, true, false><<<dim3(EE / 128, GN / 128), 256, 0, stream>>>(
            (const ushort*)tP, nullptr,
            w2_hi + (size_t)l * 256 * DFFN, w2_lo + (size_t)l * 256 * DFFN,
            ff2_b + l * 256, delta, nullptr, nullptr, nullptr, nullptr,
            GN, EE, 1024, 1024, DFFN);
      else
        mm_split<128, 128, 1, false, false, true, true, false><<<dim3(EE / 128, GN / 128), 256, 0, stream>>>(
            (const ushort*)tP, nullptr,
            w2_hi + (size_t)l * 256 * DFFN + 1024, w2_lo + (size_t)l * 256 * DFFN + 1024,
            ff2_b + l * 256, delta, nullptr, nullptr, nullptr, nullptr,
            GN, EE, 1024, 1024, DFFN);
    }
    ln_res_kernel<<<GN / 4, 256, 0, stream>>>(
        h, delta, ln2_w + l * EE, ln2_b + l * EE, hP);
  }

  score_kernel<<<GN / 4, 256, 0, stream>>>(h, sc_w, sc_b, probs);
  topk_kernel<<<GG, 256, 0, stream>>>(probs, out);
  edge_kernel<<<NEDGE / 256, 256, 0, stream>>>(ei, ewts, out);
}

// Round 12
// 1729.888 us; speedup vs baseline: 1.2619x; 1.1027x over previous
//
#include <hip/hip_runtime.h>
#include <cstdint>
#include <cstddef>

#define GN    32768
#define GG    64
#define NNODE 512
#define EE    256
#define LL    4
#define DFFN  2048
#define NHH   8
#define HD    32
#define NEDGE 524288
#define KSEL  128
#define DIN   128

typedef __attribute__((ext_vector_type(8))) short short8;
typedef __attribute__((ext_vector_type(4))) float floatx4;

// ---- bf16 helpers (RNE) ---------------------------------------------------
__device__ __forceinline__ unsigned short f2bf(float x) {
  unsigned u = __float_as_uint(x);
  u = (u + 0x7FFFu + ((u >> 16) & 1u)) >> 16;
  return (unsigned short)u;
}
__device__ __forceinline__ float bf2f(unsigned short u) {
  return __uint_as_float((unsigned)u << 16);
}
// trunc-split + hw pack: low16 = bf16(hi, exact), high16 = bf16(residual, RNE)
__device__ __forceinline__ unsigned tpack(float v) {
  unsigned hib = __float_as_uint(v) & 0xFFFF0000u;
  float hif = __uint_as_float(hib);
  unsigned pk;
  asm("v_cvt_pk_bf16_f32 %0, %1, %2" : "=v"(pk) : "v"(hif), "v"(v - hif));
  return pk;
}
// single bf16 RNE via hw cvt (1 VALU; low16 of result)
__device__ __forceinline__ unsigned short bf1(float v) {
  unsigned pk;
  asm("v_cvt_pk_bf16_f32 %0, %1, %2" : "=v"(pk) : "v"(v), "v"(0.0f));
  return (unsigned short)pk;
}
// unpack 8 packed uints (2x uint4) -> hi short8 + lo short8
__device__ __forceinline__ void unpk(uint4 a0, uint4 a1, short8& hi, short8& lo) {
  union { short8 s; unsigned u[4]; } H, L;
  H.u[0] = __builtin_amdgcn_perm(a0.y, a0.x, 0x05040100u);
  H.u[1] = __builtin_amdgcn_perm(a0.w, a0.z, 0x05040100u);
  H.u[2] = __builtin_amdgcn_perm(a1.y, a1.x, 0x05040100u);
  H.u[3] = __builtin_amdgcn_perm(a1.w, a1.z, 0x05040100u);
  L.u[0] = __builtin_amdgcn_perm(a0.y, a0.x, 0x07060302u);
  L.u[1] = __builtin_amdgcn_perm(a0.w, a0.z, 0x07060302u);
  L.u[2] = __builtin_amdgcn_perm(a1.y, a1.x, 0x07060302u);
  L.u[3] = __builtin_amdgcn_perm(a1.w, a1.z, 0x07060302u);
  hi = H.s; lo = L.s;
}

// async global->LDS, 16B per lane (LDS dst must be wave-uniform base + lane*16)
__device__ __forceinline__ void ld_lds16(const ushort* g, ushort* l) {
  __builtin_amdgcn_global_load_lds(
      (const __attribute__((address_space(1))) unsigned int*)g,
      (__attribute__((address_space(3))) unsigned int*)l, 16, 0, 0);
}

// ---------------------------------------------------------------------------
// split fp32 -> (hi, lo) bf16 pair, 4 elements/thread
// ---------------------------------------------------------------------------
__global__ __launch_bounds__(256) void split_kernel(const float* __restrict__ in,
                                                    ushort* __restrict__ hi,
                                                    ushort* __restrict__ lo, int n4) {
  int i = blockIdx.x * 256 + threadIdx.x;
  if (i >= n4) return;
  float4 v = ((const float4*)in)[i];
  ushort4 hv, lv;
  float t[4] = {v.x, v.y, v.z, v.w};
  unsigned short hb;
  hb = f2bf(t[0]); hv.x = hb; lv.x = f2bf(t[0] - bf2f(hb));
  hb = f2bf(t[1]); hv.y = hb; lv.y = f2bf(t[1] - bf2f(hb));
  hb = f2bf(t[2]); hv.z = hb; lv.z = f2bf(t[2] - bf2f(hb));
  hb = f2bf(t[3]); hv.w = hb; lv.w = f2bf(t[3] - bf2f(hb));
  ((ushort4*)hi)[i] = hv;
  ((ushort4*)lo)[i] = lv;
}

// ---------------------------------------------------------------------------
// qkv_w split with softmax scale folded into Q rows (rows 0..255 of each 768)
// ---------------------------------------------------------------------------
__global__ __launch_bounds__(256) void split_qkvw(const float* __restrict__ in,
                                                  ushort* __restrict__ hi,
                                                  ushort* __restrict__ lo, int n4) {
  int i = blockIdx.x * 256 + threadIdx.x;
  if (i >= n4) return;
  float4 v = ((const float4*)in)[i];
  int row = (i >> 6) % 768;   // element i*4 / 256-per-row
  float sc = (row < 256) ? (0.17677669529663687f * 1.44269504088896340f) : 1.0f;
  float t[4] = {v.x * sc, v.y * sc, v.z * sc, v.w * sc};
  ushort4 hv, lv;
  unsigned short hb;
  hb = f2bf(t[0]); hv.x = hb; lv.x = f2bf(t[0] - bf2f(hb));
  hb = f2bf(t[1]); hv.y = hb; lv.y = f2bf(t[1] - bf2f(hb));
  hb = f2bf(t[2]); hv.z = hb; lv.z = f2bf(t[2] - bf2f(hb));
  hb = f2bf(t[3]); hv.w = hb; lv.w = f2bf(t[3] - bf2f(hb));
  ((ushort4*)hi)[i] = hv;
  ((ushort4*)lo)[i] = lv;
}

// qkv bias with Q entries scaled
__global__ __launch_bounds__(256) void scale_qb(const float* __restrict__ qb,
                                                float* __restrict__ outb) {
  int i = blockIdx.x * 256 + threadIdx.x;
  if (i >= LL * 768) return;
  float sc = ((i % 768) < 256) ? (0.17677669529663687f * 1.44269504088896340f) : 1.0f;
  outb[i] = qb[i] * sc;
}

// ---------------------------------------------------------------------------
// Split-bf16 MFMA GEMM: C[M,N] = split(A)[M,K] @ split(B)[N,K]^T (+bias / +=C)
// XOR-swizzled LDS; XCD-chunked block swizzle (r1); double-buffered K (r3).
// MODE bit0: fp32 C; bit1: split bf16 C.
// PACKA: A packed uint (hi|lo<<16), lda in uints.
// SINGA: A plain bf16 (r12: t is single-bf16; 2-term MFMA = exact product,
//   one LDS plane -> 48 KB, 3 blocks/CU).
// PACKC: C packed uint (full 64B lines). SINGC: C single bf16 ushort (r12: t).
// PACKC+VT: V cols>=512 go ONLY to vt (single bf16, r12); qkvP V-cols skipped
//   (-16 MB/layer dead writes).
// r5/r7: no FFN fusion at BM=32 (L2-BW-bound). r9: no FFN row-slicing (1
//   block/CU). Both measured regressions.
// ---------------------------------------------------------------------------
template <int BM, int BN, int MODE, bool RELU, bool VT, bool ACC,
          bool PACKA = false, bool PACKC = false, bool SINGA = false,
          bool SINGC = false>
__global__ __launch_bounds__(256) void mm_split(
    const ushort* __restrict__ a_hi, const ushort* __restrict__ a_lo,
    const ushort* __restrict__ b_hi, const ushort* __restrict__ b_lo,
    const float* __restrict__ bias,
    float* __restrict__ Cf, ushort* __restrict__ c_hi, ushort* __restrict__ c_lo,
    ushort* __restrict__ vth, ushort* __restrict__ vtl,
    int M, int N, int K, int lda, int ldb) {
  constexpr int MI = BM / 32;
  constexpr int NJ = BN / 32;
  constexpr int APL = SINGA ? 1 : 2;
  __shared__ ushort As[2][APL][BM * 32];   // [dbuf][planes]
  __shared__ ushort Bs[2][2][BN * 32];
  const int tid = threadIdx.x;
  const int w = tid >> 6, lane = tid & 63;
  const int wm = (w >> 1) * (BM / 2), wn = (w & 1) * (BN / 2);

  const int nwg = gridDim.x * gridDim.y;
  int flat = blockIdx.x + gridDim.x * blockIdx.y;
  int bnb, bmb;
  if ((nwg & 7) == 0) {
    int v = (flat & 7) * (nwg >> 3) + (flat >> 3);
    bnb = v % gridDim.x;
    bmb = v / gridDim.x;
  } else {
    bnb = blockIdx.x;
    bmb = blockIdx.y;
  }
  const int bm = bmb * BM, bn = bnb * BN;
  const int lrow = lane & 15, lquad = lane >> 4;

  floatx4 acc[MI][NJ];
  floatx4 zz = {0.f, 0.f, 0.f, 0.f};
#pragma unroll
  for (int i = 0; i < MI; ++i)
#pragma unroll
    for (int j = 0; j < NJ; ++j) acc[i][j] = zz;

  const uint* aP = (const uint*)a_hi;     // PACKA view
  const int arow = tid >> 2;
  const int acol = (((tid & 3) ^ ((arow >> 1) & 3)) << 3);  // swizzled source col
  const ushort* pah = a_hi + (size_t)(bm + arow) * lda + acol;
  const ushort* pal = a_lo + (size_t)(bm + arow) * lda + acol;
  const ushort* pbh = b_hi + (size_t)(bn + arow) * ldb + acol;
  const ushort* pbl = b_lo + (size_t)(bn + arow) * ldb + acol;

  auto stage = [&](int p, int k0) {
    if constexpr (PACKA) {
#pragma unroll
      for (int s = 0; s < BM / 32; ++s) {
        int row = s * 32 + (tid >> 3);
        int gp = tid & 7;
        const uint* src = aP + (size_t)(bm + row) * lda + k0 + ((gp ^ (row & 7)) << 2);
        ld_lds16((const ushort*)src,
                 (ushort*)((char*)&As[p][0][0] + s * 4096 + tid * 16));
      }
    } else {
#pragma unroll
      for (int s = 0; s < BM / 64; ++s) {
        ld_lds16(pah + (size_t)s * 64 * lda + k0, &As[p][0][s * 2048 + tid * 8]);
        if constexpr (!SINGA)
          ld_lds16(pal + (size_t)s * 64 * lda + k0, &As[p][1][s * 2048 + tid * 8]);
      }
    }
#pragma unroll
    for (int s = 0; s < BN / 64; ++s) {
      ld_lds16(pbh + (size_t)s * 64 * ldb + k0, &Bs[p][0][s * 2048 + tid * 8]);
      ld_lds16(pbl + (size_t)s * 64 * ldb + k0, &Bs[p][1][s * 2048 + tid * 8]);
    }
  };

  stage(0, 0);
  const int nk = K >> 5;
  for (int t = 0; t < nk; ++t) {
    const int p = t & 1;
    __syncthreads();                 // stage(p) landed; prev readers of p^1 done
    if (t + 1 < nk) stage(p ^ 1, (t + 1) << 5);  // async under compute(t)
    short8 ah[MI], al[MI], bh[NJ], bl[NJ];
    if constexpr (PACKA) {
      const uint* Ap = (const uint*)&As[p][0][0];
#pragma unroll
      for (int i = 0; i < MI; ++i) {
        int rr = wm + i * 16 + lrow;
        const uint* rb = Ap + rr * 32;
        uint4 a0 = *(const uint4*)(rb + (((lquad * 2) ^ (rr & 7)) << 2));
        uint4 a1 = *(const uint4*)(rb + (((lquad * 2 + 1) ^ (rr & 7)) << 2));
        unpk(a0, a1, ah[i], al[i]);
      }
    } else {
#pragma unroll
      for (int i = 0; i < MI; ++i) {
        int rr = wm + i * 16 + lrow;
        int r = rr * 32 + ((lquad ^ ((rr >> 1) & 3)) << 3);
        ah[i] = *(const short8*)&As[p][0][r];
        if constexpr (!SINGA) al[i] = *(const short8*)&As[p][1][r];
      }
    }
#pragma unroll
    for (int j = 0; j < NJ; ++j) {
      int rr = wn + j * 16 + lrow;
      int r = rr * 32 + ((lquad ^ ((rr >> 1) & 3)) << 3);
      bh[j] = *(const short8*)&Bs[p][0][r];
      bl[j] = *(const short8*)&Bs[p][1][r];
    }
#pragma unroll
    for (int i = 0; i < MI; ++i)
#pragma unroll
      for (int j = 0; j < NJ; ++j) {
        if constexpr (SINGA) {
          acc[i][j] = __builtin_amdgcn_mfma_f32_16x16x32_bf16(ah[i], bl[j], acc[i][j], 0, 0, 0);
          acc[i][j] = __builtin_amdgcn_mfma_f32_16x16x32_bf16(ah[i], bh[j], acc[i][j], 0, 0, 0);
        } else {
          acc[i][j] = __builtin_amdgcn_mfma_f32_16x16x32_bf16(al[i], bh[j], acc[i][j], 0, 0, 0);
          acc[i][j] = __builtin_amdgcn_mfma_f32_16x16x32_bf16(ah[i], bl[j], acc[i][j], 0, 0, 0);
          acc[i][j] = __builtin_amdgcn_mfma_f32_16x16x32_bf16(ah[i], bh[j], acc[i][j], 0, 0, 0);
        }
      }
  }

#pragma unroll
  for (int j = 0; j < NJ; ++j) {
    int col = bn + wn + j * 16 + lrow;
    float bj = ACC ? 0.0f : bias[col];
#pragma unroll
    for (int i = 0; i < MI; ++i) {
      int row0 = bm + wm + i * 16 + lquad * 4;
#pragma unroll
      for (int r = 0; r < 4; ++r) {
        size_t off = (size_t)(row0 + r) * N + col;
        float v = acc[i][j][r] + bj;
        if constexpr (ACC) v += Cf[off];
        if (RELU) v = fmaxf(v, 0.0f);
        if constexpr (MODE & 1) Cf[off] = v;
        if constexpr (SINGC) {
          c_hi[off] = bf1(v);
        } else if constexpr (PACKC) {
          if constexpr (VT) {
            if (col < 512) {
              ((uint*)c_hi)[off] = tpack(v);
            } else {
              int hd = col - 512;
              int row = row0 + r;
              size_t vo = ((size_t)((row >> 9) * 8 + (hd >> 5)) * 32 + (hd & 31)) * 512 + (row & 511);
              vth[vo] = bf1(v);               // single-bf16 V (r12)
            }
          } else {
            ((uint*)c_hi)[off] = tpack(v);
          }
        } else if constexpr (MODE & 2) {
          unsigned short hb = f2bf(v);
          unsigned short lb = f2bf(v - bf2f(hb));
          c_hi[off] = hb;
          c_lo[off] = lb;
        }
      }
    }
  }
}

// ---------------------------------------------------------------------------
// Split GEMM + bias + residual + LayerNorm fused epilogue (BM=32; K=256
// out-proj only). A = PACKED attn output; h out = PACKED hP.
// ---------------------------------------------------------------------------
__global__ __launch_bounds__(256) void mm_ln(
    const uint* __restrict__ oP,
    const ushort* __restrict__ b_hi, const ushort* __restrict__ b_lo,
    const float* __restrict__ bias, const float* __restrict__ lnw,
    const float* __restrict__ lnb, float* __restrict__ hbuf,
    uint* __restrict__ hP, int K) {
  __shared__ uint AsP[32 * 32];          // packed A chunk (4KB)
  __shared__ ushort Bs[2][256 * 32];
  __shared__ float rsum[32], rsq[32], muA[32], rsA[32];
  const int tid = threadIdx.x;
  const int w = tid >> 6, lane = tid & 63;
  const int wn = w * 64;
  const int bm = blockIdx.x * 32;
  const int lr = lane & 15, quad = lane >> 4;

  floatx4 acc[2][4];
  floatx4 zz = {0.f, 0.f, 0.f, 0.f};
#pragma unroll
  for (int i = 0; i < 2; ++i)
#pragma unroll
    for (int j = 0; j < 4; ++j) acc[i][j] = zz;

  if (tid < 32) { rsum[tid] = 0.f; rsq[tid] = 0.f; }

  const int brow = tid >> 2;
  const int bcol = (((tid & 3) ^ ((brow >> 1) & 3)) << 3);

  for (int k0 = 0; k0 < K; k0 += 32) {
    __syncthreads();
    {
      int row = tid >> 3, gp = tid & 7;
      const uint* src = oP + (size_t)(bm + row) * 256 + k0 + ((gp ^ (row & 7)) << 2);
      ld_lds16((const ushort*)src, (ushort*)((char*)AsP + tid * 16));
    }
#pragma unroll
    for (int s = 0; s < 4; ++s) {
      ld_lds16(b_hi + (size_t)(s * 64 + brow) * K + bcol + k0, &Bs[0][s * 2048 + tid * 8]);
      ld_lds16(b_lo + (size_t)(s * 64 + brow) * K + bcol + k0, &Bs[1][s * 2048 + tid * 8]);
    }
    __syncthreads();
    short8 ah[2], al[2], bh[4], bl[4];
#pragma unroll
    for (int i = 0; i < 2; ++i) {
      int rr = i * 16 + lr;
      const uint* rb = AsP + rr * 32;
      uint4 a0 = *(const uint4*)(rb + (((quad * 2) ^ (rr & 7)) << 2));
      uint4 a1 = *(const uint4*)(rb + (((quad * 2 + 1) ^ (rr & 7)) << 2));
      unpk(a0, a1, ah[i], al[i]);
    }
#pragma unroll
    for (int j = 0; j < 4; ++j) {
      int rr = wn + j * 16 + lr;
      int r = rr * 32 + ((quad ^ ((rr >> 1) & 3)) << 3);
      bh[j] = *(const short8*)&Bs[0][r];
      bl[j] = *(const short8*)&Bs[1][r];
    }
#pragma unroll
    for (int i = 0; i < 2; ++i)
#pragma unroll
      for (int j = 0; j < 4; ++j) {
        acc[i][j] = __builtin_amdgcn_mfma_f32_16x16x32_bf16(al[i], bh[j], acc[i][j], 0, 0, 0);
        acc[i][j] = __builtin_amdgcn_mfma_f32_16x16x32_bf16(ah[i], bl[j], acc[i][j], 0, 0, 0);
        acc[i][j] = __builtin_amdgcn_mfma_f32_16x16x32_bf16(ah[i], bh[j], acc[i][j], 0, 0, 0);
      }
  }

  // ---- epilogue: v = acc + bias + residual; row LN; write h + packed ----
#pragma unroll
  for (int i = 0; i < 2; ++i) {
#pragma unroll
    for (int r = 0; r < 4; ++r) {
      int ridx = i * 16 + quad * 4 + r;
      float sp = 0.f, qp = 0.f;
#pragma unroll
      for (int j = 0; j < 4; ++j) {
        int col = wn + j * 16 + lr;
        float v = acc[i][j][r] + bias[col] + hbuf[(size_t)(bm + ridx) * EE + col];
        acc[i][j][r] = v;
        sp += v;
        qp += v * v;
      }
#pragma unroll
      for (int m = 1; m < 16; m <<= 1) { sp += __shfl_xor(sp, m); qp += __shfl_xor(qp, m); }
      if (lr == 0) { atomicAdd(&rsum[ridx], sp); atomicAdd(&rsq[ridx], qp); }
    }
  }
  __syncthreads();
  if (tid < 32) {
    float mu = rsum[tid] * (1.0f / 256.0f);
    float var = rsq[tid] * (1.0f / 256.0f) - mu * mu;
    muA[tid] = mu;
    rsA[tid] = 1.0f / sqrtf(var + 1e-5f);
  }
  __syncthreads();
#pragma unroll
  for (int i = 0; i < 2; ++i) {
#pragma unroll
    for (int r = 0; r < 4; ++r) {
      int ridx = i * 16 + quad * 4 + r;
      float mu = muA[ridx], rsv = rsA[ridx];
#pragma unroll
      for (int j = 0; j < 4; ++j) {
        int col = wn + j * 16 + lr;
        float o = (acc[i][j][r] - mu) * rsv * lnw[col] + lnb[col];
        size_t off = (size_t)(bm + ridx) * EE + col;
        hbuf[off] = o;
        hP[off] = tpack(o);
      }
    }
  }
}

// ---------------------------------------------------------------------------
// h = LN(h + t)*w + b ; writes fp32 h + PACKED hP. One wave per row.
// ---------------------------------------------------------------------------
__global__ __launch_bounds__(256) void ln_res_kernel(float* __restrict__ h,
                                                     const float* __restrict__ t,
                                                     const float* __restrict__ w,
                                                     const float* __restrict__ b,
                                                     uint* __restrict__ hP) {
  int row = blockIdx.x * 4 + (threadIdx.x >> 6);
  int lane = threadIdx.x & 63;
  size_t off = (size_t)row * EE + (lane << 2);
  float4 hv = *(const float4*)&h[off];
  float4 tv = *(const float4*)&t[off];
  float v0 = hv.x + tv.x, v1 = hv.y + tv.y, v2 = hv.z + tv.z, v3 = hv.w + tv.w;
  float s = (v0 + v1) + (v2 + v3);
#pragma unroll
  for (int m = 32; m > 0; m >>= 1) s += __shfl_xor(s, m);
  float mu = s * (1.0f / 256.0f);
  float d0 = v0 - mu, d1 = v1 - mu, d2 = v2 - mu, d3 = v3 - mu;
  float s2 = (d0 * d0 + d1 * d1) + (d2 * d2 + d3 * d3);
#pragma unroll
  for (int m = 32; m > 0; m >>= 1) s2 += __shfl_xor(s2, m);
  float rs = 1.0f / sqrtf(s2 * (1.0f / 256.0f) + 1e-5f);
  float4 wv = *(const float4*)&w[lane << 2];
  float4 bv = *(const float4*)&b[lane << 2];
  float4 o;
  o.x = d0 * rs * wv.x + bv.x;
  o.y = d1 * rs * wv.y + bv.y;
  o.z = d2 * rs * wv.z + bv.z;
  o.w = d3 * rs * wv.w + bv.w;
  *(float4*)&h[off] = o;
  uint4 pk;
  pk.x = tpack(o.x);
  pk.y = tpack(o.y);
  pk.z = tpack(o.z);
  pk.w = tpack(o.w);
  *(uint4*)&hP[off] = pk;
}

// ---------------------------------------------------------------------------
// MFMA flash attention — r7 structure + VALU diet + XCD swizzle + packed
// q/k input + packed o + Q-scale fold + single-bf16 P (r11).
// r12: single-bf16 V (self-consistent: O = sum(P V^)/sum(P), convex combo ->
// quantization un-amplified). V staging unpk deleted, PV 10->6 MFMA/tile,
// LDS 28.6 -> 23.5 KB = 6 blocks/CU.
// Do NOT: hoist S across m-tiles, chunk softmax <128 keys, 2 m-tiles/block,
// (gh,qt) grid — all measured regressions.
// ---------------------------------------------------------------------------
__global__ __launch_bounds__(256) void attn_mfma(const uint* __restrict__ qP,
                                                 const ushort* __restrict__ vtS,
                                                 uint* __restrict__ oP) {
  __shared__ ushort Ks[2][64 * 40];
  __shared__ ushort Vt[32 * 72];      // single-bf16 V (4.5 KB)
  __shared__ ushort Ps[4][16 * 72];   // single-bf16 P (9 KB)
  const int tid = threadIdx.x;
  const int w = tid >> 6, lane = tid & 63, c = lane & 15, quad = lane >> 4;
  int flat = blockIdx.x + 8 * (blockIdx.y + 8 * blockIdx.z);
  int v = (flat & 7) * ((GG * 64) >> 3) + (flat >> 3);
  const int qt = v & 7, hh = (v >> 3) & 7, g = v >> 6;
  const size_t g512 = (size_t)g * 512;
  const size_t vtbase = (size_t)(g * 8 + hh) * 32 * 512;

  const size_t qnode = g512 + qt * 64 + w * 16 + c;
  const uint* qp0 = qP + qnode * 768 + hh * 32 + quad * 8;
  uint4 q0 = *(const uint4*)qp0, q1 = *(const uint4*)(qp0 + 4);
  short8 qfh, qfl;
  unpk(q0, q1, qfh, qfl);

  floatx4 O0 = {0.f, 0.f, 0.f, 0.f}, O1 = {0.f, 0.f, 0.f, 0.f};
  floatx4 Lac = {0.f, 0.f, 0.f, 0.f};
  const short onev = (short)0x3F80;  // bf16 1.0
  const short8 onef = {onev, onev, onev, onev, onev, onev, onev, onev};

  const int skey = tid >> 2, sdc = (tid & 3) << 3;
  const int sd = tid >> 3, skc = (tid & 7) << 3;
  uint4 stg[2];
  short8 stgv;
  auto load_tile = [&](int kb) {
    size_t go = (g512 + kb + skey) * 768 + 256 + hh * 32 + sdc;
    stg[0] = *(const uint4*)(qP + go);
    stg[1] = *(const uint4*)(qP + go + 4);
    size_t vo = vtbase + (size_t)sd * 512 + kb + skc;
    stgv = *(const short8*)(vtS + vo);
  };
  load_tile(0);

  for (int t = 0; t < 8; ++t) {
    if (t) __syncthreads();
    {
      short8 kh, kl;
      unpk(stg[0], stg[1], kh, kl);
      *(short8*)&Ks[0][skey * 40 + sdc] = kh;
      *(short8*)&Ks[1][skey * 40 + sdc] = kl;
      *(short8*)&Vt[sd * 72 + skc] = stgv;
    }
    __syncthreads();
    if (t < 7) load_tile((t + 1) * 64);

    // ---- S = Q K^T : 4 n-tiles of 16x16 (Q pre-scaled at split) ----
    floatx4 S[4];
#pragma unroll
    for (int n = 0; n < 4; ++n) {
      int r = (n * 16 + c) * 40 + quad * 8;
      short8 kfh = *(const short8*)&Ks[0][r];
      short8 kfl = *(const short8*)&Ks[1][r];
      floatx4 s = {0.f, 0.f, 0.f, 0.f};
      s = __builtin_amdgcn_mfma_f32_16x16x32_bf16(qfh, kfl, s, 0, 0, 0);
      s = __builtin_amdgcn_mfma_f32_16x16x32_bf16(qfl, kfh, s, 0, 0, 0);
      s = __builtin_amdgcn_mfma_f32_16x16x32_bf16(qfh, kfh, s, 0, 0, 0);
      S[n] = s;
    }
    // ---- softmax numerator: P = bf16(exp2(S)), single precision ----
#pragma unroll
    for (int n = 0; n < 4; ++n) {
#pragma unroll
      for (int r = 0; r < 4; ++r) {
        float pp = exp2f(S[n][r]);
        Ps[w][(quad * 4 + r) * 72 + n * 16 + c] = bf1(pp);
      }
    }
    // ---- PV: O += P @ V ; l += P @ 1 (2 d-tiles x 2 k-steps) ----
#pragma unroll
    for (int ks = 0; ks < 2; ++ks) {
      short8 p = *(const short8*)&Ps[w][c * 72 + ks * 32 + quad * 8];
      short8 v0 = *(const short8*)&Vt[c * 72 + ks * 32 + quad * 8];
      short8 v1 = *(const short8*)&Vt[(16 + c) * 72 + ks * 32 + quad * 8];
      O0 = __builtin_amdgcn_mfma_f32_16x16x32_bf16(p, v0, O0, 0, 0, 0);
      O1 = __builtin_amdgcn_mfma_f32_16x16x32_bf16(p, v1, O1, 0, 0, 0);
      Lac = __builtin_amdgcn_mfma_f32_16x16x32_bf16(p, onef, Lac, 0, 0, 0);
    }
  }

  // ---- epilogue: normalize, pack, store (full 64B lines) ----
#pragma unroll
  for (int r = 0; r < 4; ++r) {
    float inv = 1.0f / Lac[r];
    size_t node = g512 + qt * 64 + w * 16 + quad * 4 + r;
    size_t off0 = node * EE + hh * 32 + c;
    oP[off0] = tpack(O0[r] * inv);
    oP[off0 + 16] = tpack(O1[r] * inv);
  }
}

// ---------------------------------------------------------------------------
__global__ __launch_bounds__(256) void score_kernel(const float* __restrict__ h,
                                                    const float* __restrict__ sw,
                                                    const float* __restrict__ sb,
                                                    float* __restrict__ probs) {
  int row = blockIdx.x * 4 + (threadIdx.x >> 6);
  int lane = threadIdx.x & 63;
  float4 a = *(const float4*)&h[(size_t)row * EE + (lane << 2)];
  float4 w = *(const float4*)&sw[lane << 2];
  float s = (a.x * w.x + a.y * w.y) + (a.z * w.z + a.w * w.w);
#pragma unroll
  for (int m = 32; m > 0; m >>= 1) s += __shfl_xor(s, m);
  if (lane == 0) {
    float sc = s + sb[0];
    probs[row] = 1.0f / (1.0f + expf(-sc));
  }
}

// ---------------------------------------------------------------------------
// Per-graph exact top-k with jax.lax.top_k tie semantics (lower index wins).
// ---------------------------------------------------------------------------
__global__ __launch_bounds__(256) void topk_kernel(const float* __restrict__ probs,
                                                   float* __restrict__ out) {
  __shared__ unsigned long long keys[NNODE];
  __shared__ float pv[NNODE];
  __shared__ int flags[NNODE];
  __shared__ int sc[NNODE];
  const int g = blockIdx.x, tid = threadIdx.x;
  for (int i = tid; i < NNODE; i += 256) {
    float p = probs[g * NNODE + i];
    pv[i] = p;
    keys[i] = ((unsigned long long)__float_as_uint(p) << 32) |
              (unsigned long long)(~(unsigned)i);
    flags[i] = 0;
  }
  for (int k = 2; k <= NNODE; k <<= 1) {
    for (int j = k >> 1; j > 0; j >>= 1) {
      __syncthreads();
      for (int i = tid; i < NNODE; i += 256) {
        int ixj = i ^ j;
        if (ixj > i) {
          unsigned long long a = keys[i], bq = keys[ixj];
          bool desc = ((i & k) == 0);
          bool sw = desc ? (a < bq) : (a > bq);
          if (sw) { keys[i] = bq; keys[ixj] = a; }
        }
      }
    }
  }
  __syncthreads();
  if (tid < KSEL) {
    unsigned idx = ~(unsigned)(keys[tid] & 0xFFFFFFFFull);
    flags[idx] = 1;
  }
  __syncthreads();
  sc[tid] = flags[tid];
  sc[tid + 256] = flags[tid + 256];
  for (int off = 1; off < NNODE; off <<= 1) {
    __syncthreads();
    int x0 = (tid >= off) ? sc[tid - off] : 0;
    int x1 = sc[tid + 256 - off];
    int b0 = sc[tid], b1 = sc[tid + 256];
    __syncthreads();
    sc[tid] = b0 + x0;
    sc[tid + 256] = b1 + x1;
  }
  __syncthreads();
  for (int i = tid; i < NNODE; i += 256) {
    float p = pv[i];
    int f = flags[i];
    float ind = ((float)f - p) + p;
    float pf = p * ind;
    out[NEDGE + GG * KSEL + g * NNODE + i] = pf;
    if (f) out[NEDGE + g * KSEL + (sc[i] - 1)] = (float)(g * NNODE + i);
  }
}

// ---------------------------------------------------------------------------
__global__ __launch_bounds__(256) void edge_kernel(const int* __restrict__ ei,
                                                   const float* __restrict__ w,
                                                   float* __restrict__ out) {
  int e = blockIdx.x * 256 + threadIdx.x;
  const float* pf = out + NEDGE + GG * KSEL;
  out[e] = w[e] * pf[ei[e]] * pf[ei[NEDGE + e]];
}

// ---------------------------------------------------------------------------
extern "C" void kernel_launch(void* const* d_in, const int* in_sizes, int n_in,
                              void* d_out, int out_size, void* d_ws, size_t ws_size,
                              hipStream_t stream) {
  (void)in_sizes; (void)n_in; (void)out_size; (void)ws_size;
  const float* x     = (const float*)d_in[0];
  const int*   ei    = (const int*)d_in[1];
  const float* ewts  = (const float*)d_in[2];
  const float* emb_w = (const float*)d_in[3];
  const float* emb_b = (const float*)d_in[4];
  const float* qkv_w = (const float*)d_in[5];
  const float* qkv_b = (const float*)d_in[6];
  const float* out_w = (const float*)d_in[7];
  const float* out_b = (const float*)d_in[8];
  const float* ln1_w = (const float*)d_in[9];
  const float* ln1_b = (const float*)d_in[10];
  const float* ln2_w = (const float*)d_in[11];
  const float* ln2_b = (const float*)d_in[12];
  const float* ff1_w = (const float*)d_in[13];
  const float* ff1_b = (const float*)d_in[14];
  const float* ff2_w = (const float*)d_in[15];
  const float* ff2_b = (const float*)d_in[16];
  const float* sc_w  = (const float*)d_in[17];
  const float* sc_b  = (const float*)d_in[18];
  float* out = (float*)d_out;

  const size_t MB = 1024 * 1024;
  char* base = (char*)d_ws;
  float*  h    = (float*)base;                       // [0,32)
  uint*   hP   = (uint*)(base + 32 * MB);            // [32,64) GN x 256 packed
  char*   R    = base + 64 * MB;                     // [64,224) multi-use
  // attn phase:
  uint*   qkvP = (uint*)R;                           // [64,160)  GN x 768 packed
  uint*   oP   = (uint*)(R + 96 * MB);               // [160,192) GN x 256 packed
  ushort* vtS  = (ushort*)(R + 128 * MB);            // [192,208) single-bf16 V-t
  // FFN phase (qkvP/oP/vtS dead): DFF-sliced
  ushort* tS   = (ushort*)R;                         // [64,128)  GN x 1024 bf16
  float*  delta = (float*)(R + 128 * MB);            // [192,224) GN x 256 fp32
  // embed phase:
  ushort* x_hi = (ushort*)R;                         // [64,72)
  ushort* x_lo = (ushort*)(R + 8 * MB);              // [72,80)
  float*  probs = (float*)R;                         // final
  char* W = base + 224 * MB;
  size_t woff = 0;
  auto walloc = [&](size_t bytes) { char* r = W + woff; woff += (bytes + 255) & ~(size_t)255; return (ushort*)r; };
  ushort* we_hi = walloc(256 * 128 * 2);
  ushort* we_lo = walloc(256 * 128 * 2);
  ushort* wq_hi = walloc((size_t)LL * 768 * 256 * 2);
  ushort* wq_lo = walloc((size_t)LL * 768 * 256 * 2);
  ushort* wo_hi = walloc((size_t)LL * 256 * 256 * 2);
  ushort* wo_lo = walloc((size_t)LL * 256 * 256 * 2);
  ushort* w1_hi = walloc((size_t)LL * DFFN * 256 * 2);
  ushort* w1_lo = walloc((size_t)LL * DFFN * 256 * 2);
  ushort* w2_hi = walloc((size_t)LL * 256 * DFFN * 2);
  ushort* w2_lo = walloc((size_t)LL * 256 * DFFN * 2);
  float*  qbs   = (float*)walloc((size_t)LL * 768 * 4);  // scaled qkv bias

  auto split = [&](const float* src, ushort* hi, ushort* lo, size_t n) {
    int n4 = (int)(n / 4);
    split_kernel<<<(n4 + 255) / 256, 256, 0, stream>>>(src, hi, lo, n4);
  };
  split(x, x_hi, x_lo, (size_t)GN * DIN);
  split(emb_w, we_hi, we_lo, 256 * 128);
  split_qkvw<<<((LL * 768 * 256 / 4) + 255) / 256, 256, 0, stream>>>(
      qkv_w, wq_hi, wq_lo, LL * 768 * 256 / 4);
  scale_qb<<<(LL * 768 + 255) / 256, 256, 0, stream>>>(qkv_b, qbs);
  split(out_w, wo_hi, wo_lo, (size_t)LL * 256 * 256);
  split(ff1_w, w1_hi, w1_lo, (size_t)LL * DFFN * 256);
  split(ff2_w, w2_hi, w2_lo, (size_t)LL * 256 * DFFN);

  // ---- embed: h = x @ emb_w^T + emb_b (fp32 h + PACKED hP) ----
  mm_split<128, 128, 1, false, false, false, false, true><<<dim3(EE / 128, GN / 128), 256, 0, stream>>>(
      x_hi, x_lo, we_hi, we_lo, emb_b, h, (ushort*)hP, nullptr, nullptr, nullptr,
      GN, EE, DIN, DIN, DIN);

  for (int l = 0; l < LL; ++l) {
    // qkv: PACKED A (hP) -> PACKED Q/K + single-bf16 V-transpose (V cols
    // skipped in qkvP: -16 MB/layer dead writes)
    mm_split<128, 128, 0, false, true, false, true, true><<<dim3(768 / 128, GN / 128), 256, 0, stream>>>(
        (const ushort*)hP, nullptr, wq_hi + (size_t)l * 768 * 256, wq_lo + (size_t)l * 768 * 256,
        qbs + l * 768, nullptr, (ushort*)qkvP, nullptr, vtS, nullptr,
        GN, 768, EE, EE, EE);
    attn_mfma<<<dim3(8, 8, GG), 256, 0, stream>>>(qkvP, vtS, oP);
    // out-proj + residual + LN1 fused (K=256), packed A + packed h out
    mm_ln<<<GN / 32, 256, 0, stream>>>(
        oP, wo_hi + (size_t)l * 256 * 256, wo_lo + (size_t)l * 256 * 256,
        out_b + l * 256, ln1_w + l * EE, ln1_b + l * EE, h, hP, EE);
    // FFN DFF-sliced: ff1 (PACKA h) -> single-bf16 t; ff2 (SINGA t, 2-term
    // MFMA, 48 KB LDS = 3 blocks/CU) -> delta, slice 1 accumulates.
    for (int s = 0; s < 2; ++s) {
      mm_split<128, 128, 0, true, false, false, true, false, false, true><<<dim3(1024 / 128, GN / 128), 256, 0, stream>>>(
          (const ushort*)hP, nullptr,
          w1_hi + (size_t)l * DFFN * 256 + (size_t)s * 1024 * 256,
          w1_lo + (size_t)l * DFFN * 256 + (size_t)s * 1024 * 256,
          ff1_b + l * DFFN + s * 1024, nullptr, tS, nullptr, nullptr, nullptr,
          GN, 1024, EE, EE, EE);
      if (s == 0)
        mm_split<128, 128, 1, false, false, false, false, false, true><<<dim3(EE / 128, GN / 128), 256, 0, stream>>>(
            tS, nullptr,
            w2_hi + (size_t)l * 256 * DFFN, w2_lo + (size_t)l * 256 * DFFN,
            ff2_b + l * 256, delta, nullptr, nullptr, nullptr, nullptr,
            GN, EE, 1024, 1024, DFFN);
      else
        mm_split<128, 128, 1, false, false, true, false, false, true><<<dim3(EE / 128, GN / 128), 256, 0, stream>>>(
            tS, nullptr,
            w2_hi + (size_t)l * 256 * DFFN + 1024, w2_lo + (size_t)l * 256 * DFFN + 1024,
            ff2_b + l * 256, delta, nullptr, nullptr, nullptr, nullptr,
            GN, EE, 1024, 1024, DFFN);
    }
    ln_res_kernel<<<GN / 4, 256, 0, stream>>>(
        h, delta, ln2_w + l * EE, ln2_b + l * EE, hP);
  }

  score_kernel<<<GN / 4, 256, 0, stream>>>(h, sc_w, sc_b, probs);
  topk_kernel<<<GG, 256, 0, stream>>>(probs, out);
  edge_kernel<<<NEDGE / 256, 256, 0, stream>>>(ei, ewts, out);
}

// Round 13
// 1484.356 us; speedup vs baseline: 1.4706x; 1.1654x over previous
//
#include <hip/hip_runtime.h>
#include <cstdint>
#include <cstddef>

#define GN    32768
#define GG    64
#define NNODE 512
#define EE    256
#define LL    4
#define DFFN  2048
#define NHH   8
#define HD    32
#define NEDGE 524288
#define KSEL  128
#define DIN   128

typedef __attribute__((ext_vector_type(8))) short short8;
typedef __attribute__((ext_vector_type(4))) float floatx4;
typedef _Float16 half8 __attribute__((ext_vector_type(8)));
union h8u { short8 s; half8 h; };

// ---- bf16 helpers (RNE) ---------------------------------------------------
__device__ __forceinline__ unsigned short f2bf(float x) {
  unsigned u = __float_as_uint(x);
  u = (u + 0x7FFFu + ((u >> 16) & 1u)) >> 16;
  return (unsigned short)u;
}
__device__ __forceinline__ float bf2f(unsigned short u) {
  return __uint_as_float((unsigned)u << 16);
}
// trunc-split + hw pack: low16 = bf16(hi, exact), high16 = bf16(residual, RNE)
__device__ __forceinline__ unsigned tpack(float v) {
  unsigned hib = __float_as_uint(v) & 0xFFFF0000u;
  float hif = __uint_as_float(hib);
  unsigned pk;
  asm("v_cvt_pk_bf16_f32 %0, %1, %2" : "=v"(pk) : "v"(hif), "v"(v - hif));
  return pk;
}
// single bf16 RNE via hw cvt (1 VALU; low16 of result)
__device__ __forceinline__ unsigned short bf1(float v) {
  unsigned pk;
  asm("v_cvt_pk_bf16_f32 %0, %1, %2" : "=v"(pk) : "v"(v), "v"(0.0f));
  return (unsigned short)pk;
}
// fp16 RNE conversion, bit pattern as ushort
__device__ __forceinline__ unsigned short f2h(float x) {
  union { _Float16 f; unsigned short u; } c;
  c.f = (_Float16)x;
  return c.u;
}
// unpack 8 packed uints (2x uint4) -> hi short8 + lo short8
__device__ __forceinline__ void unpk(uint4 a0, uint4 a1, short8& hi, short8& lo) {
  union { short8 s; unsigned u[4]; } H, L;
  H.u[0] = __builtin_amdgcn_perm(a0.y, a0.x, 0x05040100u);
  H.u[1] = __builtin_amdgcn_perm(a0.w, a0.z, 0x05040100u);
  H.u[2] = __builtin_amdgcn_perm(a1.y, a1.x, 0x05040100u);
  H.u[3] = __builtin_amdgcn_perm(a1.w, a1.z, 0x05040100u);
  L.u[0] = __builtin_amdgcn_perm(a0.y, a0.x, 0x07060302u);
  L.u[1] = __builtin_amdgcn_perm(a0.w, a0.z, 0x07060302u);
  L.u[2] = __builtin_amdgcn_perm(a1.y, a1.x, 0x07060302u);
  L.u[3] = __builtin_amdgcn_perm(a1.w, a1.z, 0x07060302u);
  hi = H.s; lo = L.s;
}

// async global->LDS, 16B per lane (LDS dst must be wave-uniform base + lane*16)
__device__ __forceinline__ void ld_lds16(const ushort* g, ushort* l) {
  __builtin_amdgcn_global_load_lds(
      (const __attribute__((address_space(1))) unsigned int*)g,
      (__attribute__((address_space(3))) unsigned int*)l, 16, 0, 0);
}

// ---------------------------------------------------------------------------
// split fp32 -> (hi, lo) bf16 pair, 4 elements/thread
// ---------------------------------------------------------------------------
__global__ __launch_bounds__(256) void split_kernel(const float* __restrict__ in,
                                                    ushort* __restrict__ hi,
                                                    ushort* __restrict__ lo, int n4) {
  int i = blockIdx.x * 256 + threadIdx.x;
  if (i >= n4) return;
  float4 v = ((const float4*)in)[i];
  ushort4 hv, lv;
  float t[4] = {v.x, v.y, v.z, v.w};
  unsigned short hb;
  hb = f2bf(t[0]); hv.x = hb; lv.x = f2bf(t[0] - bf2f(hb));
  hb = f2bf(t[1]); hv.y = hb; lv.y = f2bf(t[1] - bf2f(hb));
  hb = f2bf(t[2]); hv.z = hb; lv.z = f2bf(t[2] - bf2f(hb));
  hb = f2bf(t[3]); hv.w = hb; lv.w = f2bf(t[3] - bf2f(hb));
  ((ushort4*)hi)[i] = hv;
  ((ushort4*)lo)[i] = lv;
}

// fp32 -> single fp16 plane (FFN weights, r13)
__global__ __launch_bounds__(256) void split_f16(const float* __restrict__ in,
                                                 ushort* __restrict__ o, int n4) {
  int i = blockIdx.x * 256 + threadIdx.x;
  if (i >= n4) return;
  float4 v = ((const float4*)in)[i];
  ushort4 r;
  r.x = f2h(v.x); r.y = f2h(v.y); r.z = f2h(v.z); r.w = f2h(v.w);
  ((ushort4*)o)[i] = r;
}

// ---------------------------------------------------------------------------
// qkv_w split with softmax scale folded into Q rows (rows 0..255 of each 768)
// ---------------------------------------------------------------------------
__global__ __launch_bounds__(256) void split_qkvw(const float* __restrict__ in,
                                                  ushort* __restrict__ hi,
                                                  ushort* __restrict__ lo, int n4) {
  int i = blockIdx.x * 256 + threadIdx.x;
  if (i >= n4) return;
  float4 v = ((const float4*)in)[i];
  int row = (i >> 6) % 768;   // element i*4 / 256-per-row
  float sc = (row < 256) ? (0.17677669529663687f * 1.44269504088896340f) : 1.0f;
  float t[4] = {v.x * sc, v.y * sc, v.z * sc, v.w * sc};
  ushort4 hv, lv;
  unsigned short hb;
  hb = f2bf(t[0]); hv.x = hb; lv.x = f2bf(t[0] - bf2f(hb));
  hb = f2bf(t[1]); hv.y = hb; lv.y = f2bf(t[1] - bf2f(hb));
  hb = f2bf(t[2]); hv.z = hb; lv.z = f2bf(t[2] - bf2f(hb));
  hb = f2bf(t[3]); hv.w = hb; lv.w = f2bf(t[3] - bf2f(hb));
  ((ushort4*)hi)[i] = hv;
  ((ushort4*)lo)[i] = lv;
}

// qkv bias with Q entries scaled
__global__ __launch_bounds__(256) void scale_qb(const float* __restrict__ qb,
                                                float* __restrict__ outb) {
  int i = blockIdx.x * 256 + threadIdx.x;
  if (i >= LL * 768) return;
  float sc = ((i % 768) < 256) ? (0.17677669529663687f * 1.44269504088896340f) : 1.0f;
  outb[i] = qb[i] * sc;
}

// ---------------------------------------------------------------------------
// Split-bf16 MFMA GEMM (embed/qkv/out-proj): C = split(A) @ split(B)^T.
// XOR-swizzled LDS; XCD-chunked block swizzle (r1); double-buffered K (r3).
// MODE bit0: fp32 C. PACKA: A packed uint. PACKC: C packed uint.
// PACKC+VT: V cols>=512 -> single-bf16 vt only (qkvP V-cols skipped).
// r5/r7: no FFN fusion at BM=32. r9: no FFN row-slicing. Both regressions.
// ---------------------------------------------------------------------------
template <int BM, int BN, int MODE, bool RELU, bool VT, bool ACC,
          bool PACKA = false, bool PACKC = false>
__global__ __launch_bounds__(256) void mm_split(
    const ushort* __restrict__ a_hi, const ushort* __restrict__ a_lo,
    const ushort* __restrict__ b_hi, const ushort* __restrict__ b_lo,
    const float* __restrict__ bias,
    float* __restrict__ Cf, ushort* __restrict__ c_hi, ushort* __restrict__ c_lo,
    ushort* __restrict__ vth, ushort* __restrict__ vtl,
    int M, int N, int K, int lda, int ldb) {
  constexpr int MI = BM / 32;
  constexpr int NJ = BN / 32;
  __shared__ ushort As[2][2][BM * 32];   // [dbuf][hi/lo] (PACKA: packed uints)
  __shared__ ushort Bs[2][2][BN * 32];
  const int tid = threadIdx.x;
  const int w = tid >> 6, lane = tid & 63;
  const int wm = (w >> 1) * (BM / 2), wn = (w & 1) * (BN / 2);

  const int nwg = gridDim.x * gridDim.y;
  int flat = blockIdx.x + gridDim.x * blockIdx.y;
  int bnb, bmb;
  if ((nwg & 7) == 0) {
    int v = (flat & 7) * (nwg >> 3) + (flat >> 3);
    bnb = v % gridDim.x;
    bmb = v / gridDim.x;
  } else {
    bnb = blockIdx.x;
    bmb = blockIdx.y;
  }
  const int bm = bmb * BM, bn = bnb * BN;
  const int lrow = lane & 15, lquad = lane >> 4;

  floatx4 acc[MI][NJ];
  floatx4 zz = {0.f, 0.f, 0.f, 0.f};
#pragma unroll
  for (int i = 0; i < MI; ++i)
#pragma unroll
    for (int j = 0; j < NJ; ++j) acc[i][j] = zz;

  const uint* aP = (const uint*)a_hi;     // PACKA view
  const int arow = tid >> 2;
  const int acol = (((tid & 3) ^ ((arow >> 1) & 3)) << 3);  // swizzled source col
  const ushort* pah = a_hi + (size_t)(bm + arow) * lda + acol;
  const ushort* pal = a_lo + (size_t)(bm + arow) * lda + acol;
  const ushort* pbh = b_hi + (size_t)(bn + arow) * ldb + acol;
  const ushort* pbl = b_lo + (size_t)(bn + arow) * ldb + acol;

  auto stage = [&](int p, int k0) {
    if constexpr (PACKA) {
#pragma unroll
      for (int s = 0; s < BM / 32; ++s) {
        int row = s * 32 + (tid >> 3);
        int gp = tid & 7;
        const uint* src = aP + (size_t)(bm + row) * lda + k0 + ((gp ^ (row & 7)) << 2);
        ld_lds16((const ushort*)src,
                 (ushort*)((char*)&As[p][0][0] + s * 4096 + tid * 16));
      }
    } else {
#pragma unroll
      for (int s = 0; s < BM / 64; ++s) {
        ld_lds16(pah + (size_t)s * 64 * lda + k0, &As[p][0][s * 2048 + tid * 8]);
        ld_lds16(pal + (size_t)s * 64 * lda + k0, &As[p][1][s * 2048 + tid * 8]);
      }
    }
#pragma unroll
    for (int s = 0; s < BN / 64; ++s) {
      ld_lds16(pbh + (size_t)s * 64 * ldb + k0, &Bs[p][0][s * 2048 + tid * 8]);
      ld_lds16(pbl + (size_t)s * 64 * ldb + k0, &Bs[p][1][s * 2048 + tid * 8]);
    }
  };

  stage(0, 0);
  const int nk = K >> 5;
  for (int t = 0; t < nk; ++t) {
    const int p = t & 1;
    __syncthreads();                 // stage(p) landed; prev readers of p^1 done
    if (t + 1 < nk) stage(p ^ 1, (t + 1) << 5);  // async under compute(t)
    short8 ah[MI], al[MI], bh[NJ], bl[NJ];
    if constexpr (PACKA) {
      const uint* Ap = (const uint*)&As[p][0][0];
#pragma unroll
      for (int i = 0; i < MI; ++i) {
        int rr = wm + i * 16 + lrow;
        const uint* rb = Ap + rr * 32;
        uint4 a0 = *(const uint4*)(rb + (((lquad * 2) ^ (rr & 7)) << 2));
        uint4 a1 = *(const uint4*)(rb + (((lquad * 2 + 1) ^ (rr & 7)) << 2));
        unpk(a0, a1, ah[i], al[i]);
      }
    } else {
#pragma unroll
      for (int i = 0; i < MI; ++i) {
        int rr = wm + i * 16 + lrow;
        int r = rr * 32 + ((lquad ^ ((rr >> 1) & 3)) << 3);
        ah[i] = *(const short8*)&As[p][0][r];
        al[i] = *(const short8*)&As[p][1][r];
      }
    }
#pragma unroll
    for (int j = 0; j < NJ; ++j) {
      int rr = wn + j * 16 + lrow;
      int r = rr * 32 + ((lquad ^ ((rr >> 1) & 3)) << 3);
      bh[j] = *(const short8*)&Bs[p][0][r];
      bl[j] = *(const short8*)&Bs[p][1][r];
    }
#pragma unroll
    for (int i = 0; i < MI; ++i)
#pragma unroll
      for (int j = 0; j < NJ; ++j) {
        acc[i][j] = __builtin_amdgcn_mfma_f32_16x16x32_bf16(al[i], bh[j], acc[i][j], 0, 0, 0);
        acc[i][j] = __builtin_amdgcn_mfma_f32_16x16x32_bf16(ah[i], bl[j], acc[i][j], 0, 0, 0);
        acc[i][j] = __builtin_amdgcn_mfma_f32_16x16x32_bf16(ah[i], bh[j], acc[i][j], 0, 0, 0);
      }
  }

#pragma unroll
  for (int j = 0; j < NJ; ++j) {
    int col = bn + wn + j * 16 + lrow;
    float bj = ACC ? 0.0f : bias[col];
#pragma unroll
    for (int i = 0; i < MI; ++i) {
      int row0 = bm + wm + i * 16 + lquad * 4;
#pragma unroll
      for (int r = 0; r < 4; ++r) {
        size_t off = (size_t)(row0 + r) * N + col;
        float v = acc[i][j][r] + bj;
        if constexpr (ACC) v += Cf[off];
        if (RELU) v = fmaxf(v, 0.0f);
        if constexpr (MODE & 1) Cf[off] = v;
        if constexpr (PACKC) {
          if constexpr (VT) {
            if (col < 512) {
              ((uint*)c_hi)[off] = tpack(v);
            } else {
              int hd = col - 512;
              int row = row0 + r;
              size_t vo = ((size_t)((row >> 9) * 8 + (hd >> 5)) * 32 + (hd & 31)) * 512 + (row & 511);
              vth[vo] = bf1(v);               // single-bf16 V (r12)
            }
          } else {
            ((uint*)c_hi)[off] = tpack(v);
          }
        } else if constexpr (MODE & 2) {
          unsigned short hb = f2bf(v);
          unsigned short lb = f2bf(v - bf2f(hb));
          c_hi[off] = hb;
          c_lo[off] = lb;
        }
      }
    }
  }
}

// ---------------------------------------------------------------------------
// Single-fp16 MFMA GEMM (FFN, r13): C[M,N] = A16[M,K] @ B16[N,K]^T.
// fp16 rel err 2^-11 -> t/delta error ~1.5e-4/layer (r12's single-bf16 was
// ~4e-3 and flipped a top-k rank, absmax 128). 1-term MFMA (exact fp16
// product accumulated fp32), 32 KB LDS = 4 blocks/CU, staging halved.
// OUT16: C as fp16 ushort (ff1 -> t16). Else fp32 Cf (ff2 -> delta, ACC).
// ---------------------------------------------------------------------------
template <bool RELU, bool ACC, bool OUT16>
__global__ __launch_bounds__(256) void mm_f16(
    const ushort* __restrict__ a16, const ushort* __restrict__ b16,
    const float* __restrict__ bias,
    float* __restrict__ Cf, ushort* __restrict__ c16,
    int M, int N, int K, int lda, int ldb) {
  __shared__ ushort As[2][128 * 32];
  __shared__ ushort Bs[2][128 * 32];
  const int tid = threadIdx.x;
  const int w = tid >> 6, lane = tid & 63;
  const int wm = (w >> 1) * 64, wn = (w & 1) * 64;

  const int nwg = gridDim.x * gridDim.y;
  int flat = blockIdx.x + gridDim.x * blockIdx.y;
  int bnb, bmb;
  if ((nwg & 7) == 0) {
    int v = (flat & 7) * (nwg >> 3) + (flat >> 3);
    bnb = v % gridDim.x;
    bmb = v / gridDim.x;
  } else {
    bnb = blockIdx.x;
    bmb = blockIdx.y;
  }
  const int bm = bmb * 128, bn = bnb * 128;
  const int lrow = lane & 15, lquad = lane >> 4;

  floatx4 acc[4][4];
  floatx4 zz = {0.f, 0.f, 0.f, 0.f};
#pragma unroll
  for (int i = 0; i < 4; ++i)
#pragma unroll
    for (int j = 0; j < 4; ++j) acc[i][j] = zz;

  const int arow = tid >> 2;
  const int acol = (((tid & 3) ^ ((arow >> 1) & 3)) << 3);  // swizzled source col
  const ushort* pa = a16 + (size_t)(bm + arow) * lda + acol;
  const ushort* pb = b16 + (size_t)(bn + arow) * ldb + acol;

  auto stage = [&](int p, int k0) {
    ld_lds16(pa + k0, &As[p][tid * 8]);
    ld_lds16(pa + (size_t)64 * lda + k0, &As[p][2048 + tid * 8]);
    ld_lds16(pb + k0, &Bs[p][tid * 8]);
    ld_lds16(pb + (size_t)64 * ldb + k0, &Bs[p][2048 + tid * 8]);
  };

  stage(0, 0);
  const int nk = K >> 5;
  for (int t = 0; t < nk; ++t) {
    const int p = t & 1;
    __syncthreads();                 // stage(p) landed; prev readers of p^1 done
    if (t + 1 < nk) stage(p ^ 1, (t + 1) << 5);  // async under compute(t)
    h8u a[4], b[4];
#pragma unroll
    for (int i = 0; i < 4; ++i) {
      int rr = wm + i * 16 + lrow;
      a[i].s = *(const short8*)&As[p][rr * 32 + ((lquad ^ ((rr >> 1) & 3)) << 3)];
    }
#pragma unroll
    for (int j = 0; j < 4; ++j) {
      int rr = wn + j * 16 + lrow;
      b[j].s = *(const short8*)&Bs[p][rr * 32 + ((lquad ^ ((rr >> 1) & 3)) << 3)];
    }
#pragma unroll
    for (int i = 0; i < 4; ++i)
#pragma unroll
      for (int j = 0; j < 4; ++j)
        acc[i][j] = __builtin_amdgcn_mfma_f32_16x16x32_f16(a[i].h, b[j].h, acc[i][j], 0, 0, 0);
  }

#pragma unroll
  for (int j = 0; j < 4; ++j) {
    int col = bn + wn + j * 16 + lrow;
    float bj = ACC ? 0.0f : bias[col];
#pragma unroll
    for (int i = 0; i < 4; ++i) {
      int row0 = bm + wm + i * 16 + lquad * 4;
#pragma unroll
      for (int r = 0; r < 4; ++r) {
        size_t off = (size_t)(row0 + r) * N + col;
        float v = acc[i][j][r] + bj;
        if constexpr (ACC) v += Cf[off];
        if (RELU) v = fmaxf(v, 0.0f);
        if constexpr (OUT16) c16[off] = f2h(v);
        else Cf[off] = v;
      }
    }
  }
}

// ---------------------------------------------------------------------------
// Split GEMM + bias + residual + LayerNorm fused epilogue (BM=32; K=256
// out-proj only). A = PACKED attn output; h out = PACKED hP + fp16 h16
// (h16 feeds ff1 only; sole producer is this kernel).
// ---------------------------------------------------------------------------
__global__ __launch_bounds__(256) void mm_ln(
    const uint* __restrict__ oP,
    const ushort* __restrict__ b_hi, const ushort* __restrict__ b_lo,
    const float* __restrict__ bias, const float* __restrict__ lnw,
    const float* __restrict__ lnb, float* __restrict__ hbuf,
    uint* __restrict__ hP, ushort* __restrict__ h16, int K) {
  __shared__ uint AsP[32 * 32];          // packed A chunk (4KB)
  __shared__ ushort Bs[2][256 * 32];
  __shared__ float rsum[32], rsq[32], muA[32], rsA[32];
  const int tid = threadIdx.x;
  const int w = tid >> 6, lane = tid & 63;
  const int wn = w * 64;
  const int bm = blockIdx.x * 32;
  const int lr = lane & 15, quad = lane >> 4;

  floatx4 acc[2][4];
  floatx4 zz = {0.f, 0.f, 0.f, 0.f};
#pragma unroll
  for (int i = 0; i < 2; ++i)
#pragma unroll
    for (int j = 0; j < 4; ++j) acc[i][j] = zz;

  if (tid < 32) { rsum[tid] = 0.f; rsq[tid] = 0.f; }

  const int brow = tid >> 2;
  const int bcol = (((tid & 3) ^ ((brow >> 1) & 3)) << 3);

  for (int k0 = 0; k0 < K; k0 += 32) {
    __syncthreads();
    {
      int row = tid >> 3, gp = tid & 7;
      const uint* src = oP + (size_t)(bm + row) * 256 + k0 + ((gp ^ (row & 7)) << 2);
      ld_lds16((const ushort*)src, (ushort*)((char*)AsP + tid * 16));
    }
#pragma unroll
    for (int s = 0; s < 4; ++s) {
      ld_lds16(b_hi + (size_t)(s * 64 + brow) * K + bcol + k0, &Bs[0][s * 2048 + tid * 8]);
      ld_lds16(b_lo + (size_t)(s * 64 + brow) * K + bcol + k0, &Bs[1][s * 2048 + tid * 8]);
    }
    __syncthreads();
    short8 ah[2], al[2], bh[4], bl[4];
#pragma unroll
    for (int i = 0; i < 2; ++i) {
      int rr = i * 16 + lr;
      const uint* rb = AsP + rr * 32;
      uint4 a0 = *(const uint4*)(rb + (((quad * 2) ^ (rr & 7)) << 2));
      uint4 a1 = *(const uint4*)(rb + (((quad * 2 + 1) ^ (rr & 7)) << 2));
      unpk(a0, a1, ah[i], al[i]);
    }
#pragma unroll
    for (int j = 0; j < 4; ++j) {
      int rr = wn + j * 16 + lr;
      int r = rr * 32 + ((quad ^ ((rr >> 1) & 3)) << 3);
      bh[j] = *(const short8*)&Bs[0][r];
      bl[j] = *(const short8*)&Bs[1][r];
    }
#pragma unroll
    for (int i = 0; i < 2; ++i)
#pragma unroll
      for (int j = 0; j < 4; ++j) {
        acc[i][j] = __builtin_amdgcn_mfma_f32_16x16x32_bf16(al[i], bh[j], acc[i][j], 0, 0, 0);
        acc[i][j] = __builtin_amdgcn_mfma_f32_16x16x32_bf16(ah[i], bl[j], acc[i][j], 0, 0, 0);
        acc[i][j] = __builtin_amdgcn_mfma_f32_16x16x32_bf16(ah[i], bh[j], acc[i][j], 0, 0, 0);
      }
  }

  // ---- epilogue: v = acc + bias + residual; row LN; write h + packed ----
#pragma unroll
  for (int i = 0; i < 2; ++i) {
#pragma unroll
    for (int r = 0; r < 4; ++r) {
      int ridx = i * 16 + quad * 4 + r;
      float sp = 0.f, qp = 0.f;
#pragma unroll
      for (int j = 0; j < 4; ++j) {
        int col = wn + j * 16 + lr;
        float v = acc[i][j][r] + bias[col] + hbuf[(size_t)(bm + ridx) * EE + col];
        acc[i][j][r] = v;
        sp += v;
        qp += v * v;
      }
#pragma unroll
      for (int m = 1; m < 16; m <<= 1) { sp += __shfl_xor(sp, m); qp += __shfl_xor(qp, m); }
      if (lr == 0) { atomicAdd(&rsum[ridx], sp); atomicAdd(&rsq[ridx], qp); }
    }
  }
  __syncthreads();
  if (tid < 32) {
    float mu = rsum[tid] * (1.0f / 256.0f);
    float var = rsq[tid] * (1.0f / 256.0f) - mu * mu;
    muA[tid] = mu;
    rsA[tid] = 1.0f / sqrtf(var + 1e-5f);
  }
  __syncthreads();
#pragma unroll
  for (int i = 0; i < 2; ++i) {
#pragma unroll
    for (int r = 0; r < 4; ++r) {
      int ridx = i * 16 + quad * 4 + r;
      float mu = muA[ridx], rsv = rsA[ridx];
#pragma unroll
      for (int j = 0; j < 4; ++j) {
        int col = wn + j * 16 + lr;
        float o = (acc[i][j][r] - mu) * rsv * lnw[col] + lnb[col];
        size_t off = (size_t)(bm + ridx) * EE + col;
        hbuf[off] = o;
        hP[off] = tpack(o);
        h16[off] = f2h(o);
      }
    }
  }
}

// ---------------------------------------------------------------------------
// h = LN(h + t)*w + b ; writes fp32 h + PACKED hP. One wave per row.
// ---------------------------------------------------------------------------
__global__ __launch_bounds__(256) void ln_res_kernel(float* __restrict__ h,
                                                     const float* __restrict__ t,
                                                     const float* __restrict__ w,
                                                     const float* __restrict__ b,
                                                     uint* __restrict__ hP) {
  int row = blockIdx.x * 4 + (threadIdx.x >> 6);
  int lane = threadIdx.x & 63;
  size_t off = (size_t)row * EE + (lane << 2);
  float4 hv = *(const float4*)&h[off];
  float4 tv = *(const float4*)&t[off];
  float v0 = hv.x + tv.x, v1 = hv.y + tv.y, v2 = hv.z + tv.z, v3 = hv.w + tv.w;
  float s = (v0 + v1) + (v2 + v3);
#pragma unroll
  for (int m = 32; m > 0; m >>= 1) s += __shfl_xor(s, m);
  float mu = s * (1.0f / 256.0f);
  float d0 = v0 - mu, d1 = v1 - mu, d2 = v2 - mu, d3 = v3 - mu;
  float s2 = (d0 * d0 + d1 * d1) + (d2 * d2 + d3 * d3);
#pragma unroll
  for (int m = 32; m > 0; m >>= 1) s2 += __shfl_xor(s2, m);
  float rs = 1.0f / sqrtf(s2 * (1.0f / 256.0f) + 1e-5f);
  float4 wv = *(const float4*)&w[lane << 2];
  float4 bv = *(const float4*)&b[lane << 2];
  float4 o;
  o.x = d0 * rs * wv.x + bv.x;
  o.y = d1 * rs * wv.y + bv.y;
  o.z = d2 * rs * wv.z + bv.z;
  o.w = d3 * rs * wv.w + bv.w;
  *(float4*)&h[off] = o;
  uint4 pk;
  pk.x = tpack(o.x);
  pk.y = tpack(o.y);
  pk.z = tpack(o.z);
  pk.w = tpack(o.w);
  *(uint4*)&hP[off] = pk;
}

// ---------------------------------------------------------------------------
// MFMA flash attention — r7 structure + VALU diet + XCD swizzle + packed
// q/k input + packed o + Q-scale fold + single-bf16 P (r11) + single-bf16 V
// (r12). Do NOT: hoist S across m-tiles, chunk softmax <128 keys,
// 2 m-tiles/block, (gh,qt) grid — all measured regressions.
// ---------------------------------------------------------------------------
__global__ __launch_bounds__(256) void attn_mfma(const uint* __restrict__ qP,
                                                 const ushort* __restrict__ vtS,
                                                 uint* __restrict__ oP) {
  __shared__ ushort Ks[2][64 * 40];
  __shared__ ushort Vt[32 * 72];      // single-bf16 V (4.5 KB)
  __shared__ ushort Ps[4][16 * 72];   // single-bf16 P (9 KB)
  const int tid = threadIdx.x;
  const int w = tid >> 6, lane = tid & 63, c = lane & 15, quad = lane >> 4;
  int flat = blockIdx.x + 8 * (blockIdx.y + 8 * blockIdx.z);
  int v = (flat & 7) * ((GG * 64) >> 3) + (flat >> 3);
  const int qt = v & 7, hh = (v >> 3) & 7, g = v >> 6;
  const size_t g512 = (size_t)g * 512;
  const size_t vtbase = (size_t)(g * 8 + hh) * 32 * 512;

  const size_t qnode = g512 + qt * 64 + w * 16 + c;
  const uint* qp0 = qP + qnode * 768 + hh * 32 + quad * 8;
  uint4 q0 = *(const uint4*)qp0, q1 = *(const uint4*)(qp0 + 4);
  short8 qfh, qfl;
  unpk(q0, q1, qfh, qfl);

  floatx4 O0 = {0.f, 0.f, 0.f, 0.f}, O1 = {0.f, 0.f, 0.f, 0.f};
  floatx4 Lac = {0.f, 0.f, 0.f, 0.f};
  const short onev = (short)0x3F80;  // bf16 1.0
  const short8 onef = {onev, onev, onev, onev, onev, onev, onev, onev};

  const int skey = tid >> 2, sdc = (tid & 3) << 3;
  const int sd = tid >> 3, skc = (tid & 7) << 3;
  uint4 stg[2];
  short8 stgv;
  auto load_tile = [&](int kb) {
    size_t go = (g512 + kb + skey) * 768 + 256 + hh * 32 + sdc;
    stg[0] = *(const uint4*)(qP + go);
    stg[1] = *(const uint4*)(qP + go + 4);
    size_t vo = vtbase + (size_t)sd * 512 + kb + skc;
    stgv = *(const short8*)(vtS + vo);
  };
  load_tile(0);

  for (int t = 0; t < 8; ++t) {
    if (t) __syncthreads();
    {
      short8 kh, kl;
      unpk(stg[0], stg[1], kh, kl);
      *(short8*)&Ks[0][skey * 40 + sdc] = kh;
      *(short8*)&Ks[1][skey * 40 + sdc] = kl;
      *(short8*)&Vt[sd * 72 + skc] = stgv;
    }
    __syncthreads();
    if (t < 7) load_tile((t + 1) * 64);

    // ---- S = Q K^T : 4 n-tiles of 16x16 (Q pre-scaled at split) ----
    floatx4 S[4];
#pragma unroll
    for (int n = 0; n < 4; ++n) {
      int r = (n * 16 + c) * 40 + quad * 8;
      short8 kfh = *(const short8*)&Ks[0][r];
      short8 kfl = *(const short8*)&Ks[1][r];
      floatx4 s = {0.f, 0.f, 0.f, 0.f};
      s = __builtin_amdgcn_mfma_f32_16x16x32_bf16(qfh, kfl, s, 0, 0, 0);
      s = __builtin_amdgcn_mfma_f32_16x16x32_bf16(qfl, kfh, s, 0, 0, 0);
      s = __builtin_amdgcn_mfma_f32_16x16x32_bf16(qfh, kfh, s, 0, 0, 0);
      S[n] = s;
    }
    // ---- softmax numerator: P = bf16(exp2(S)), single precision ----
#pragma unroll
    for (int n = 0; n < 4; ++n) {
#pragma unroll
      for (int r = 0; r < 4; ++r) {
        float pp = exp2f(S[n][r]);
        Ps[w][(quad * 4 + r) * 72 + n * 16 + c] = bf1(pp);
      }
    }
    // ---- PV: O += P @ V ; l += P @ 1 (2 d-tiles x 2 k-steps) ----
#pragma unroll
    for (int ks = 0; ks < 2; ++ks) {
      short8 p = *(const short8*)&Ps[w][c * 72 + ks * 32 + quad * 8];
      short8 v0 = *(const short8*)&Vt[c * 72 + ks * 32 + quad * 8];
      short8 v1 = *(const short8*)&Vt[(16 + c) * 72 + ks * 32 + quad * 8];
      O0 = __builtin_amdgcn_mfma_f32_16x16x32_bf16(p, v0, O0, 0, 0, 0);
      O1 = __builtin_amdgcn_mfma_f32_16x16x32_bf16(p, v1, O1, 0, 0, 0);
      Lac = __builtin_amdgcn_mfma_f32_16x16x32_bf16(p, onef, Lac, 0, 0, 0);
    }
  }

  // ---- epilogue: normalize, pack, store (full 64B lines) ----
#pragma unroll
  for (int r = 0; r < 4; ++r) {
    float inv = 1.0f / Lac[r];
    size_t node = g512 + qt * 64 + w * 16 + quad * 4 + r;
    size_t off0 = node * EE + hh * 32 + c;
    oP[off0] = tpack(O0[r] * inv);
    oP[off0 + 16] = tpack(O1[r] * inv);
  }
}

// ---------------------------------------------------------------------------
__global__ __launch_bounds__(256) void score_kernel(const float* __restrict__ h,
                                                    const float* __restrict__ sw,
                                                    const float* __restrict__ sb,
                                                    float* __restrict__ probs) {
  int row = blockIdx.x * 4 + (threadIdx.x >> 6);
  int lane = threadIdx.x & 63;
  float4 a = *(const float4*)&h[(size_t)row * EE + (lane << 2)];
  float4 w = *(const float4*)&sw[lane << 2];
  float s = (a.x * w.x + a.y * w.y) + (a.z * w.z + a.w * w.w);
#pragma unroll
  for (int m = 32; m > 0; m >>= 1) s += __shfl_xor(s, m);
  if (lane == 0) {
    float sc = s + sb[0];
    probs[row] = 1.0f / (1.0f + expf(-sc));
  }
}

// ---------------------------------------------------------------------------
// Per-graph exact top-k with jax.lax.top_k tie semantics (lower index wins).
// ---------------------------------------------------------------------------
__global__ __launch_bounds__(256) void topk_kernel(const float* __restrict__ probs,
                                                   float* __restrict__ out) {
  __shared__ unsigned long long keys[NNODE];
  __shared__ float pv[NNODE];
  __shared__ int flags[NNODE];
  __shared__ int sc[NNODE];
  const int g = blockIdx.x, tid = threadIdx.x;
  for (int i = tid; i < NNODE; i += 256) {
    float p = probs[g * NNODE + i];
    pv[i] = p;
    keys[i] = ((unsigned long long)__float_as_uint(p) << 32) |
              (unsigned long long)(~(unsigned)i);
    flags[i] = 0;
  }
  for (int k = 2; k <= NNODE; k <<= 1) {
    for (int j = k >> 1; j > 0; j >>= 1) {
      __syncthreads();
      for (int i = tid; i < NNODE; i += 256) {
        int ixj = i ^ j;
        if (ixj > i) {
          unsigned long long a = keys[i], bq = keys[ixj];
          bool desc = ((i & k) == 0);
          bool sw = desc ? (a < bq) : (a > bq);
          if (sw) { keys[i] = bq; keys[ixj] = a; }
        }
      }
    }
  }
  __syncthreads();
  if (tid < KSEL) {
    unsigned idx = ~(unsigned)(keys[tid] & 0xFFFFFFFFull);
    flags[idx] = 1;
  }
  __syncthreads();
  sc[tid] = flags[tid];
  sc[tid + 256] = flags[tid + 256];
  for (int off = 1; off < NNODE; off <<= 1) {
    __syncthreads();
    int x0 = (tid >= off) ? sc[tid - off] : 0;
    int x1 = sc[tid + 256 - off];
    int b0 = sc[tid], b1 = sc[tid + 256];
    __syncthreads();
    sc[tid] = b0 + x0;
    sc[tid + 256] = b1 + x1;
  }
  __syncthreads();
  for (int i = tid; i < NNODE; i += 256) {
    float p = pv[i];
    int f = flags[i];
    float ind = ((float)f - p) + p;
    float pf = p * ind;
    out[NEDGE + GG * KSEL + g * NNODE + i] = pf;
    if (f) out[NEDGE + g * KSEL + (sc[i] - 1)] = (float)(g * NNODE + i);
  }
}

// ---------------------------------------------------------------------------
__global__ __launch_bounds__(256) void edge_kernel(const int* __restrict__ ei,
                                                   const float* __restrict__ w,
                                                   float* __restrict__ out) {
  int e = blockIdx.x * 256 + threadIdx.x;
  const float* pf = out + NEDGE + GG * KSEL;
  out[e] = w[e] * pf[ei[e]] * pf[ei[NEDGE + e]];
}

// ---------------------------------------------------------------------------
extern "C" void kernel_launch(void* const* d_in, const int* in_sizes, int n_in,
                              void* d_out, int out_size, void* d_ws, size_t ws_size,
                              hipStream_t stream) {
  (void)in_sizes; (void)n_in; (void)out_size; (void)ws_size;
  const float* x     = (const float*)d_in[0];
  const int*   ei    = (const int*)d_in[1];
  const float* ewts  = (const float*)d_in[2];
  const float* emb_w = (const float*)d_in[3];
  const float* emb_b = (const float*)d_in[4];
  const float* qkv_w = (const float*)d_in[5];
  const float* qkv_b = (const float*)d_in[6];
  const float* out_w = (const float*)d_in[7];
  const float* out_b = (const float*)d_in[8];
  const float* ln1_w = (const float*)d_in[9];
  const float* ln1_b = (const float*)d_in[10];
  const float* ln2_w = (const float*)d_in[11];
  const float* ln2_b = (const float*)d_in[12];
  const float* ff1_w = (const float*)d_in[13];
  const float* ff1_b = (const float*)d_in[14];
  const float* ff2_w = (const float*)d_in[15];
  const float* ff2_b = (const float*)d_in[16];
  const float* sc_w  = (const float*)d_in[17];
  const float* sc_b  = (const float*)d_in[18];
  float* out = (float*)d_out;

  const size_t MB = 1024 * 1024;
  char* base = (char*)d_ws;
  float*  h    = (float*)base;                       // [0,32)
  uint*   hP   = (uint*)(base + 32 * MB);            // [32,64) GN x 256 packed
  char*   R    = base + 64 * MB;                     // [64,224) multi-use
  // attn phase:
  uint*   qkvP = (uint*)R;                           // [64,160)  GN x 768 packed
  uint*   oP   = (uint*)(R + 96 * MB);               // [160,192) GN x 256 packed
  ushort* vtS  = (ushort*)(R + 128 * MB);            // [192,208) single-bf16 V-t
  ushort* h16  = (ushort*)(R + 144 * MB);            // [208,224) GN x 256 fp16
  // FFN phase (qkvP dead after mm_ln; oP dead after mm_ln; vtS dead):
  ushort* t16  = (ushort*)R;                         // [64,128)  GN x 1024 fp16
  float*  delta = (float*)(R + 96 * MB);             // [160,192) GN x 256 fp32
  // embed phase:
  ushort* x_hi = (ushort*)R;                         // [64,72)
  ushort* x_lo = (ushort*)(R + 8 * MB);              // [72,80)
  float*  probs = (float*)R;                         // final
  char* W = base + 224 * MB;
  size_t woff = 0;
  auto walloc = [&](size_t bytes) { char* r = W + woff; woff += (bytes + 255) & ~(size_t)255; return (ushort*)r; };
  ushort* we_hi = walloc(256 * 128 * 2);
  ushort* we_lo = walloc(256 * 128 * 2);
  ushort* wq_hi = walloc((size_t)LL * 768 * 256 * 2);
  ushort* wq_lo = walloc((size_t)LL * 768 * 256 * 2);
  ushort* wo_hi = walloc((size_t)LL * 256 * 256 * 2);
  ushort* wo_lo = walloc((size_t)LL * 256 * 256 * 2);
  ushort* w1f = walloc((size_t)LL * DFFN * 256 * 2);   // fp16 single planes
  ushort* w2f = walloc((size_t)LL * 256 * DFFN * 2);
  float*  qbs = (float*)walloc((size_t)LL * 768 * 4);  // scaled qkv bias

  auto split = [&](const float* src, ushort* hi, ushort* lo, size_t n) {
    int n4 = (int)(n / 4);
    split_kernel<<<(n4 + 255) / 256, 256, 0, stream>>>(src, hi, lo, n4);
  };
  split(x, x_hi, x_lo, (size_t)GN * DIN);
  split(emb_w, we_hi, we_lo, 256 * 128);
  split_qkvw<<<((LL * 768 * 256 / 4) + 255) / 256, 256, 0, stream>>>(
      qkv_w, wq_hi, wq_lo, LL * 768 * 256 / 4);
  scale_qb<<<(LL * 768 + 255) / 256, 256, 0, stream>>>(qkv_b, qbs);
  split(out_w, wo_hi, wo_lo, (size_t)LL * 256 * 256);
  split_f16<<<((LL * DFFN * 256 / 4) + 255) / 256, 256, 0, stream>>>(
      ff1_w, w1f, LL * DFFN * 256 / 4);
  split_f16<<<((LL * 256 * DFFN / 4) + 255) / 256, 256, 0, stream>>>(
      ff2_w, w2f, LL * 256 * DFFN / 4);

  // ---- embed: h = x @ emb_w^T + emb_b (fp32 h + PACKED hP) ----
  mm_split<128, 128, 1, false, false, false, false, true><<<dim3(EE / 128, GN / 128), 256, 0, stream>>>(
      x_hi, x_lo, we_hi, we_lo, emb_b, h, (ushort*)hP, nullptr, nullptr, nullptr,
      GN, EE, DIN, DIN, DIN);

  for (int l = 0; l < LL; ++l) {
    // qkv: PACKED A (hP) -> PACKED Q/K + single-bf16 V-transpose
    mm_split<128, 128, 0, false, true, false, true, true><<<dim3(768 / 128, GN / 128), 256, 0, stream>>>(
        (const ushort*)hP, nullptr, wq_hi + (size_t)l * 768 * 256, wq_lo + (size_t)l * 768 * 256,
        qbs + l * 768, nullptr, (ushort*)qkvP, nullptr, vtS, nullptr,
        GN, 768, EE, EE, EE);
    attn_mfma<<<dim3(8, 8, GG), 256, 0, stream>>>(qkvP, vtS, oP);
    // out-proj + residual + LN1 fused (K=256): packed A -> h, hP, h16
    mm_ln<<<GN / 32, 256, 0, stream>>>(
        oP, wo_hi + (size_t)l * 256 * 256, wo_lo + (size_t)l * 256 * 256,
        out_b + l * 256, ln1_w + l * EE, ln1_b + l * EE, h, hP, h16, EE);
    // FFN fp16 (r13): ff1 1-term fp16 -> t16; ff2 1-term fp16 -> delta
    for (int s = 0; s < 2; ++s) {
      mm_f16<true, false, true><<<dim3(1024 / 128, GN / 128), 256, 0, stream>>>(
          h16, w1f + (size_t)l * DFFN * 256 + (size_t)s * 1024 * 256,
          ff1_b + l * DFFN + s * 1024, nullptr, t16,
          GN, 1024, EE, EE, EE);
      if (s == 0)
        mm_f16<false, false, false><<<dim3(EE / 128, GN / 128), 256, 0, stream>>>(
            t16, w2f + (size_t)l * 256 * DFFN,
            ff2_b + l * 256, delta, nullptr,
            GN, EE, 1024, 1024, DFFN);
      else
        mm_f16<false, true, false><<<dim3(EE / 128, GN / 128), 256, 0, stream>>>(
            t16, w2f + (size_t)l * 256 * DFFN + 1024,
            ff2_b + l * 256, delta, nullptr,
            GN, EE, 1024, 1024, DFFN);
    }
    ln_res_kernel<<<GN / 4, 256, 0, stream>>>(
        h, delta, ln2_w + l * EE, ln2_b + l * EE, hP);
  }

  score_kernel<<<GN / 4, 256, 0, stream>>>(h, sc_w, sc_b, probs);
  topk_kernel<<<GG, 256, 0, stream>>>(probs, out);
  edge_kernel<<<NEDGE / 256, 256, 0, stream>>>(ei, ewts, out);
}